// Round 9
// baseline (3502.407 us; speedup 1.0000x reference)
//
#include <hip/hip_runtime.h>
#include <math.h>

#define SLOPE 0.2f
#define EPSV 1e-12f
#define NEGINF (-3.0e38f)

static __device__ __forceinline__ float lrelu_combine(float xv, float dvv, float dot, float dsq) {
  float xneg = xv - dot / (dsq + EPSV) * dvv;
  float w = (dot >= 0.f) ? xv : xneg;
  return SLOPE * xv + (1.f - SLOPE) * w;
}

// ---------------- squared norms per point, up to 2 inputs (side = blockIdx.z) ----------------
__global__ void k_xx2(const float* __restrict__ x0, const float* __restrict__ x1,
                      float* __restrict__ xxA, float* __restrict__ xxB, int D, int N) {
  int side = blockIdx.z;
  const float* x = side ? x1 : x0;
  float* xx = side ? xxB : xxA;
  int b = blockIdx.y;
  int m = blockIdx.x * 256 + threadIdx.x;
  if (m >= N) return;
  const float* xp = x + (size_t)b * D * N + m;
  float s = 0.f;
  for (int d = 0; d < D; ++d) { float v = xp[(size_t)d * N]; s = fmaf(v, v, s); }
  xx[b * N + m] = s;
}

// ---------------- legacy fused knn (used for D=3 only) ----------------
template <int D>
__global__ void __launch_bounds__(256) k_knn2(const float* __restrict__ x0, const float* __restrict__ x1,
                                              const float* __restrict__ xxA, const float* __restrict__ xxB,
                                              int* __restrict__ idx0, int* __restrict__ idx1, int N) {
  int side = blockIdx.z;
  const float* x = side ? x1 : x0;
  const float* xx = side ? xxB : xxA;
  int* idx = side ? idx1 : idx0;
  __shared__ float qt[D * 4];
  __shared__ float dist[4][2048];
  __shared__ float xxq[4];
  int b = blockIdx.y, tid = threadIdx.x;
  int q0 = blockIdx.x * 4;
  const float* xb = x + (size_t)b * D * N;
  for (int i = tid; i < D * 4; i += 256) qt[i] = xb[(size_t)(i >> 2) * N + q0 + (i & 3)];
  if (tid < 4) xxq[tid] = xx[b * N + q0 + tid];
  __syncthreads();
  int kouter = N >> 10;
  for (int k = 0; k < kouter; ++k) {
    int m0 = tid + (k << 10);
    float4 a0 = {0, 0, 0, 0}, a1 = {0, 0, 0, 0}, a2 = {0, 0, 0, 0}, a3 = {0, 0, 0, 0};
#pragma unroll
    for (int d = 0; d < D; ++d) {
      const float4 q4 = *(const float4*)&qt[d * 4];
      const float* xr = xb + (size_t)d * N + m0;
      float v0 = xr[0], v1 = xr[256], v2 = xr[512], v3 = xr[768];
      a0.x = fmaf(q4.x, v0, a0.x); a0.y = fmaf(q4.y, v0, a0.y);
      a0.z = fmaf(q4.z, v0, a0.z); a0.w = fmaf(q4.w, v0, a0.w);
      a1.x = fmaf(q4.x, v1, a1.x); a1.y = fmaf(q4.y, v1, a1.y);
      a1.z = fmaf(q4.z, v1, a1.z); a1.w = fmaf(q4.w, v1, a1.w);
      a2.x = fmaf(q4.x, v2, a2.x); a2.y = fmaf(q4.y, v2, a2.y);
      a2.z = fmaf(q4.z, v2, a2.z); a2.w = fmaf(q4.w, v2, a2.w);
      a3.x = fmaf(q4.x, v3, a3.x); a3.y = fmaf(q4.y, v3, a3.y);
      a3.z = fmaf(q4.z, v3, a3.z); a3.w = fmaf(q4.w, v3, a3.w);
    }
    const float* xxb2 = xx + b * N + m0;
    float x0v = xxb2[0], x1v = xxb2[256], x2v = xxb2[512], x3v = xxb2[768];
    dist[0][m0]       = 2.f * a0.x - xxq[0] - x0v;
    dist[1][m0]       = 2.f * a0.y - xxq[1] - x0v;
    dist[2][m0]       = 2.f * a0.z - xxq[2] - x0v;
    dist[3][m0]       = 2.f * a0.w - xxq[3] - x0v;
    dist[0][m0 + 256] = 2.f * a1.x - xxq[0] - x1v;
    dist[1][m0 + 256] = 2.f * a1.y - xxq[1] - x1v;
    dist[2][m0 + 256] = 2.f * a1.z - xxq[2] - x1v;
    dist[3][m0 + 256] = 2.f * a1.w - xxq[3] - x1v;
    dist[0][m0 + 512] = 2.f * a2.x - xxq[0] - x2v;
    dist[1][m0 + 512] = 2.f * a2.y - xxq[1] - x2v;
    dist[2][m0 + 512] = 2.f * a2.z - xxq[2] - x2v;
    dist[3][m0 + 512] = 2.f * a2.w - xxq[3] - x2v;
    dist[0][m0 + 768] = 2.f * a3.x - xxq[0] - x3v;
    dist[1][m0 + 768] = 2.f * a3.y - xxq[1] - x3v;
    dist[2][m0 + 768] = 2.f * a3.z - xxq[2] - x3v;
    dist[3][m0 + 768] = 2.f * a3.w - xxq[3] - x3v;
  }
  __syncthreads();
  int g = tid >> 6, lane = tid & 63;
  float* dr = dist[g];
  int n = q0 + g;
  int imax = N >> 8;
  int* op = idx + ((size_t)b * N + n) * 16;
  for (int r = 0; r < 16; ++r) {
    float bv = NEGINF;
    int bi = N;
    for (int i = 0; i < imax; ++i) {
      int mb = i * 256 + lane * 4;
      float4 v = *(const float4*)&dr[mb];
      if (v.x > bv) { bv = v.x; bi = mb; }
      if (v.y > bv) { bv = v.y; bi = mb + 1; }
      if (v.z > bv) { bv = v.z; bi = mb + 2; }
      if (v.w > bv) { bv = v.w; bi = mb + 3; }
    }
#pragma unroll
    for (int s = 1; s < 64; s <<= 1) {
      float ov = __shfl_xor(bv, s, 64);
      int oi = __shfl_xor(bi, s, 64);
      if (ov > bv || (ov == bv && oi < bi)) { bv = ov; bi = oi; }
    }
    if (lane == 0) { op[r] = bi; dr[bi] = NEGINF; }
  }
}

// ---------------- streaming block-KNN (D=192): 64-query tile x m-segment, top-16 in LDS ----------------
// Distances: identical fmaf chains + epilogue as k_gram/k_knn2. Selection: sorted-16 list under the
// total order (v desc, idx asc) == reference's iterative argmax with min-index ties (order statistics).
__global__ void __launch_bounds__(256) k_knnb(const float* __restrict__ x0, const float* __restrict__ x1,
                                              const float* __restrict__ xxA, const float* __restrict__ xxB,
                                              float* __restrict__ pv, int* __restrict__ pi, int N) {
  int side = blockIdx.z;
  const float* x = side ? x1 : x0;
  const float* xx = side ? xxB : xxA;
  __shared__ float sq[16][64];
  __shared__ float sm[16][64];
  __shared__ float dist[64][64];
  __shared__ float tv[64][16];
  __shared__ int   ti[64][16];
  int b = blockIdx.y >> 2;   // grid.y = B*4
  int seg = blockIdx.y & 3;
  int q0 = blockIdx.x << 6;
  int tid = threadIdx.x;
  for (int i = tid; i < 64 * 16; i += 256) { tv[i >> 4][i & 15] = NEGINF; ti[i >> 4][i & 15] = 0x7fffffff; }
  __syncthreads();
  const float* xb = x + (size_t)b * 192 * N;
  int tmg = tid & 15, tqg = tid >> 4;
  int wave = tid >> 6, lane = tid & 63;
  int segN = N >> 2;
  int NT = segN >> 6;
  for (int t = 0; t < NT; ++t) {
    int m0 = seg * segN + (t << 6);
    float acc[16];
#pragma unroll
    for (int i = 0; i < 16; ++i) acc[i] = 0.f;
    for (int dc = 0; dc < 192; dc += 16) {
      for (int i = tid; i < 1024; i += 256) {
        int dd = i >> 6, c = i & 63;
        sq[dd][c] = xb[(size_t)(dc + dd) * N + q0 + c];
        sm[dd][c] = xb[(size_t)(dc + dd) * N + m0 + c];
      }
      __syncthreads();
#pragma unroll
      for (int dd = 0; dd < 16; ++dd) {
        float4 qv = *(const float4*)&sq[dd][tqg * 4];
        float4 mv = *(const float4*)&sm[dd][tmg * 4];
        acc[0]  = fmaf(qv.x, mv.x, acc[0]);
        acc[1]  = fmaf(qv.x, mv.y, acc[1]);
        acc[2]  = fmaf(qv.x, mv.z, acc[2]);
        acc[3]  = fmaf(qv.x, mv.w, acc[3]);
        acc[4]  = fmaf(qv.y, mv.x, acc[4]);
        acc[5]  = fmaf(qv.y, mv.y, acc[5]);
        acc[6]  = fmaf(qv.y, mv.z, acc[6]);
        acc[7]  = fmaf(qv.y, mv.w, acc[7]);
        acc[8]  = fmaf(qv.z, mv.x, acc[8]);
        acc[9]  = fmaf(qv.z, mv.y, acc[9]);
        acc[10] = fmaf(qv.z, mv.z, acc[10]);
        acc[11] = fmaf(qv.z, mv.w, acc[11]);
        acc[12] = fmaf(qv.w, mv.x, acc[12]);
        acc[13] = fmaf(qv.w, mv.y, acc[13]);
        acc[14] = fmaf(qv.w, mv.z, acc[14]);
        acc[15] = fmaf(qv.w, mv.w, acc[15]);
      }
      __syncthreads();
    }
    float4 xxm = *(const float4*)&xx[b * N + m0 + tmg * 4];
#pragma unroll
    for (int qi = 0; qi < 4; ++qi) {
      int ql = tqg * 4 + qi;
      float xq = xx[b * N + q0 + ql];
      float4 o;
      o.x = 2.f * acc[qi * 4 + 0] - xq - xxm.x;
      o.y = 2.f * acc[qi * 4 + 1] - xq - xxm.y;
      o.z = 2.f * acc[qi * 4 + 2] - xq - xxm.z;
      o.w = 2.f * acc[qi * 4 + 3] - xq - xxm.w;
      *(float4*)&dist[ql][tmg * 4] = o;
    }
    __syncthreads();
    // merge: wave w owns queries [w*16, w*16+16)
    for (int qq = 0; qq < 16; ++qq) {
      int ql = wave * 16 + qq;
      float dv = dist[ql][lane];
      int mg = m0 + lane;
      float thv = tv[ql][15];
      int thi = ti[ql][15];
      bool qual = (dv > thv) || (dv == thv && mg < thi);
      unsigned long long mask = __ballot(qual);
      while (mask) {
        int src = __ffsll((unsigned long long)mask) - 1;
        mask &= mask - 1;
        float cv = __shfl(dv, src, 64);
        int cm = m0 + src;
        bool prec = false;
        if (lane < 16) {
          float ev = tv[ql][lane];
          int ei = ti[ql][lane];
          prec = (ev > cv) || (ev == cv && ei < cm);
        }
        unsigned long long pmask = __ballot(prec);
        int p = __popcll(pmask & 0xFFFFull);
        if (p < 16) {
          float upv = 0.f; int upi = 0;
          if (lane < 16 && lane > p) { upv = tv[ql][lane - 1]; upi = ti[ql][lane - 1]; }
          if (lane < 16) {
            if (lane == p) { tv[ql][lane] = cv; ti[ql][lane] = cm; }
            else if (lane > p) { tv[ql][lane] = upv; ti[ql][lane] = upi; }
          }
        }
      }
    }
    __syncthreads();
  }
  for (int i = tid; i < 64 * 16; i += 256) {
    int ql = i >> 4, slot = i & 15;
    size_t base = ((size_t)((side * 2 + b) * N + q0 + ql)) * 64 + seg * 16;
    pv[base + slot] = tv[ql][slot];
    pi[base + slot] = ti[ql][slot];
  }
}

// ---------------- merge 4 partial top-16 lists -> final top-16 (exact comparator) ----------------
__global__ void __launch_bounds__(256) k_kmerge(const float* __restrict__ pv, const int* __restrict__ pi,
                                                int* __restrict__ idx0, int* __restrict__ idx1, int N) {
  int side = blockIdx.z;
  int* idx = side ? idx1 : idx0;
  int b = blockIdx.y;
  int tid = threadIdx.x;
  int q = blockIdx.x * 4 + (tid >> 6);
  int lane = tid & 63;
  size_t base = ((size_t)((side * 2 + b) * N + q)) * 64;
  float v = pv[base + lane];
  int i = pi[base + lane];
  int* op = idx + ((size_t)b * N + q) * 16;
  for (int r = 0; r < 16; ++r) {
    float bv = v; int bi = i;
#pragma unroll
    for (int s = 1; s < 64; s <<= 1) {
      float ov = __shfl_xor(bv, s, 64);
      int oi = __shfl_xor(bi, s, 64);
      if (ov > bv || (ov == bv && oi < bi)) { bv = ov; bi = oi; }
    }
    if (lane == 0) op[r] = bi;
    if (v == bv && i == bi) { v = NEGINF; i = 0x7fffffff; }
  }
}

// ---------------- multi-slot 64-out linear (slot = blockIdx.z>>2), dual-layout output ----------------
struct LinSlots {
  const float* W[5]; const float* X[5]; const float* bias[5];
  float* cm[5]; float* pm[5];
  int ws[5]; int woff[5]; int sub[5];
};

template <int KT>
__global__ void __launch_bounds__(256) k_linm(LinSlots S, int N) {
  __shared__ float wl[64 * ((KT + 3) & ~3)];
  const int KP = (KT + 3) & ~3;
  int slot = blockIdx.z >> 2;
  int oc = (blockIdx.z & 3) * 16;
  const float* W = S.W[slot];
  int ws = S.ws[slot], woff = S.woff[slot], sub = S.sub[slot];
  int tid = threadIdx.x;
  for (int i = tid; i < 64 * KT; i += 256) {
    int o = i / KT, k = i - o * KT;
    float v = W[o * ws + woff + k];
    if (sub) v -= W[o * ws + k];
    wl[o * KP + k] = v;
  }
  __syncthreads();
  int b = blockIdx.y;
  int j = blockIdx.x * 256 + tid;
  int M3 = 3 * N;
  if (j >= M3) return;
  const float* Xb = S.X[slot] + (size_t)b * KT * M3;
  float xv[KT];
#pragma unroll
  for (int k = 0; k < KT; ++k) xv[k] = Xb[(size_t)k * M3 + j];
  int d = j / N;
  const float* bias = S.bias[slot];
  float acc[16];
  if (bias) {
#pragma unroll
    for (int oo = 0; oo < 16; ++oo) acc[oo] = bias[b * 192 + (oc + oo) * 3 + d];
  } else {
#pragma unroll
    for (int oo = 0; oo < 16; ++oo) acc[oo] = 0.f;
  }
#pragma unroll
  for (int oo = 0; oo < 16; ++oo) {
    const float* wr = &wl[(oc + oo) * KP];
    float s = acc[oo];
#pragma unroll
    for (int k = 0; k < KT; ++k) s = fmaf(wr[k], xv[k], s);
    acc[oo] = s;
  }
  if (S.cm[slot]) {
    float* ob = S.cm[slot] + (size_t)b * 64 * M3;
#pragma unroll
    for (int oo = 0; oo < 16; ++oo) ob[(size_t)(oc + oo) * M3 + j] = acc[oo];
  }
  if (S.pm[slot]) {
    int n = j - d * N;
    float4* pp = (float4*)(S.pm[slot] + ((size_t)((b * N + n) * 3 + d)) * 64 + oc);
    pp[0] = make_float4(acc[0], acc[1], acc[2], acc[3]);
    pp[1] = make_float4(acc[4], acc[5], acc[6], acc[7]);
    pp[2] = make_float4(acc[8], acc[9], acc[10], acc[11]);
    pp[3] = make_float4(acc[12], acc[13], acc[14], acc[15]);
  }
}

// ---------------- edge conv, wave per point, side = blockIdx.y ----------------
__global__ void __launch_bounds__(256) k_edge2(const float* __restrict__ P1a, const float* __restrict__ P2a,
                                               const float* __restrict__ D1a, const float* __restrict__ D2a,
                                               const float* __restrict__ P1b, const float* __restrict__ P2b,
                                               const float* __restrict__ D1b, const float* __restrict__ D2b,
                                               const int* __restrict__ idxA, const int* __restrict__ idxB,
                                               float* __restrict__ outA, float* __restrict__ outB, int N) {
  int side = blockIdx.y;
  const float* P1 = side ? P1b : P1a;
  const float* P2 = side ? P2b : P2a;
  const float* D1 = side ? D1b : D1a;
  const float* D2 = side ? D2b : D2a;
  const int* idx = side ? idxB : idxA;
  float* out = side ? outB : outA;
  int tid = threadIdx.x;
  int p = blockIdx.x * 4 + (tid >> 6);
  int c = tid & 63;
  int b = p / N, n = p - b * N;
  size_t bn = ((size_t)(b * N + n) * 3) * 64 + c;
  float p2[3], d2[3];
#pragma unroll
  for (int d = 0; d < 3; ++d) { p2[d] = P2[bn + d * 64]; d2[d] = D2[bn + d * 64]; }
  const int* ip = idx + ((size_t)b * N + n) * 16;
  float acc0 = 0.f, acc1 = 0.f, acc2 = 0.f;
  for (int j = 0; j < 16; ++j) {
    int m = ip[j];
    size_t bm = ((size_t)(b * N + m) * 3) * 64 + c;
    float xl[3], dv[3];
#pragma unroll
    for (int d = 0; d < 3; ++d) {
      xl[d] = P1[bm + d * 64] + p2[d];
      dv[d] = D1[bm + d * 64] + d2[d];
    }
    float dot = xl[0] * dv[0] + xl[1] * dv[1] + xl[2] * dv[2];
    float dsq = dv[0] * dv[0] + dv[1] * dv[1] + dv[2] * dv[2];
    acc0 += lrelu_combine(xl[0], dv[0], dot, dsq);
    acc1 += lrelu_combine(xl[1], dv[1], dot, dsq);
    acc2 += lrelu_combine(xl[2], dv[2], dot, dsq);
  }
  size_t r0 = (size_t)((b * 64 + c) * 3) * N;
  out[r0 + n] = acc0 * (1.f / 16.f);
  out[r0 + N + n] = acc1 * (1.f / 16.f);
  out[r0 + 2 * (size_t)N + n] = acc2 * (1.f / 16.f);
}

// ---------------- Qx finisher: lrelu + chnorm (pm in, pm out) ----------------
__global__ void __launch_bounds__(256) k_qfin(const float* __restrict__ XL, const float* __restrict__ DV,
                                              float* __restrict__ outpm, int N) {
  int tid = threadIdx.x;
  int p = blockIdx.x * 4 + (tid >> 6);
  int c = tid & 63;
  int b = p / N, n = p - b * N;
  size_t bn = ((size_t)(b * N + n) * 3) * 64 + c;
  float xl[3], dv[3];
#pragma unroll
  for (int d = 0; d < 3; ++d) { xl[d] = XL[bn + d * 64]; dv[d] = DV[bn + d * 64]; }
  float dot = xl[0] * dv[0] + xl[1] * dv[1] + xl[2] * dv[2];
  float dsq = dv[0] * dv[0] + dv[1] * dv[1] + dv[2] * dv[2];
  float z[3];
#pragma unroll
  for (int d = 0; d < 3; ++d) z[d] = lrelu_combine(xl[d], dv[d], dot, dsq);
  float n2 = z[0] * z[0] + z[1] * z[1] + z[2] * z[2];
  float cn2 = n2;
#pragma unroll
  for (int s = 1; s < 64; s <<= 1) cn2 += __shfl_xor(cn2, s, 64);
  float n_o = sqrtf(n2), cn = sqrtf(cn2);
  float scl = (n_o / fmaxf(cn, EPSV)) / fmaxf(n_o, EPSV);
#pragma unroll
  for (int d = 0; d < 3; ++d) outpm[bn + d * 64] = z[d] * scl;
}

// ---------------- fused K-logits + softmax + V-attention + residual (wave per point) ----------------
__global__ void __launch_bounds__(256) k_att(const float* __restrict__ xres,
                                             const float* __restrict__ qxpm,
                                             const float* __restrict__ KP1, const float* __restrict__ KP2,
                                             const float* __restrict__ KD1, const float* __restrict__ KD2,
                                             const float* __restrict__ VP1, const float* __restrict__ VP2,
                                             const float* __restrict__ VD1, const float* __restrict__ VD2,
                                             const int* __restrict__ idx,
                                             float* __restrict__ out, int N) {
  int tid = threadIdx.x;
  int p = blockIdx.x * 4 + (tid >> 6);
  int c = tid & 63;
  int b = p / N, n = p - b * N;
  size_t bn = ((size_t)(b * N + n) * 3) * 64 + c;
  float qv[3], kp2[3], kd2[3], vp2[3], vd2[3];
#pragma unroll
  for (int d = 0; d < 3; ++d) {
    qv[d] = qxpm[bn + d * 64];
    kp2[d] = KP2[bn + d * 64];
    kd2[d] = KD2[bn + d * 64];
    vp2[d] = VP2[bn + d * 64];
    vd2[d] = VD2[bn + d * 64];
  }
  const int* ip = idx + ((size_t)b * N + n) * 16;
  float l[16];
#pragma unroll
  for (int j = 0; j < 16; ++j) {
    int m = ip[j];
    size_t bm = ((size_t)(b * N + m) * 3) * 64 + c;
    float xl[3], dv[3];
#pragma unroll
    for (int d = 0; d < 3; ++d) {
      xl[d] = KP1[bm + d * 64] + kp2[d];
      dv[d] = KD1[bm + d * 64] + kd2[d];
    }
    float dot = xl[0] * dv[0] + xl[1] * dv[1] + xl[2] * dv[2];
    float dsq = dv[0] * dv[0] + dv[1] * dv[1] + dv[2] * dv[2];
    float z[3];
#pragma unroll
    for (int d = 0; d < 3; ++d) z[d] = lrelu_combine(xl[d], dv[d], dot, dsq);
    float n2 = z[0] * z[0] + z[1] * z[1] + z[2] * z[2];
    float cn2 = n2;
#pragma unroll
    for (int s = 1; s < 64; s <<= 1) cn2 += __shfl_xor(cn2, s, 64);
    float n_o = sqrtf(n2), cn = sqrtf(cn2);
    float scl = (n_o / fmaxf(cn, EPSV)) / fmaxf(n_o, EPSV);
    float part = (z[0] * qv[0] + z[1] * qv[1] + z[2] * qv[2]) * scl;
#pragma unroll
    for (int s = 1; s < 32; s <<= 1) part += __shfl_xor(part, s, 32);
    part = __shfl(part, 0, 32);
    l[j] = part * 0.102062072615966f;  // 1/sqrt(96)
  }
  float mx = l[0];
#pragma unroll
  for (int j = 1; j < 16; ++j) mx = fmaxf(mx, l[j]);
  float sum = 0.f;
#pragma unroll
  for (int j = 0; j < 16; ++j) { l[j] = expf(l[j] - mx); sum += l[j]; }
  float inv = 1.f / sum;
#pragma unroll
  for (int j = 0; j < 16; ++j) l[j] *= inv;
  float acc0 = 0.f, acc1 = 0.f, acc2 = 0.f;
#pragma unroll
  for (int j = 0; j < 16; ++j) {
    int m = ip[j];
    float av = l[j];
    size_t bm = ((size_t)(b * N + m) * 3) * 64 + c;
    float xl[3], dv[3];
#pragma unroll
    for (int d = 0; d < 3; ++d) {
      xl[d] = VP1[bm + d * 64] + vp2[d];
      dv[d] = VD1[bm + d * 64] + vd2[d];
    }
    float dot = xl[0] * dv[0] + xl[1] * dv[1] + xl[2] * dv[2];
    float dsq = dv[0] * dv[0] + dv[1] * dv[1] + dv[2] * dv[2];
    acc0 = fmaf(av, lrelu_combine(xl[0], dv[0], dot, dsq), acc0);
    acc1 = fmaf(av, lrelu_combine(xl[1], dv[1], dot, dsq), acc1);
    acc2 = fmaf(av, lrelu_combine(xl[2], dv[2], dot, dsq), acc2);
  }
  size_t r0 = (size_t)((b * 64 + c) * 3) * N;
  out[r0 + n] = xres[r0 + n] + acc0;
  out[r0 + N + n] = xres[r0 + N + n] + acc1;
  out[r0 + 2 * (size_t)N + n] = xres[r0 + 2 * (size_t)N + n] + acc2;
}

// ---------------- g-fuse finisher: wave per point, side = blockIdx.y ----------------
__global__ void __launch_bounds__(256) k_gfin(const float* __restrict__ XLa, const float* __restrict__ DVa,
                                              const float* __restrict__ XLb, const float* __restrict__ DVb,
                                              float* __restrict__ outa, float* __restrict__ outpa,
                                              float* __restrict__ outb, float* __restrict__ outpb, int N) {
  int side = blockIdx.y;
  const float* XL = side ? XLb : XLa;
  const float* DV = side ? DVb : DVa;
  float* out = side ? outb : outa;
  float* outpm = side ? outpb : outpa;
  int tid = threadIdx.x;
  int p = blockIdx.x * 4 + (tid >> 6);
  int c = tid & 63;
  int b = p / N, n = p - b * N;
  size_t bn = ((size_t)(b * N + n) * 3) * 64 + c;
  float xl[3], dv[3];
#pragma unroll
  for (int d = 0; d < 3; ++d) { xl[d] = XL[bn + d * 64]; dv[d] = DV[bn + d * 64]; }
  float dot = xl[0] * dv[0] + xl[1] * dv[1] + xl[2] * dv[2];
  float dsq = dv[0] * dv[0] + dv[1] * dv[1] + dv[2] * dv[2];
  size_t r0 = (size_t)((b * 64 + c) * 3) * N;
#pragma unroll
  for (int d = 0; d < 3; ++d) {
    float z = lrelu_combine(xl[d], dv[d], dot, dsq);
    out[r0 + (size_t)d * N + n] = z;
    outpm[bn + d * 64] = z;
  }
}

// ---------------- bias for g-fuse, both sides in one launch ----------------
__global__ void k_gbias2(const float* __restrict__ gw, const float* __restrict__ meanX,
                         const float* __restrict__ meanY,
                         float* __restrict__ cbX, float* __restrict__ cbY) {
  int b = blockIdx.x, which = blockIdx.y, tid = threadIdx.x;  // 192 threads
  int o = tid / 3, d = tid - o * 3;
  const float* mb = (which ? meanY : meanX) + b * 192;
  float* cb = (which ? cbY : cbX);
  float s = 0.f;
  for (int c = 0; c < 64; ++c) s = fmaf(gw[o * 128 + 64 + c], mb[c * 3 + d], s);
  cb[b * 192 + tid] = s;
}

// ---------------- column mean over N for both arrays in one launch ----------------
__global__ void k_cmean2(const float* __restrict__ x1, const float* __restrict__ x2,
                         float* __restrict__ o1, float* __restrict__ o2,
                         int N, int ostride, int obase, float inv) {
  __shared__ float red[256];
  int b = blockIdx.y, cd = blockIdx.x, which = blockIdx.z, tid = threadIdx.x;
  const float* x = which ? x2 : x1;
  float* out = which ? o2 : o1;
  const float* p = x + ((size_t)b * 192 + cd) * N;
  float s = 0.f;
  for (int i = tid; i < N; i += 256) s += p[i];
  red[tid] = s;
  __syncthreads();
  for (int st = 128; st > 0; st >>= 1) {
    if (tid < st) red[tid] += red[tid + st];
    __syncthreads();
  }
  if (tid == 0) out[(size_t)b * ostride + obase + cd] = red[0] * inv;
}

// ---------------- channel-mean (fx_par pre-normalization) for both arrays ----------------
__global__ void k_parmean(const float* __restrict__ fx, const float* __restrict__ fy,
                          float* __restrict__ px, float* __restrict__ py, int N, int B) {
  int gi = blockIdx.x * 256 + threadIdx.x;
  int total = B * 3 * N;
  if (gi >= total) return;
  int b = gi / (3 * N);
  int r = gi - b * 3 * N;
  const float* fxb = fx + (size_t)b * 192 * N + r;
  const float* fyb = fy + (size_t)b * 192 * N + r;
  float sx = 0.f, sy = 0.f;
  for (int c = 0; c < 64; ++c) { sx += fxb[(size_t)c * 3 * N]; sy += fyb[(size_t)c * 3 * N]; }
  px[gi] = sx * (1.f / 64.f);
  py[gi] = sy * (1.f / 64.f);
}

// ---------------- score logits: sum_c (fx.px)(fy.py) (softmax+norm skipped: monotone) ----------------
__global__ void k_dotphi(const float* __restrict__ fx, const float* __restrict__ fy,
                         const float* __restrict__ px, const float* __restrict__ py,
                         float* __restrict__ dps, int N, int B) {
  int gi = blockIdx.x * 256 + threadIdx.x;
  if (gi >= B * N) return;
  int b = gi / N, n = gi - b * N;
  const float* fxb = fx + (size_t)b * 192 * N + n;
  const float* fyb = fy + (size_t)b * 192 * N + n;
  const float* pxb = px + (size_t)b * 3 * N + n;
  const float* pyb = py + (size_t)b * 3 * N + n;
  float acc = 0.f;
  for (int c = 0; c < 64; ++c) {
    float ax = 0.f, ay = 0.f;
    for (int d = 0; d < 3; ++d) {
      ax = fmaf(fxb[(size_t)(c * 3 + d) * N], pxb[(size_t)d * N], ax);
      ay = fmaf(fyb[(size_t)(c * 3 + d) * N], pyb[(size_t)d * N], ay);
    }
    acc = fmaf(ax, ay, acc);
  }
  dps[gi] = acc;
}

// ---------------- top-N/2 selection: bitonic sort (desc value, asc index) ----------------
__global__ void __launch_bounds__(1024) k_topsel(const float* __restrict__ dps,
                                                 int* __restrict__ sel, int N, int Nh) {
  __shared__ float kv[2048];
  __shared__ int ki[2048];
  int b = blockIdx.x, tid = threadIdx.x;
  for (int i = tid; i < N; i += 1024) { kv[i] = dps[b * N + i]; ki[i] = i; }
  __syncthreads();
  for (int kk = 2; kk <= N; kk <<= 1) {
    for (int jj = kk >> 1; jj > 0; jj >>= 1) {
      for (int i = tid; i < N; i += 1024) {
        int ixj = i ^ jj;
        if (ixj > i) {
          float va = kv[i], vb = kv[ixj];
          int ia = ki[i], ib = ki[ixj];
          bool aFirst = (va > vb) || (va == vb && ia < ib);
          bool up = ((i & kk) == 0);
          bool doswap = up ? (!aFirst) : aFirst;
          if (doswap) { kv[i] = vb; kv[ixj] = va; ki[i] = ib; ki[ixj] = ia; }
        }
      }
      __syncthreads();
    }
  }
  for (int i = tid; i < Nh; i += 1024) sel[b * Nh + i] = ki[i];
}

// ---------------- gather selected points (pm source, cm dest), wave per point ----------------
__global__ void __launch_bounds__(256) k_gather(const float* __restrict__ sxpm, const float* __restrict__ sypm,
                                                const int* __restrict__ sel,
                                                float* __restrict__ dx, float* __restrict__ dy,
                                                int N, int Nh) {
  int tid = threadIdx.x;
  int p = blockIdx.x * 4 + (tid >> 6);
  int c = tid & 63;
  int b = p / Nh, i = p - b * Nh;
  int s = sel[b * Nh + i];
  size_t bs = ((size_t)(b * N + s) * 3) * 64 + c;
  size_t r0 = (size_t)((b * 64 + c) * 3) * Nh;
#pragma unroll
  for (int d = 0; d < 3; ++d) {
    dx[r0 + (size_t)d * Nh + i] = sxpm[bs + d * 64];
    dy[r0 + (size_t)d * Nh + i] = sypm[bs + d * 64];
  }
}

// ---------------- final head: vn_lin_lrelu(concat blocks, h_w, h_d) ----------------
__global__ void k_head(const float* __restrict__ blkX, const float* __restrict__ blkY,
                       const float* __restrict__ hw, const float* __restrict__ hd,
                       float* __restrict__ Fx, float* __restrict__ Fy) {
  __shared__ float f[3][128];
  __shared__ float xl[3][32];
  __shared__ float dv[3][32];
  int which = blockIdx.x, b = blockIdx.y, tid = threadIdx.x;
  const float* blk = which ? blkY : blkX;
  float* F = which ? Fy : Fx;
  int o = tid & 31, dd = tid >> 5;
  for (int i = tid; i < 384; i += 96) f[i % 3][i / 3] = blk[(size_t)b * 384 + i];
  __syncthreads();
  float s = 0.f;
  for (int c = 0; c < 128; ++c) s = fmaf(hw[o * 128 + c], f[dd][c], s);
  xl[dd][o] = s;
  __syncthreads();
  float s2 = 0.f;
  for (int p = 0; p < 32; ++p) s2 = fmaf(hd[o * 32 + p], xl[dd][p], s2);
  dv[dd][o] = s2;
  __syncthreads();
  float dot = xl[0][o] * dv[0][o] + xl[1][o] * dv[1][o] + xl[2][o] * dv[2][o];
  float dsq = dv[0][o] * dv[0][o] + dv[1][o] * dv[1][o] + dv[2][o] * dv[2][o];
  F[((size_t)b * 32 + o) * 3 + dd] = lrelu_combine(xl[dd][o], dv[dd][o], dot, dsq);
}

// ================== LAPACK-faithful 3x3 SVD (dgesdd path: dgebrd + dbdsqr) ==================
#define DEPS 2.220446049250313e-16
#define DUNFL 2.2250738585072014e-308

static __device__ void dlartg_(double f, double g, double* cs, double* sn, double* r) {
  if (g == 0.0) { *cs = 1.0; *sn = 0.0; *r = f; }
  else if (f == 0.0) { *cs = 0.0; *sn = copysign(1.0, g); *r = fabs(g); }
  else {
    double d = sqrt(f * f + g * g);
    double c = fabs(f) / d;
    double rr = copysign(d, f);
    *cs = c; *r = rr; *sn = g / rr;
  }
}

static __device__ void dlas2_(double f, double g, double h, double* ssmin, double* ssmax) {
  double fa = fabs(f), ga = fabs(g), ha = fabs(h);
  double fhmn = fmin(fa, ha), fhmx = fmax(fa, ha);
  if (fhmn == 0.0) {
    *ssmin = 0.0;
    if (fhmx == 0.0) *ssmax = ga;
    else { double mx = fmax(fhmx, ga), mn = fmin(fhmx, ga); double q = mn / mx; *ssmax = mx * sqrt(1.0 + q * q); }
  } else {
    if (ga < fhmx) {
      double as_ = 1.0 + fhmn / fhmx;
      double at = (fhmx - fhmn) / fhmx;
      double au = ga / fhmx; au = au * au;
      double c = 2.0 / (sqrt(as_ * as_ + au) + sqrt(at * at + au));
      *ssmin = fhmn * c; *ssmax = fhmx / c;
    } else {
      double au = fhmx / ga;
      if (au == 0.0) { *ssmin = (fhmn * fhmx) / ga; *ssmax = ga; }
      else {
        double as_ = 1.0 + fhmn / fhmx;
        double at = (fhmx - fhmn) / fhmx;
        double t1 = as_ * au, t2 = at * au;
        double c = 1.0 / (sqrt(1.0 + t1 * t1) + sqrt(1.0 + t2 * t2));
        double sm = (fhmn * c) * au; *ssmin = sm + sm;
        *ssmax = ga / (c + c);
      }
    }
  }
}

static __device__ void dlasv2_(double f, double g, double h,
                               double* ssmin, double* ssmax,
                               double* snr, double* csr, double* snl, double* csl) {
  double ft = f, fa = fabs(f), ht = h, ha = fabs(h);
  int pmax = 1;
  bool swp = (ha > fa);
  if (swp) { pmax = 3; double t = ft; ft = ht; ht = t; t = fa; fa = ha; ha = t; }
  double gt = g, ga = fabs(g);
  double clt = 0, crt = 0, slt = 0, srt = 0;
  if (ga == 0.0) {
    *ssmin = ha; *ssmax = fa; clt = 1.0; crt = 1.0; slt = 0.0; srt = 0.0;
  } else {
    bool gasmal = true;
    if (ga > fa) {
      pmax = 2;
      if ((fa / ga) < DEPS) {
        gasmal = false;
        *ssmax = ga;
        *ssmin = (ha > 1.0) ? (fa / (ga / ha)) : ((fa / ga) * ha);
        clt = 1.0; slt = ht / gt; srt = 1.0; crt = ft / gt;
      }
    }
    if (gasmal) {
      double dd = fa - ha;
      double l = (dd == fa) ? 1.0 : (dd / fa);
      double mq = gt / ft;
      double t = 2.0 - l;
      double mm = mq * mq, tt = t * t;
      double s = sqrt(tt + mm);
      double r = (l == 0.0) ? fabs(mq) : sqrt(l * l + mm);
      double a = 0.5 * (s + r);
      *ssmin = ha / a;
      *ssmax = fa * a;
      if (mm == 0.0) {
        if (l == 0.0) t = copysign(2.0, ft) * copysign(1.0, gt);
        else t = gt / copysign(dd, ft) + mq / t;
      } else {
        t = (mq / (s + t) + mq / (r + l)) * (1.0 + a);
      }
      double l2 = sqrt(t * t + 4.0);
      crt = 2.0 / l2;
      srt = t / l2;
      clt = (crt + srt * mq) / a;
      slt = (ht / ft) * srt / a;
    }
  }
  if (swp) { *csl = srt; *snl = crt; *csr = slt; *snr = clt; }
  else { *csl = clt; *snl = slt; *csr = crt; *snr = srt; }
  double tsign = 0.0;
  if (pmax == 1) tsign = copysign(1.0, *csr) * copysign(1.0, *csl) * copysign(1.0, f);
  if (pmax == 2) tsign = copysign(1.0, *snr) * copysign(1.0, *csl) * copysign(1.0, g);
  if (pmax == 3) tsign = copysign(1.0, *snr) * copysign(1.0, *snl) * copysign(1.0, h);
  *ssmax = copysign(*ssmax, tsign);
  *ssmin = copysign(*ssmin, tsign * copysign(1.0, f) * copysign(1.0, h));
}

static __device__ void dbdsqr3(double d[3], double e[2], double VT[3][3], double U[3][3]) {
  const int n = 3;
  double tolmul = fmax(10.0, fmin(100.0, pow(DEPS, -0.125)));
  double tol = tolmul * DEPS;
  double thresh;
  {
    double sminoa = fabs(d[0]);
    if (sminoa != 0.0) {
      double mu = sminoa;
      for (int i = 1; i < n; ++i) {
        mu = fabs(d[i]) * (mu / (mu + fabs(e[i - 1])));
        sminoa = fmin(sminoa, mu);
        if (sminoa == 0.0) break;
      }
    }
    sminoa = sminoa / sqrt((double)n);
    thresh = fmax(tol * sminoa, 6.0 * n * n * DUNFL);
  }
  int maxit = 6 * n * n;
  int iter = 0, oldll = -1, oldm = -1, idir = 0;
  int m = n;
  double sminl = 0.0;
  int guard = 0;
  while (true) {
    if (m <= 1) break;
    if (iter > maxit) break;
    if (++guard > 500) break;
    double smaxb = fabs(d[m - 1]);
    int ll = 0; bool found = false;
    for (int lll = 1; lll <= m - 1; ++lll) {
      int l = m - lll;
      double abss = fabs(d[l - 1]);
      double abse = fabs(e[l - 1]);
      if (abse <= thresh) { ll = l; found = true; break; }
      smaxb = fmax(smaxb, fmax(abss, abse));
    }
    if (found) {
      e[ll - 1] = 0.0;
      if (ll == m - 1) { m = m - 1; continue; }
      ll = ll + 1;
    } else ll = 1;
    if (ll == m - 1) {
      double sigmn, sigmx, sinr, cosr, sinl2, cosl2;
      dlasv2_(d[m - 2], e[m - 2], d[m - 1], &sigmn, &sigmx, &sinr, &cosr, &sinl2, &cosl2);
      d[m - 2] = sigmx; d[m - 1] = sigmn; e[m - 2] = 0.0;
      for (int j = 0; j < 3; ++j) {
        double t1 = VT[m - 2][j], t2 = VT[m - 1][j];
        VT[m - 2][j] = cosr * t1 + sinr * t2;
        VT[m - 1][j] = cosr * t2 - sinr * t1;
      }
      for (int i2 = 0; i2 < 3; ++i2) {
        double t1 = U[i2][m - 2], t2 = U[i2][m - 1];
        U[i2][m - 2] = cosl2 * t1 + sinl2 * t2;
        U[i2][m - 1] = cosl2 * t2 - sinl2 * t1;
      }
      m -= 2;
      continue;
    }
    if (ll > oldm || m < oldll)
      idir = (fabs(d[ll - 1]) >= fabs(d[m - 1])) ? 1 : 2;
    if (idir == 1) {
      if (fabs(e[m - 2]) <= tol * fabs(d[m - 1])) { e[m - 2] = 0.0; continue; }
      double mu = fabs(d[ll - 1]); sminl = mu;
      bool conv = true;
      for (int lll = ll; lll <= m - 1; ++lll) {
        if (fabs(e[lll - 1]) > tol * mu) { conv = false; break; }
        mu = fabs(d[lll]) * (mu / (mu + fabs(e[lll - 1])));
        sminl = fmin(sminl, mu);
      }
      if (conv) { e[m - 2] = 0.0; continue; }
    } else {
      if (fabs(e[ll - 1]) <= tol * fabs(d[ll - 1])) { e[ll - 1] = 0.0; continue; }
      double mu = fabs(d[m - 1]); sminl = mu;
      bool conv = true;
      for (int lll = m - 1; lll >= ll; --lll) {
        if (fabs(e[lll - 1]) > tol * mu) { conv = false; break; }
        mu = fabs(d[lll - 1]) * (mu / (mu + fabs(e[lll - 1])));
        sminl = fmin(sminl, mu);
      }
      if (conv) { e[ll - 1] = 0.0; continue; }
    }
    oldll = ll; oldm = m;
    double shift = 0.0, rr;
    if (!(n * tol * (sminl / smaxb) <= fmax(DEPS, 0.01 * tol))) {
      double sll;
      if (idir == 1) { sll = fabs(d[ll - 1]); dlas2_(d[m - 2], e[m - 2], d[m - 1], &shift, &rr); }
      else { sll = fabs(d[m - 1]); dlas2_(d[ll - 1], e[ll - 1], d[ll], &shift, &rr); }
      if (sll > 0.0) { double q = shift / sll; if (q * q < DEPS) shift = 0.0; }
    }
    iter += m - ll;
    double csv[2], snv[2], ocsv[2], osnv[2];
    int cnt = 0;
    if (shift == 0.0) {
      if (idir == 1) {
        double cs = 1.0, oldcs = 1.0, sn = 0.0, oldsn = 0.0, r;
        for (int i = ll; i <= m - 1; ++i) {
          dlartg_(d[i - 1] * cs, e[i - 1], &cs, &sn, &r);
          if (i > ll) e[i - 2] = oldsn * r;
          dlartg_(oldcs * r, d[i] * sn, &oldcs, &oldsn, &d[i - 1]);
          csv[cnt] = cs; snv[cnt] = sn; ocsv[cnt] = oldcs; osnv[cnt] = oldsn; cnt++;
        }
        double hh = d[m - 1] * cs;
        d[m - 1] = hh * oldcs;
        e[m - 2] = hh * oldsn;
        for (int k = 0; k < cnt; ++k) {
          int r0 = ll - 1 + k, r1 = r0 + 1;
          for (int j = 0; j < 3; ++j) {
            double t1 = VT[r0][j], t2 = VT[r1][j];
            VT[r0][j] = snv[k] * t2 + csv[k] * t1;
            VT[r1][j] = csv[k] * t2 - snv[k] * t1;
          }
        }
        for (int k = 0; k < cnt; ++k) {
          int c0 = ll - 1 + k, c1 = c0 + 1;
          for (int i2 = 0; i2 < 3; ++i2) {
            double t1 = U[i2][c0], t2 = U[i2][c1];
            U[i2][c0] = osnv[k] * t2 + ocsv[k] * t1;
            U[i2][c1] = ocsv[k] * t2 - osnv[k] * t1;
          }
        }
        if (fabs(e[m - 2]) <= thresh) e[m - 2] = 0.0;
      } else {
        double cs = 1.0, oldcs = 1.0, sn = 0.0, oldsn = 0.0, r;
        for (int i = m; i >= ll + 1; --i) {
          dlartg_(d[i - 1] * cs, e[i - 2], &cs, &sn, &r);
          if (i < m) e[i - 1] = oldsn * r;
          dlartg_(oldcs * r, d[i - 2] * sn, &oldcs, &oldsn, &d[i - 1]);
          int k = i - ll - 1;
          csv[k] = cs; snv[k] = -sn; ocsv[k] = oldcs; osnv[k] = -oldsn; cnt++;
        }
        double hh = d[ll - 1] * cs;
        d[ll - 1] = hh * oldcs;
        e[ll - 1] = hh * oldsn;
        for (int k = cnt - 1; k >= 0; --k) {
          int r0 = ll - 1 + k, r1 = r0 + 1;
          for (int j = 0; j < 3; ++j) {
            double t1 = VT[r0][j], t2 = VT[r1][j];
            VT[r0][j] = osnv[k] * t2 + ocsv[k] * t1;
            VT[r1][j] = ocsv[k] * t2 - osnv[k] * t1;
          }
        }
        for (int k = cnt - 1; k >= 0; --k) {
          int c0 = ll - 1 + k, c1 = c0 + 1;
          for (int i2 = 0; i2 < 3; ++i2) {
            double t1 = U[i2][c0], t2 = U[i2][c1];
            U[i2][c0] = snv[k] * t2 + csv[k] * t1;
            U[i2][c1] = csv[k] * t2 - snv[k] * t1;
          }
        }
        if (fabs(e[ll - 1]) <= thresh) e[ll - 1] = 0.0;
      }
    } else {
      if (idir == 1) {
        double f = (fabs(d[ll - 1]) - shift) * (copysign(1.0, d[ll - 1]) + shift / d[ll - 1]);
        double g = e[ll - 1];
        double cosr, sinr, cosl2, sinl2, r;
        for (int i = ll; i <= m - 1; ++i) {
          dlartg_(f, g, &cosr, &sinr, &r);
          if (i > ll) e[i - 2] = r;
          f = cosr * d[i - 1] + sinr * e[i - 1];
          e[i - 1] = cosr * e[i - 1] - sinr * d[i - 1];
          g = sinr * d[i];
          d[i] = cosr * d[i];
          dlartg_(f, g, &cosl2, &sinl2, &r);
          d[i - 1] = r;
          f = cosl2 * e[i - 1] + sinl2 * d[i];
          d[i] = cosl2 * d[i] - sinl2 * e[i - 1];
          if (i < m - 1) {
            g = sinl2 * e[i];
            e[i] = cosl2 * e[i];
          }
          csv[cnt] = cosr; snv[cnt] = sinr; ocsv[cnt] = cosl2; osnv[cnt] = sinl2; cnt++;
        }
        e[m - 2] = f;
        for (int k = 0; k < cnt; ++k) {
          int r0 = ll - 1 + k, r1 = r0 + 1;
          for (int j = 0; j < 3; ++j) {
            double t1 = VT[r0][j], t2 = VT[r1][j];
            VT[r0][j] = snv[k] * t2 + csv[k] * t1;
            VT[r1][j] = csv[k] * t2 - snv[k] * t1;
          }
        }
        for (int k = 0; k < cnt; ++k) {
          int c0 = ll - 1 + k, c1 = c0 + 1;
          for (int i2 = 0; i2 < 3; ++i2) {
            double t1 = U[i2][c0], t2 = U[i2][c1];
            U[i2][c0] = osnv[k] * t2 + ocsv[k] * t1;
            U[i2][c1] = ocsv[k] * t2 - osnv[k] * t1;
          }
        }
        if (fabs(e[m - 2]) <= thresh) e[m - 2] = 0.0;
      } else {
        double f = (fabs(d[m - 1]) - shift) * (copysign(1.0, d[m - 1]) + shift / d[m - 1]);
        double g = e[m - 2];
        for (int i = m; i >= ll + 1; --i) {
          double cosr, sinr, cosl2, sinl2, r;
          dlartg_(f, g, &cosr, &sinr, &r);
          if (i < m) e[i - 1] = r;
          f = cosr * d[i - 1] + sinr * e[i - 2];
          e[i - 2] = cosr * e[i - 2] - sinr * d[i - 1];
          g = sinr * d[i - 2];
          d[i - 2] = cosr * d[i - 2];
          dlartg_(f, g, &cosl2, &sinl2, &r);
          d[i - 1] = r;
          f = cosl2 * e[i - 2] + sinl2 * d[i - 2];
          d[i - 2] = cosl2 * d[i - 2] - sinl2 * e[i - 2];
          if (i > ll + 1) {
            g = sinl2 * e[i - 3];
            e[i - 3] = cosl2 * e[i - 3];
          }
          int k = i - ll - 1;
          ocsv[k] = cosl2; osnv[k] = -sinl2; csv[k] = cosr; snv[k] = -sinr; cnt++;
        }
        e[ll - 1] = f;
        for (int k = cnt - 1; k >= 0; --k) {
          int r0 = ll - 1 + k, r1 = r0 + 1;
          for (int j = 0; j < 3; ++j) {
            double t1 = VT[r0][j], t2 = VT[r1][j];
            VT[r0][j] = snv[k] * t2 + csv[k] * t1;
            VT[r1][j] = csv[k] * t2 - snv[k] * t1;
          }
        }
        for (int k = cnt - 1; k >= 0; --k) {
          int c0 = ll - 1 + k, c1 = c0 + 1;
          for (int i2 = 0; i2 < 3; ++i2) {
            double t1 = U[i2][c0], t2 = U[i2][c1];
            U[i2][c0] = osnv[k] * t2 + ocsv[k] * t1;
            U[i2][c1] = ocsv[k] * t2 - osnv[k] * t1;
          }
        }
        if (fabs(e[ll - 1]) <= thresh) e[ll - 1] = 0.0;
      }
    }
  }
  for (int i = 0; i < n; ++i)
    if (d[i] < 0.0) { d[i] = -d[i]; for (int j = 0; j < 3; ++j) VT[i][j] = -VT[i][j]; }
  for (int i = 1; i <= n - 1; ++i) {
    int isub = 1; double smn = d[0];
    for (int j = 2; j <= n + 1 - i; ++j)
      if (d[j - 1] <= smn) { isub = j; smn = d[j - 1]; }
    if (isub != n + 1 - i) {
      int a = isub - 1, b2 = n - i;
      double t = d[a]; d[a] = d[b2]; d[b2] = t;
      for (int j = 0; j < 3; ++j) { t = VT[a][j]; VT[a][j] = VT[b2][j]; VT[b2][j] = t; }
      for (int j = 0; j < 3; ++j) { t = U[j][a]; U[j][a] = U[j][b2]; U[j][b2] = t; }
    }
  }
}

__global__ void k_svd(const float* __restrict__ Fx, const float* __restrict__ Fy,
                      float* __restrict__ out, int B) {
  int b = blockIdx.x;
  if (threadIdx.x != 0) return;
  double A[3][3];
  for (int d = 0; d < 3; ++d)
    for (int e = 0; e < 3; ++e) {
      double s = 0.0;
      for (int c = 0; c < 32; ++c)
        s += (double)Fx[((size_t)b * 32 + c) * 3 + d] * (double)Fy[((size_t)b * 32 + c) * 3 + e];
      A[d][e] = s;
    }
  double dg[3], eg[2], tauq0, tauq1, taup0;
  double v1_1 = 0, v1_2 = 0, v2_1 = 0, w1 = 0;
  {
    double alpha = A[0][0];
    double xn = sqrt(A[1][0] * A[1][0] + A[2][0] * A[2][0]);
    if (xn == 0.0) { tauq0 = 0.0; dg[0] = alpha; }
    else {
      double beta = -copysign(sqrt(alpha * alpha + xn * xn), alpha);
      tauq0 = (beta - alpha) / beta;
      double scal = 1.0 / (alpha - beta);
      v1_1 = A[1][0] * scal; v1_2 = A[2][0] * scal;
      dg[0] = beta;
    }
    for (int j = 1; j < 3; ++j) {
      double w = A[0][j] + v1_1 * A[1][j] + v1_2 * A[2][j];
      w *= tauq0;
      A[0][j] -= w; A[1][j] -= w * v1_1; A[2][j] -= w * v1_2;
    }
  }
  {
    double alpha = A[0][1];
    double xn = fabs(A[0][2]);
    if (xn == 0.0) { taup0 = 0.0; eg[0] = alpha; }
    else {
      double beta = -copysign(sqrt(alpha * alpha + xn * xn), alpha);
      taup0 = (beta - alpha) / beta;
      w1 = A[0][2] / (alpha - beta);
      eg[0] = beta;
    }
    for (int i = 1; i < 3; ++i) {
      double t = A[i][1] + w1 * A[i][2];
      t *= taup0;
      A[i][1] -= t; A[i][2] -= t * w1;
    }
  }
  {
    double alpha = A[1][1];
    double xn = fabs(A[2][1]);
    if (xn == 0.0) { tauq1 = 0.0; dg[1] = alpha; }
    else {
      double beta = -copysign(sqrt(alpha * alpha + xn * xn), alpha);
      tauq1 = (beta - alpha) / beta;
      v2_1 = A[2][1] / (alpha - beta);
      dg[1] = beta;
    }
    double w = A[1][2] + v2_1 * A[2][2];
    w *= tauq1;
    A[1][2] -= w; A[2][2] -= w * v2_1;
  }
  eg[1] = A[1][2];
  dg[2] = A[2][2];
  double U[3][3] = {{1, 0, 0}, {0, 1, 0}, {0, 0, 1}};
  double VT[3][3] = {{1, 0, 0}, {0, 1, 0}, {0, 0, 1}};
  dbdsqr3(dg, eg, VT, U);
  for (int j = 0; j < 3; ++j) {
    double w = U[1][j] + v2_1 * U[2][j];
    w *= tauq1;
    U[1][j] -= w; U[2][j] -= w * v2_1;
  }
  for (int j = 0; j < 3; ++j) {
    double w = U[0][j] + v1_1 * U[1][j] + v1_2 * U[2][j];
    w *= tauq0;
    U[0][j] -= w; U[1][j] -= w * v1_1; U[2][j] -= w * v1_2;
  }
  for (int r = 0; r < 3; ++r) {
    double t = VT[r][1] + w1 * VT[r][2];
    t *= taup0;
    VT[r][1] -= t; VT[r][2] -= t * w1;
  }
  for (int i = 0; i < 3; ++i)
    for (int j = 0; j < 3; ++j) {
      double r = 0;
      for (int k = 0; k < 3; ++k) r += U[i][k] * VT[j][k];
      out[b * 9 + i * 3 + j] = (float)r;
    }
  for (int dd = 0; dd < 3; ++dd) {
    float sx = 0.f, sy = 0.f;
    for (int c = 0; c < 32; ++c) {
      float vx = Fx[((size_t)b * 32 + c) * 3 + dd];
      float vy = Fy[((size_t)b * 32 + c) * 3 + dd];
      sx = fmaf(vx, vx, sx);
      sy = fmaf(vy, vy, sy);
    }
    out[B * 9 + b * 3 + dd] = sqrtf(sy) / sqrtf(sx);
  }
}

extern "C" void kernel_launch(void* const* d_in, const int* in_sizes, int n_in,
                              void* d_out, int out_size, void* d_ws, size_t ws_size,
                              hipStream_t stream) {
  (void)in_sizes; (void)n_in; (void)out_size; (void)ws_size;
  const int B = 2, N0 = 2048;
  const float* W[24];
  for (int i = 0; i < 24; ++i) W[i] = (const float*)d_in[i];

  float* ws = (float*)d_ws;
  const size_t P = (size_t)B * 64 * 3 * 2048;  // 786432 floats
  float* bufA = ws;
  float* bufB = bufA + P;
  float* bufC = bufB + P;
  float* bufD = bufC + P;
  float* bufApm = bufD + P;
  float* bufBpm = bufApm + P;
  float* qxpm = bufBpm + P;
  float* C1 = qxpm + P;
  float* C2 = C1 + P;
  float* C3 = C2 + P;
  float* C4 = C3 + P;
  float* C5 = C4 + P;
  float* M1 = C5 + P;
  float* M2 = M1 + P;
  float* M3 = M2 + P;
  float* M4 = M3 + P;
  float* M5 = M4 + P;
  float* M6 = M5 + P;
  float* M7 = M6 + P;
  float* M8 = M7 + P;
  float* M9 = M8 + P;
  float* M10 = M9 + P;
  float* px = M10 + P;               // B*3*2048 = 12288
  float* py = px + 12288;
  float* dps = py + 12288;           // 4096
  float* xx0 = dps + 4096;           // 4096
  float* xx1 = xx0 + 4096;           // 4096
  float* meanX = xx1 + 4096;         // 384
  float* meanY = meanX + 384;
  float* cbX = meanY + 384;
  float* cbY = cbX + 384;
  float* blkX = cbY + 384;           // 768
  float* blkY = blkX + 768;
  float* Fxb = blkY + 768;           // 192
  float* Fyb = Fxb + 192;
  int* idxA = (int*)(Fyb + 192);     // 65536
  int* idxB = idxA + 65536;
  int* sel = idxB + 65536;           // 2048
  // partial top-16 lists for streaming KNN: alias C1 (float vals) / C2 (int idx).
  // Dead at KNN time: every knnb/kmerge precedes the k_linm writes of C1/C2 in each stage.
  float* pvb = C1;
  int* pib = (int*)C2;

  auto knn3 = [&](const float* xa, const float* xb2, int N, int* ia, int* ib, int ns) {
    k_xx2<<<dim3((N + 255) / 256, B, ns), 256, 0, stream>>>(xa, xb2, xx0, xx1, 3, N);
    dim3 g2(N / 4, B, ns);
    k_knn2<3><<<g2, 256, 0, stream>>>(xa, xb2, xx0, xx1, ia, ib, N);
  };
  auto knn192 = [&](const float* xa, const float* xb2, int N, int* ia, int* ib, int ns) {
    k_xx2<<<dim3((N + 255) / 256, B, ns), 256, 0, stream>>>(xa, xb2, xx0, xx1, 192, N);
    k_knnb<<<dim3(N >> 6, B * 4, ns), 256, 0, stream>>>(xa, xb2, xx0, xx1, pvb, pib, N);
    k_kmerge<<<dim3(N / 4, B, ns), 256, 0, stream>>>(pvb, pib, ia, ib, N);
  };

  const float* fx = W[0];
  const float* fy = W[1];
  int N = N0;
  for (int blk = 0; blk < 2; ++blk) {
    const float* dgw = W[blk ? 12 : 2]; const float* dgd = W[blk ? 13 : 3];
    const float* qw  = W[blk ? 14 : 4]; const float* qd  = W[blk ? 15 : 5];
    const float* kw  = W[blk ? 16 : 6]; const float* kd  = W[blk ? 17 : 7];
    const float* vw  = W[blk ? 18 : 8]; const float* vd  = W[blk ? 19 : 9];
    const float* gw  = W[blk ? 20 : 10]; const float* gd = W[blk ? 21 : 11];
    dim3 gP(B * N / 4);
    dim3 gL((3 * N + 255) / 256, B, 1);

    // ======== dgcnn, both sides in merged launches ========
    if (blk == 0) knn3(fx, fy, N, idxA, idxB, 2);
    else          knn192(fx, fy, N, idxA, idxB, 2);
    {
      LinSlots s{};  // stage1: W1*x, (W2-W1)*x for fx and fy
      int wsd = (blk == 0) ? 2 : 128;
      int off2 = (blk == 0) ? 1 : 64;
      const float* Xs[4] = {fx, fx, fy, fy};
      float* cms[4] = {C1, C2, C3, C4};
      float* pms[4] = {M1, M2, M3, M4};
      for (int i = 0; i < 4; ++i) {
        s.W[i] = dgw; s.X[i] = Xs[i]; s.bias[i] = nullptr;
        s.cm[i] = cms[i]; s.pm[i] = pms[i];
        s.ws[i] = wsd; s.woff[i] = (i & 1) ? off2 : 0; s.sub[i] = (i & 1);
      }
      gL.z = 16;
      if (blk == 0) k_linm<1><<<gL, 256, 0, stream>>>(s, N);
      else          k_linm<64><<<gL, 256, 0, stream>>>(s, N);
    }
    {
      LinSlots s{};  // stage2: Wd * each
      const float* Xs[4] = {C1, C2, C3, C4};
      float* pms[4] = {M5, M6, M7, M8};
      for (int i = 0; i < 4; ++i) {
        s.W[i] = dgd; s.X[i] = Xs[i]; s.bias[i] = nullptr;
        s.cm[i] = nullptr; s.pm[i] = pms[i];
        s.ws[i] = 64; s.woff[i] = 0; s.sub[i] = 0;
      }
      gL.z = 16;
      k_linm<64><<<gL, 256, 0, stream>>>(s, N);
    }
    k_edge2<<<dim3(B * N / 4, 2), 256, 0, stream>>>(M1, M2, M5, M6, M3, M4, M7, M8,
                                                    idxA, idxB, bufA, bufB, N);

    // ======== cross_context #1: x=bufA, y=bufB -> bufC ========
    knn192(bufB, bufB, N, idxB, idxB, 1);
    {
      LinSlots s{};  // stage1: q,k1,k2,v1,v2
      const float* Wm[5] = {qw, kw, kw, vw, vw};
      const float* Xs[5] = {bufA, bufB, bufB, bufB, bufB};
      float* cms[5] = {C1, C2, C3, C4, C5};
      float* pms[5] = {M1, M3, M4, M5, M6};
      int wss[5] = {64, 128, 128, 128, 128};
      int offs[5] = {0, 0, 64, 0, 64};
      int subs[5] = {0, 0, 1, 0, 1};
      for (int i = 0; i < 5; ++i) {
        s.W[i] = Wm[i]; s.X[i] = Xs[i]; s.bias[i] = nullptr;
        s.cm[i] = cms[i]; s.pm[i] = pms[i];
        s.ws[i] = wss[i]; s.woff[i] = offs[i]; s.sub[i] = subs[i];
      }
      gL.z = 20;
      k_linm<64><<<gL, 256, 0, stream>>>(s, N);
    }
    {
      LinSlots s{};  // stage2: qd,kd,kd,vd,vd
      const float* Wm[5] = {qd, kd, kd, vd, vd};
      const float* Xs[5] = {C1, C2, C3, C4, C5};
      float* pms[5] = {M2, M7, M8, M9, M10};
      for (int i = 0; i < 5; ++i) {
        s.W[i] = Wm[i]; s.X[i] = Xs[i]; s.bias[i] = nullptr;
        s.cm[i] = nullptr; s.pm[i] = pms[i];
        s.ws[i] = 64; s.woff[i] = 0; s.sub[i] = 0;
      }
      gL.z = 20;
      k_linm<64><<<gL, 256, 0, stream>>>(s, N);
    }
    k_qfin<<<gP, 256, 0, stream>>>(M1, M2, qxpm, N);
    k_att<<<gP, 256, 0, stream>>>(bufA, qxpm, M3, M4, M7, M8, M5, M6, M9, M10, idxB, bufC, N);

    // ======== cross_context #2: x=bufB, y=bufC -> bufD ========
    knn192(bufC, bufC, N, idxA, idxA, 1);
    {
      LinSlots s{};
      const float* Wm[5] = {qw, kw, kw, vw, vw};
      const float* Xs[5] = {bufB, bufC, bufC, bufC, bufC};
      float* cms[5] = {C1, C2, C3, C4, C5};
      float* pms[5] = {M1, M3, M4, M5, M6};
      int wss[5] = {64, 128, 128, 128, 128};
      int offs[5] = {0, 0, 64, 0, 64};
      int subs[5] = {0, 0, 1, 0, 1};
      for (int i = 0; i < 5; ++i) {
        s.W[i] = Wm[i]; s.X[i] = Xs[i]; s.bias[i] = nullptr;
        s.cm[i] = cms[i]; s.pm[i] = pms[i];
        s.ws[i] = wss[i]; s.woff[i] = offs[i]; s.sub[i] = subs[i];
      }
      gL.z = 20;
      k_linm<64><<<gL, 256, 0, stream>>>(s, N);
    }
    {
      LinSlots s{};
      const float* Wm[5] = {qd, kd, kd, vd, vd};
      const float* Xs[5] = {C1, C2, C3, C4, C5};
      float* pms[5] = {M2, M7, M8, M9, M10};
      for (int i = 0; i < 5; ++i) {
        s.W[i] = Wm[i]; s.X[i] = Xs[i]; s.bias[i] = nullptr;
        s.cm[i] = nullptr; s.pm[i] = pms[i];
        s.ws[i] = 64; s.woff[i] = 0; s.sub[i] = 0;
      }
      gL.z = 20;
      k_linm<64><<<gL, 256, 0, stream>>>(s, N);
    }
    k_qfin<<<gP, 256, 0, stream>>>(M1, M2, qxpm, N);
    k_att<<<gP, 256, 0, stream>>>(bufB, qxpm, M3, M4, M7, M8, M5, M6, M9, M10, idxA, bufD, N);

    // ======== global fuse ========
    k_cmean2<<<dim3(192, B, 2), 256, 0, stream>>>(bufC, bufD, meanX, meanY, N, 192, 0, 1.f / (float)N);
    k_gbias2<<<dim3(B, 2), 192, 0, stream>>>(gw, meanX, meanY, cbX, cbY);
    {
      LinSlots s{};  // gw on both sides (with bias)
      const float* Xs[2] = {bufC, bufD};
      const float* bs[2] = {cbX, cbY};
      float* cms[2] = {C1, C2};
      float* pms[2] = {M1, M2};
      for (int i = 0; i < 2; ++i) {
        s.W[i] = gw; s.X[i] = Xs[i]; s.bias[i] = bs[i];
        s.cm[i] = cms[i]; s.pm[i] = pms[i];
        s.ws[i] = 128; s.woff[i] = 0; s.sub[i] = 0;
      }
      gL.z = 8;
      k_linm<64><<<gL, 256, 0, stream>>>(s, N);
    }
    {
      LinSlots s{};  // gd on both sides
      const float* Xs[2] = {C1, C2};
      float* pms[2] = {M3, M4};
      for (int i = 0; i < 2; ++i) {
        s.W[i] = gd; s.X[i] = Xs[i]; s.bias[i] = nullptr;
        s.cm[i] = nullptr; s.pm[i] = pms[i];
        s.ws[i] = 64; s.woff[i] = 0; s.sub[i] = 0;
      }
      gL.z = 8;
      k_linm<64><<<gL, 256, 0, stream>>>(s, N);
    }
    k_gfin<<<dim3(B * N / 4, 2), 256, 0, stream>>>(M1, M3, M2, M4, bufA, bufApm, bufB, bufBpm, N);

    // ======== score + top-half selection ========
    int Nh = N / 2;
    k_parmean<<<dim3((B * 3 * N + 255) / 256), 256, 0, stream>>>(bufA, bufB, px, py, N, B);
    k_dotphi<<<dim3((B * N + 255) / 256), 256, 0, stream>>>(bufA, bufB, px, py, dps, N, B);
    k_topsel<<<dim3(B), 1024, 0, stream>>>(dps, sel, N, Nh);
    k_gather<<<dim3(B * Nh / 4), 256, 0, stream>>>(bufApm, bufBpm, sel, bufC, bufD, N, Nh);
    k_cmean2<<<dim3(192, B, 2), 256, 0, stream>>>(bufC, bufD, blkX, blkY, Nh, 384, blk * 192, 1.f / (float)Nh);
    fx = bufC; fy = bufD;
    N = Nh;
  }
  k_head<<<dim3(2, B), 96, 0, stream>>>(blkX, blkY, W[22], W[23], Fxb, Fyb);
  k_svd<<<dim3(B), 64, 0, stream>>>(Fxb, Fyb, (float*)d_out, B);
}

// Round 10
// 3446.667 us; speedup vs baseline: 1.0162x; 1.0162x over previous
//
#include <hip/hip_runtime.h>
#include <math.h>

#define SLOPE 0.2f
#define EPSV 1e-12f
#define NEGINF (-3.0e38f)

static __device__ __forceinline__ float lrelu_combine(float xv, float dvv, float dot, float dsq) {
  float xneg = xv - dot / (dsq + EPSV) * dvv;
  float w = (dot >= 0.f) ? xv : xneg;
  return SLOPE * xv + (1.f - SLOPE) * w;
}

// ---------------- squared norms per point, up to 2 inputs (side = blockIdx.z) ----------------
__global__ void k_xx2(const float* __restrict__ x0, const float* __restrict__ x1,
                      float* __restrict__ xxA, float* __restrict__ xxB, int D, int N) {
  int side = blockIdx.z;
  const float* x = side ? x1 : x0;
  float* xx = side ? xxB : xxA;
  int b = blockIdx.y;
  int m = blockIdx.x * 256 + threadIdx.x;
  if (m >= N) return;
  const float* xp = x + (size_t)b * D * N + m;
  float s = 0.f;
  for (int d = 0; d < D; ++d) { float v = xp[(size_t)d * N]; s = fmaf(v, v, s); }
  xx[b * N + m] = s;
}

// ---------------- fused knn top-16 (round-7 proven; best of 3 structural attempts) ----------------
// 4 queries/block, 4 m-points/thread. Ascending-d fmaf chain, 2*dot - xxn - xxm; selection via
// float4 scan + 64-lane butterfly with (max, min-index) tie-break -> matches lax.top_k exactly.
template <int D>
__global__ void __launch_bounds__(256) k_knn2(const float* __restrict__ x0, const float* __restrict__ x1,
                                              const float* __restrict__ xxA, const float* __restrict__ xxB,
                                              int* __restrict__ idx0, int* __restrict__ idx1, int N) {
  int side = blockIdx.z;
  const float* x = side ? x1 : x0;
  const float* xx = side ? xxB : xxA;
  int* idx = side ? idx1 : idx0;
  __shared__ float qt[D * 4];
  __shared__ float dist[4][2048];
  __shared__ float xxq[4];
  int b = blockIdx.y, tid = threadIdx.x;
  int q0 = blockIdx.x * 4;
  const float* xb = x + (size_t)b * D * N;
  for (int i = tid; i < D * 4; i += 256) qt[i] = xb[(size_t)(i >> 2) * N + q0 + (i & 3)];
  if (tid < 4) xxq[tid] = xx[b * N + q0 + tid];
  __syncthreads();
  int kouter = N >> 10;
  for (int k = 0; k < kouter; ++k) {
    int m0 = tid + (k << 10);
    float4 a0 = {0, 0, 0, 0}, a1 = {0, 0, 0, 0}, a2 = {0, 0, 0, 0}, a3 = {0, 0, 0, 0};
#pragma unroll
    for (int d = 0; d < D; ++d) {
      const float4 q4 = *(const float4*)&qt[d * 4];
      const float* xr = xb + (size_t)d * N + m0;
      float v0 = xr[0], v1 = xr[256], v2 = xr[512], v3 = xr[768];
      a0.x = fmaf(q4.x, v0, a0.x); a0.y = fmaf(q4.y, v0, a0.y);
      a0.z = fmaf(q4.z, v0, a0.z); a0.w = fmaf(q4.w, v0, a0.w);
      a1.x = fmaf(q4.x, v1, a1.x); a1.y = fmaf(q4.y, v1, a1.y);
      a1.z = fmaf(q4.z, v1, a1.z); a1.w = fmaf(q4.w, v1, a1.w);
      a2.x = fmaf(q4.x, v2, a2.x); a2.y = fmaf(q4.y, v2, a2.y);
      a2.z = fmaf(q4.z, v2, a2.z); a2.w = fmaf(q4.w, v2, a2.w);
      a3.x = fmaf(q4.x, v3, a3.x); a3.y = fmaf(q4.y, v3, a3.y);
      a3.z = fmaf(q4.z, v3, a3.z); a3.w = fmaf(q4.w, v3, a3.w);
    }
    const float* xxb2 = xx + b * N + m0;
    float x0v = xxb2[0], x1v = xxb2[256], x2v = xxb2[512], x3v = xxb2[768];
    dist[0][m0]       = 2.f * a0.x - xxq[0] - x0v;
    dist[1][m0]       = 2.f * a0.y - xxq[1] - x0v;
    dist[2][m0]       = 2.f * a0.z - xxq[2] - x0v;
    dist[3][m0]       = 2.f * a0.w - xxq[3] - x0v;
    dist[0][m0 + 256] = 2.f * a1.x - xxq[0] - x1v;
    dist[1][m0 + 256] = 2.f * a1.y - xxq[1] - x1v;
    dist[2][m0 + 256] = 2.f * a1.z - xxq[2] - x1v;
    dist[3][m0 + 256] = 2.f * a1.w - xxq[3] - x1v;
    dist[0][m0 + 512] = 2.f * a2.x - xxq[0] - x2v;
    dist[1][m0 + 512] = 2.f * a2.y - xxq[1] - x2v;
    dist[2][m0 + 512] = 2.f * a2.z - xxq[2] - x2v;
    dist[3][m0 + 512] = 2.f * a2.w - xxq[3] - x2v;
    dist[0][m0 + 768] = 2.f * a3.x - xxq[0] - x3v;
    dist[1][m0 + 768] = 2.f * a3.y - xxq[1] - x3v;
    dist[2][m0 + 768] = 2.f * a3.z - xxq[2] - x3v;
    dist[3][m0 + 768] = 2.f * a3.w - xxq[3] - x3v;
  }
  __syncthreads();
  int g = tid >> 6, lane = tid & 63;
  float* dr = dist[g];
  int n = q0 + g;
  int imax = N >> 8;
  int* op = idx + ((size_t)b * N + n) * 16;
  for (int r = 0; r < 16; ++r) {
    float bv = NEGINF;
    int bi = N;
    for (int i = 0; i < imax; ++i) {
      int mb = i * 256 + lane * 4;
      float4 v = *(const float4*)&dr[mb];
      if (v.x > bv) { bv = v.x; bi = mb; }
      if (v.y > bv) { bv = v.y; bi = mb + 1; }
      if (v.z > bv) { bv = v.z; bi = mb + 2; }
      if (v.w > bv) { bv = v.w; bi = mb + 3; }
    }
#pragma unroll
    for (int s = 1; s < 64; s <<= 1) {
      float ov = __shfl_xor(bv, s, 64);
      int oi = __shfl_xor(bi, s, 64);
      if (ov > bv || (ov == bv && oi < bi)) { bv = ov; bi = oi; }
    }
    if (lane == 0) { op[r] = bi; dr[bi] = NEGINF; }
  }
}

// ---------------- multi-slot 64-out linear (slot = blockIdx.z>>2), dual-layout output ----------------
struct LinSlots {
  const float* W[5]; const float* X[5]; const float* bias[5];
  float* cm[5]; float* pm[5];
  int ws[5]; int woff[5]; int sub[5];
};

template <int KT>
__global__ void __launch_bounds__(256) k_linm(LinSlots S, int N) {
  __shared__ float wl[64 * ((KT + 3) & ~3)];
  const int KP = (KT + 3) & ~3;
  int slot = blockIdx.z >> 2;
  int oc = (blockIdx.z & 3) * 16;
  const float* W = S.W[slot];
  int ws = S.ws[slot], woff = S.woff[slot], sub = S.sub[slot];
  int tid = threadIdx.x;
  for (int i = tid; i < 64 * KT; i += 256) {
    int o = i / KT, k = i - o * KT;
    float v = W[o * ws + woff + k];
    if (sub) v -= W[o * ws + k];
    wl[o * KP + k] = v;
  }
  __syncthreads();
  int b = blockIdx.y;
  int j = blockIdx.x * 256 + tid;
  int M3 = 3 * N;
  if (j >= M3) return;
  const float* Xb = S.X[slot] + (size_t)b * KT * M3;
  float xv[KT];
#pragma unroll
  for (int k = 0; k < KT; ++k) xv[k] = Xb[(size_t)k * M3 + j];
  int d = j / N;
  const float* bias = S.bias[slot];
  float acc[16];
  if (bias) {
#pragma unroll
    for (int oo = 0; oo < 16; ++oo) acc[oo] = bias[b * 192 + (oc + oo) * 3 + d];
  } else {
#pragma unroll
    for (int oo = 0; oo < 16; ++oo) acc[oo] = 0.f;
  }
#pragma unroll
  for (int oo = 0; oo < 16; ++oo) {
    const float* wr = &wl[(oc + oo) * KP];
    float s = acc[oo];
#pragma unroll
    for (int k = 0; k < KT; ++k) s = fmaf(wr[k], xv[k], s);
    acc[oo] = s;
  }
  if (S.cm[slot]) {
    float* ob = S.cm[slot] + (size_t)b * 64 * M3;
#pragma unroll
    for (int oo = 0; oo < 16; ++oo) ob[(size_t)(oc + oo) * M3 + j] = acc[oo];
  }
  if (S.pm[slot]) {
    int n = j - d * N;
    float4* pp = (float4*)(S.pm[slot] + ((size_t)((b * N + n) * 3 + d)) * 64 + oc);
    pp[0] = make_float4(acc[0], acc[1], acc[2], acc[3]);
    pp[1] = make_float4(acc[4], acc[5], acc[6], acc[7]);
    pp[2] = make_float4(acc[8], acc[9], acc[10], acc[11]);
    pp[3] = make_float4(acc[12], acc[13], acc[14], acc[15]);
  }
}

// ---------------- edge conv, wave per point, side = blockIdx.y ----------------
__global__ void __launch_bounds__(256) k_edge2(const float* __restrict__ P1a, const float* __restrict__ P2a,
                                               const float* __restrict__ D1a, const float* __restrict__ D2a,
                                               const float* __restrict__ P1b, const float* __restrict__ P2b,
                                               const float* __restrict__ D1b, const float* __restrict__ D2b,
                                               const int* __restrict__ idxA, const int* __restrict__ idxB,
                                               float* __restrict__ outA, float* __restrict__ outB, int N) {
  int side = blockIdx.y;
  const float* P1 = side ? P1b : P1a;
  const float* P2 = side ? P2b : P2a;
  const float* D1 = side ? D1b : D1a;
  const float* D2 = side ? D2b : D2a;
  const int* idx = side ? idxB : idxA;
  float* out = side ? outB : outA;
  int tid = threadIdx.x;
  int p = blockIdx.x * 4 + (tid >> 6);
  int c = tid & 63;
  int b = p / N, n = p - b * N;
  size_t bn = ((size_t)(b * N + n) * 3) * 64 + c;
  float p2[3], d2[3];
#pragma unroll
  for (int d = 0; d < 3; ++d) { p2[d] = P2[bn + d * 64]; d2[d] = D2[bn + d * 64]; }
  const int* ip = idx + ((size_t)b * N + n) * 16;
  float acc0 = 0.f, acc1 = 0.f, acc2 = 0.f;
  for (int j = 0; j < 16; ++j) {
    int m = ip[j];
    size_t bm = ((size_t)(b * N + m) * 3) * 64 + c;
    float xl[3], dv[3];
#pragma unroll
    for (int d = 0; d < 3; ++d) {
      xl[d] = P1[bm + d * 64] + p2[d];
      dv[d] = D1[bm + d * 64] + d2[d];
    }
    float dot = xl[0] * dv[0] + xl[1] * dv[1] + xl[2] * dv[2];
    float dsq = dv[0] * dv[0] + dv[1] * dv[1] + dv[2] * dv[2];
    acc0 += lrelu_combine(xl[0], dv[0], dot, dsq);
    acc1 += lrelu_combine(xl[1], dv[1], dot, dsq);
    acc2 += lrelu_combine(xl[2], dv[2], dot, dsq);
  }
  size_t r0 = (size_t)((b * 64 + c) * 3) * N;
  out[r0 + n] = acc0 * (1.f / 16.f);
  out[r0 + N + n] = acc1 * (1.f / 16.f);
  out[r0 + 2 * (size_t)N + n] = acc2 * (1.f / 16.f);
}

// ---------------- fused Q-finisher + K-logits + softmax + V-attention + residual ----------------
// Q path inline = k_qfin's exact arithmetic (same chains, same 64-lane cn2 butterfly).
// Logits bit-identical (lane-0 butterfly broadcast); softmax = k_soft's sequence; V loop unchanged.
__global__ void __launch_bounds__(256) k_att(const float* __restrict__ xres,
                                             const float* __restrict__ QXL, const float* __restrict__ QDV,
                                             const float* __restrict__ KP1, const float* __restrict__ KP2,
                                             const float* __restrict__ KD1, const float* __restrict__ KD2,
                                             const float* __restrict__ VP1, const float* __restrict__ VP2,
                                             const float* __restrict__ VD1, const float* __restrict__ VD2,
                                             const int* __restrict__ idx,
                                             float* __restrict__ out, int N) {
  int tid = threadIdx.x;
  int p = blockIdx.x * 4 + (tid >> 6);
  int c = tid & 63;
  int b = p / N, n = p - b * N;
  size_t bn = ((size_t)(b * N + n) * 3) * 64 + c;
  float qv[3], kp2[3], kd2[3], vp2[3], vd2[3];
  {  // inline qfin
    float xl[3], dv[3];
#pragma unroll
    for (int d = 0; d < 3; ++d) { xl[d] = QXL[bn + d * 64]; dv[d] = QDV[bn + d * 64]; }
    float dot = xl[0] * dv[0] + xl[1] * dv[1] + xl[2] * dv[2];
    float dsq = dv[0] * dv[0] + dv[1] * dv[1] + dv[2] * dv[2];
    float z[3];
#pragma unroll
    for (int d = 0; d < 3; ++d) z[d] = lrelu_combine(xl[d], dv[d], dot, dsq);
    float n2 = z[0] * z[0] + z[1] * z[1] + z[2] * z[2];
    float cn2 = n2;
#pragma unroll
    for (int s = 1; s < 64; s <<= 1) cn2 += __shfl_xor(cn2, s, 64);
    float n_o = sqrtf(n2), cn = sqrtf(cn2);
    float scl = (n_o / fmaxf(cn, EPSV)) / fmaxf(n_o, EPSV);
#pragma unroll
    for (int d = 0; d < 3; ++d) qv[d] = z[d] * scl;
  }
#pragma unroll
  for (int d = 0; d < 3; ++d) {
    kp2[d] = KP2[bn + d * 64];
    kd2[d] = KD2[bn + d * 64];
    vp2[d] = VP2[bn + d * 64];
    vd2[d] = VD2[bn + d * 64];
  }
  const int* ip = idx + ((size_t)b * N + n) * 16;
  float l[16];
#pragma unroll
  for (int j = 0; j < 16; ++j) {
    int m = ip[j];
    size_t bm = ((size_t)(b * N + m) * 3) * 64 + c;
    float xl[3], dv[3];
#pragma unroll
    for (int d = 0; d < 3; ++d) {
      xl[d] = KP1[bm + d * 64] + kp2[d];
      dv[d] = KD1[bm + d * 64] + kd2[d];
    }
    float dot = xl[0] * dv[0] + xl[1] * dv[1] + xl[2] * dv[2];
    float dsq = dv[0] * dv[0] + dv[1] * dv[1] + dv[2] * dv[2];
    float z[3];
#pragma unroll
    for (int d = 0; d < 3; ++d) z[d] = lrelu_combine(xl[d], dv[d], dot, dsq);
    float n2 = z[0] * z[0] + z[1] * z[1] + z[2] * z[2];
    float cn2 = n2;
#pragma unroll
    for (int s = 1; s < 64; s <<= 1) cn2 += __shfl_xor(cn2, s, 64);
    float n_o = sqrtf(n2), cn = sqrtf(cn2);
    float scl = (n_o / fmaxf(cn, EPSV)) / fmaxf(n_o, EPSV);
    float part = (z[0] * qv[0] + z[1] * qv[1] + z[2] * qv[2]) * scl;
#pragma unroll
    for (int s = 1; s < 32; s <<= 1) part += __shfl_xor(part, s, 32);
    part = __shfl(part, 0, 32);
    l[j] = part * 0.102062072615966f;  // 1/sqrt(96)
  }
  float mx = l[0];
#pragma unroll
  for (int j = 1; j < 16; ++j) mx = fmaxf(mx, l[j]);
  float sum = 0.f;
#pragma unroll
  for (int j = 0; j < 16; ++j) { l[j] = expf(l[j] - mx); sum += l[j]; }
  float inv = 1.f / sum;
#pragma unroll
  for (int j = 0; j < 16; ++j) l[j] *= inv;
  float acc0 = 0.f, acc1 = 0.f, acc2 = 0.f;
#pragma unroll
  for (int j = 0; j < 16; ++j) {
    int m = ip[j];
    float av = l[j];
    size_t bm = ((size_t)(b * N + m) * 3) * 64 + c;
    float xl[3], dv[3];
#pragma unroll
    for (int d = 0; d < 3; ++d) {
      xl[d] = VP1[bm + d * 64] + vp2[d];
      dv[d] = VD1[bm + d * 64] + vd2[d];
    }
    float dot = xl[0] * dv[0] + xl[1] * dv[1] + xl[2] * dv[2];
    float dsq = dv[0] * dv[0] + dv[1] * dv[1] + dv[2] * dv[2];
    acc0 = fmaf(av, lrelu_combine(xl[0], dv[0], dot, dsq), acc0);
    acc1 = fmaf(av, lrelu_combine(xl[1], dv[1], dot, dsq), acc1);
    acc2 = fmaf(av, lrelu_combine(xl[2], dv[2], dot, dsq), acc2);
  }
  size_t r0 = (size_t)((b * 64 + c) * 3) * N;
  out[r0 + n] = xres[r0 + n] + acc0;
  out[r0 + N + n] = xres[r0 + N + n] + acc1;
  out[r0 + 2 * (size_t)N + n] = xres[r0 + 2 * (size_t)N + n] + acc2;
}

// ---------------- g-fuse finisher: wave per point, side = blockIdx.y ----------------
__global__ void __launch_bounds__(256) k_gfin(const float* __restrict__ XLa, const float* __restrict__ DVa,
                                              const float* __restrict__ XLb, const float* __restrict__ DVb,
                                              float* __restrict__ outa, float* __restrict__ outpa,
                                              float* __restrict__ outb, float* __restrict__ outpb, int N) {
  int side = blockIdx.y;
  const float* XL = side ? XLb : XLa;
  const float* DV = side ? DVb : DVa;
  float* out = side ? outb : outa;
  float* outpm = side ? outpb : outpa;
  int tid = threadIdx.x;
  int p = blockIdx.x * 4 + (tid >> 6);
  int c = tid & 63;
  int b = p / N, n = p - b * N;
  size_t bn = ((size_t)(b * N + n) * 3) * 64 + c;
  float xl[3], dv[3];
#pragma unroll
  for (int d = 0; d < 3; ++d) { xl[d] = XL[bn + d * 64]; dv[d] = DV[bn + d * 64]; }
  float dot = xl[0] * dv[0] + xl[1] * dv[1] + xl[2] * dv[2];
  float dsq = dv[0] * dv[0] + dv[1] * dv[1] + dv[2] * dv[2];
  size_t r0 = (size_t)((b * 64 + c) * 3) * N;
#pragma unroll
  for (int d = 0; d < 3; ++d) {
    float z = lrelu_combine(xl[d], dv[d], dot, dsq);
    out[r0 + (size_t)d * N + n] = z;
    outpm[bn + d * 64] = z;
  }
}

// ---------------- bias for g-fuse, both sides in one launch ----------------
__global__ void k_gbias2(const float* __restrict__ gw, const float* __restrict__ meanX,
                         const float* __restrict__ meanY,
                         float* __restrict__ cbX, float* __restrict__ cbY) {
  int b = blockIdx.x, which = blockIdx.y, tid = threadIdx.x;  // 192 threads
  int o = tid / 3, d = tid - o * 3;
  const float* mb = (which ? meanY : meanX) + b * 192;
  float* cb = (which ? cbY : cbX);
  float s = 0.f;
  for (int c = 0; c < 64; ++c) s = fmaf(gw[o * 128 + 64 + c], mb[c * 3 + d], s);
  cb[b * 192 + tid] = s;
}

// ---------------- column mean over N for both arrays in one launch ----------------
__global__ void k_cmean2(const float* __restrict__ x1, const float* __restrict__ x2,
                         float* __restrict__ o1, float* __restrict__ o2,
                         int N, int ostride, int obase, float inv) {
  __shared__ float red[256];
  int b = blockIdx.y, cd = blockIdx.x, which = blockIdx.z, tid = threadIdx.x;
  const float* x = which ? x2 : x1;
  float* out = which ? o2 : o1;
  const float* p = x + ((size_t)b * 192 + cd) * N;
  float s = 0.f;
  for (int i = tid; i < N; i += 256) s += p[i];
  red[tid] = s;
  __syncthreads();
  for (int st = 128; st > 0; st >>= 1) {
    if (tid < st) red[tid] += red[tid + st];
    __syncthreads();
  }
  if (tid == 0) out[(size_t)b * ostride + obase + cd] = red[0] * inv;
}

// ---------------- channel-mean (fx_par pre-normalization) for both arrays ----------------
__global__ void k_parmean(const float* __restrict__ fx, const float* __restrict__ fy,
                          float* __restrict__ px, float* __restrict__ py, int N, int B) {
  int gi = blockIdx.x * 256 + threadIdx.x;
  int total = B * 3 * N;
  if (gi >= total) return;
  int b = gi / (3 * N);
  int r = gi - b * 3 * N;
  const float* fxb = fx + (size_t)b * 192 * N + r;
  const float* fyb = fy + (size_t)b * 192 * N + r;
  float sx = 0.f, sy = 0.f;
  for (int c = 0; c < 64; ++c) { sx += fxb[(size_t)c * 3 * N]; sy += fyb[(size_t)c * 3 * N]; }
  px[gi] = sx * (1.f / 64.f);
  py[gi] = sy * (1.f / 64.f);
}

// ---------------- score logits: sum_c (fx.px)(fy.py) (softmax+norm skipped: monotone) ----------------
__global__ void k_dotphi(const float* __restrict__ fx, const float* __restrict__ fy,
                         const float* __restrict__ px, const float* __restrict__ py,
                         float* __restrict__ dps, int N, int B) {
  int gi = blockIdx.x * 256 + threadIdx.x;
  if (gi >= B * N) return;
  int b = gi / N, n = gi - b * N;
  const float* fxb = fx + (size_t)b * 192 * N + n;
  const float* fyb = fy + (size_t)b * 192 * N + n;
  const float* pxb = px + (size_t)b * 3 * N + n;
  const float* pyb = py + (size_t)b * 3 * N + n;
  float acc = 0.f;
  for (int c = 0; c < 64; ++c) {
    float ax = 0.f, ay = 0.f;
    for (int d = 0; d < 3; ++d) {
      ax = fmaf(fxb[(size_t)(c * 3 + d) * N], pxb[(size_t)d * N], ax);
      ay = fmaf(fyb[(size_t)(c * 3 + d) * N], pyb[(size_t)d * N], ay);
    }
    acc = fmaf(ax, ay, acc);
  }
  dps[gi] = acc;
}

// ---------------- top-N/2 selection: bitonic sort (desc value, asc index) ----------------
__global__ void __launch_bounds__(1024) k_topsel(const float* __restrict__ dps,
                                                 int* __restrict__ sel, int N, int Nh) {
  __shared__ float kv[2048];
  __shared__ int ki[2048];
  int b = blockIdx.x, tid = threadIdx.x;
  for (int i = tid; i < N; i += 1024) { kv[i] = dps[b * N + i]; ki[i] = i; }
  __syncthreads();
  for (int kk = 2; kk <= N; kk <<= 1) {
    for (int jj = kk >> 1; jj > 0; jj >>= 1) {
      for (int i = tid; i < N; i += 1024) {
        int ixj = i ^ jj;
        if (ixj > i) {
          float va = kv[i], vb = kv[ixj];
          int ia = ki[i], ib = ki[ixj];
          bool aFirst = (va > vb) || (va == vb && ia < ib);
          bool up = ((i & kk) == 0);
          bool doswap = up ? (!aFirst) : aFirst;
          if (doswap) { kv[i] = vb; kv[ixj] = va; ki[i] = ib; ki[ixj] = ia; }
        }
      }
      __syncthreads();
    }
  }
  for (int i = tid; i < Nh; i += 1024) sel[b * Nh + i] = ki[i];
}

// ---------------- gather selected points (pm source, cm dest), wave per point ----------------
__global__ void __launch_bounds__(256) k_gather(const float* __restrict__ sxpm, const float* __restrict__ sypm,
                                                const int* __restrict__ sel,
                                                float* __restrict__ dx, float* __restrict__ dy,
                                                int N, int Nh) {
  int tid = threadIdx.x;
  int p = blockIdx.x * 4 + (tid >> 6);
  int c = tid & 63;
  int b = p / Nh, i = p - b * Nh;
  int s = sel[b * Nh + i];
  size_t bs = ((size_t)(b * N + s) * 3) * 64 + c;
  size_t r0 = (size_t)((b * 64 + c) * 3) * Nh;
#pragma unroll
  for (int d = 0; d < 3; ++d) {
    dx[r0 + (size_t)d * Nh + i] = sxpm[bs + d * 64];
    dy[r0 + (size_t)d * Nh + i] = sypm[bs + d * 64];
  }
}

// ---------------- final head: vn_lin_lrelu(concat blocks, h_w, h_d) ----------------
__global__ void k_head(const float* __restrict__ blkX, const float* __restrict__ blkY,
                       const float* __restrict__ hw, const float* __restrict__ hd,
                       float* __restrict__ Fx, float* __restrict__ Fy) {
  __shared__ float f[3][128];
  __shared__ float xl[3][32];
  __shared__ float dv[3][32];
  int which = blockIdx.x, b = blockIdx.y, tid = threadIdx.x;
  const float* blk = which ? blkY : blkX;
  float* F = which ? Fy : Fx;
  int o = tid & 31, dd = tid >> 5;
  for (int i = tid; i < 384; i += 96) f[i % 3][i / 3] = blk[(size_t)b * 384 + i];
  __syncthreads();
  float s = 0.f;
  for (int c = 0; c < 128; ++c) s = fmaf(hw[o * 128 + c], f[dd][c], s);
  xl[dd][o] = s;
  __syncthreads();
  float s2 = 0.f;
  for (int p = 0; p < 32; ++p) s2 = fmaf(hd[o * 32 + p], xl[dd][p], s2);
  dv[dd][o] = s2;
  __syncthreads();
  float dot = xl[0][o] * dv[0][o] + xl[1][o] * dv[1][o] + xl[2][o] * dv[2][o];
  float dsq = dv[0][o] * dv[0][o] + dv[1][o] * dv[1][o] + dv[2][o] * dv[2][o];
  F[((size_t)b * 32 + o) * 3 + dd] = lrelu_combine(xl[dd][o], dv[dd][o], dot, dsq);
}

// ================== LAPACK-faithful 3x3 SVD (dgesdd path: dgebrd + dbdsqr) ==================
#define DEPS 2.220446049250313e-16
#define DUNFL 2.2250738585072014e-308

static __device__ void dlartg_(double f, double g, double* cs, double* sn, double* r) {
  if (g == 0.0) { *cs = 1.0; *sn = 0.0; *r = f; }
  else if (f == 0.0) { *cs = 0.0; *sn = copysign(1.0, g); *r = fabs(g); }
  else {
    double d = sqrt(f * f + g * g);
    double c = fabs(f) / d;
    double rr = copysign(d, f);
    *cs = c; *r = rr; *sn = g / rr;
  }
}

static __device__ void dlas2_(double f, double g, double h, double* ssmin, double* ssmax) {
  double fa = fabs(f), ga = fabs(g), ha = fabs(h);
  double fhmn = fmin(fa, ha), fhmx = fmax(fa, ha);
  if (fhmn == 0.0) {
    *ssmin = 0.0;
    if (fhmx == 0.0) *ssmax = ga;
    else { double mx = fmax(fhmx, ga), mn = fmin(fhmx, ga); double q = mn / mx; *ssmax = mx * sqrt(1.0 + q * q); }
  } else {
    if (ga < fhmx) {
      double as_ = 1.0 + fhmn / fhmx;
      double at = (fhmx - fhmn) / fhmx;
      double au = ga / fhmx; au = au * au;
      double c = 2.0 / (sqrt(as_ * as_ + au) + sqrt(at * at + au));
      *ssmin = fhmn * c; *ssmax = fhmx / c;
    } else {
      double au = fhmx / ga;
      if (au == 0.0) { *ssmin = (fhmn * fhmx) / ga; *ssmax = ga; }
      else {
        double as_ = 1.0 + fhmn / fhmx;
        double at = (fhmx - fhmn) / fhmx;
        double t1 = as_ * au, t2 = at * au;
        double c = 1.0 / (sqrt(1.0 + t1 * t1) + sqrt(1.0 + t2 * t2));
        double sm = (fhmn * c) * au; *ssmin = sm + sm;
        *ssmax = ga / (c + c);
      }
    }
  }
}

static __device__ void dlasv2_(double f, double g, double h,
                               double* ssmin, double* ssmax,
                               double* snr, double* csr, double* snl, double* csl) {
  double ft = f, fa = fabs(f), ht = h, ha = fabs(h);
  int pmax = 1;
  bool swp = (ha > fa);
  if (swp) { pmax = 3; double t = ft; ft = ht; ht = t; t = fa; fa = ha; ha = t; }
  double gt = g, ga = fabs(g);
  double clt = 0, crt = 0, slt = 0, srt = 0;
  if (ga == 0.0) {
    *ssmin = ha; *ssmax = fa; clt = 1.0; crt = 1.0; slt = 0.0; srt = 0.0;
  } else {
    bool gasmal = true;
    if (ga > fa) {
      pmax = 2;
      if ((fa / ga) < DEPS) {
        gasmal = false;
        *ssmax = ga;
        *ssmin = (ha > 1.0) ? (fa / (ga / ha)) : ((fa / ga) * ha);
        clt = 1.0; slt = ht / gt; srt = 1.0; crt = ft / gt;
      }
    }
    if (gasmal) {
      double dd = fa - ha;
      double l = (dd == fa) ? 1.0 : (dd / fa);
      double mq = gt / ft;
      double t = 2.0 - l;
      double mm = mq * mq, tt = t * t;
      double s = sqrt(tt + mm);
      double r = (l == 0.0) ? fabs(mq) : sqrt(l * l + mm);
      double a = 0.5 * (s + r);
      *ssmin = ha / a;
      *ssmax = fa * a;
      if (mm == 0.0) {
        if (l == 0.0) t = copysign(2.0, ft) * copysign(1.0, gt);
        else t = gt / copysign(dd, ft) + mq / t;
      } else {
        t = (mq / (s + t) + mq / (r + l)) * (1.0 + a);
      }
      double l2 = sqrt(t * t + 4.0);
      crt = 2.0 / l2;
      srt = t / l2;
      clt = (crt + srt * mq) / a;
      slt = (ht / ft) * srt / a;
    }
  }
  if (swp) { *csl = srt; *snl = crt; *csr = slt; *snr = clt; }
  else { *csl = clt; *snl = slt; *csr = crt; *snr = srt; }
  double tsign = 0.0;
  if (pmax == 1) tsign = copysign(1.0, *csr) * copysign(1.0, *csl) * copysign(1.0, f);
  if (pmax == 2) tsign = copysign(1.0, *snr) * copysign(1.0, *csl) * copysign(1.0, g);
  if (pmax == 3) tsign = copysign(1.0, *snr) * copysign(1.0, *snl) * copysign(1.0, h);
  *ssmax = copysign(*ssmax, tsign);
  *ssmin = copysign(*ssmin, tsign * copysign(1.0, f) * copysign(1.0, h));
}

static __device__ void dbdsqr3(double d[3], double e[2], double VT[3][3], double U[3][3]) {
  const int n = 3;
  double tolmul = fmax(10.0, fmin(100.0, pow(DEPS, -0.125)));
  double tol = tolmul * DEPS;
  double thresh;
  {
    double sminoa = fabs(d[0]);
    if (sminoa != 0.0) {
      double mu = sminoa;
      for (int i = 1; i < n; ++i) {
        mu = fabs(d[i]) * (mu / (mu + fabs(e[i - 1])));
        sminoa = fmin(sminoa, mu);
        if (sminoa == 0.0) break;
      }
    }
    sminoa = sminoa / sqrt((double)n);
    thresh = fmax(tol * sminoa, 6.0 * n * n * DUNFL);
  }
  int maxit = 6 * n * n;
  int iter = 0, oldll = -1, oldm = -1, idir = 0;
  int m = n;
  double sminl = 0.0;
  int guard = 0;
  while (true) {
    if (m <= 1) break;
    if (iter > maxit) break;
    if (++guard > 500) break;
    double smaxb = fabs(d[m - 1]);
    int ll = 0; bool found = false;
    for (int lll = 1; lll <= m - 1; ++lll) {
      int l = m - lll;
      double abss = fabs(d[l - 1]);
      double abse = fabs(e[l - 1]);
      if (abse <= thresh) { ll = l; found = true; break; }
      smaxb = fmax(smaxb, fmax(abss, abse));
    }
    if (found) {
      e[ll - 1] = 0.0;
      if (ll == m - 1) { m = m - 1; continue; }
      ll = ll + 1;
    } else ll = 1;
    if (ll == m - 1) {
      double sigmn, sigmx, sinr, cosr, sinl2, cosl2;
      dlasv2_(d[m - 2], e[m - 2], d[m - 1], &sigmn, &sigmx, &sinr, &cosr, &sinl2, &cosl2);
      d[m - 2] = sigmx; d[m - 1] = sigmn; e[m - 2] = 0.0;
      for (int j = 0; j < 3; ++j) {
        double t1 = VT[m - 2][j], t2 = VT[m - 1][j];
        VT[m - 2][j] = cosr * t1 + sinr * t2;
        VT[m - 1][j] = cosr * t2 - sinr * t1;
      }
      for (int i2 = 0; i2 < 3; ++i2) {
        double t1 = U[i2][m - 2], t2 = U[i2][m - 1];
        U[i2][m - 2] = cosl2 * t1 + sinl2 * t2;
        U[i2][m - 1] = cosl2 * t2 - sinl2 * t1;
      }
      m -= 2;
      continue;
    }
    if (ll > oldm || m < oldll)
      idir = (fabs(d[ll - 1]) >= fabs(d[m - 1])) ? 1 : 2;
    if (idir == 1) {
      if (fabs(e[m - 2]) <= tol * fabs(d[m - 1])) { e[m - 2] = 0.0; continue; }
      double mu = fabs(d[ll - 1]); sminl = mu;
      bool conv = true;
      for (int lll = ll; lll <= m - 1; ++lll) {
        if (fabs(e[lll - 1]) > tol * mu) { conv = false; break; }
        mu = fabs(d[lll]) * (mu / (mu + fabs(e[lll - 1])));
        sminl = fmin(sminl, mu);
      }
      if (conv) { e[m - 2] = 0.0; continue; }
    } else {
      if (fabs(e[ll - 1]) <= tol * fabs(d[ll - 1])) { e[ll - 1] = 0.0; continue; }
      double mu = fabs(d[m - 1]); sminl = mu;
      bool conv = true;
      for (int lll = m - 1; lll >= ll; --lll) {
        if (fabs(e[lll - 1]) > tol * mu) { conv = false; break; }
        mu = fabs(d[lll - 1]) * (mu / (mu + fabs(e[lll - 1])));
        sminl = fmin(sminl, mu);
      }
      if (conv) { e[ll - 1] = 0.0; continue; }
    }
    oldll = ll; oldm = m;
    double shift = 0.0, rr;
    if (!(n * tol * (sminl / smaxb) <= fmax(DEPS, 0.01 * tol))) {
      double sll;
      if (idir == 1) { sll = fabs(d[ll - 1]); dlas2_(d[m - 2], e[m - 2], d[m - 1], &shift, &rr); }
      else { sll = fabs(d[m - 1]); dlas2_(d[ll - 1], e[ll - 1], d[ll], &shift, &rr); }
      if (sll > 0.0) { double q = shift / sll; if (q * q < DEPS) shift = 0.0; }
    }
    iter += m - ll;
    double csv[2], snv[2], ocsv[2], osnv[2];
    int cnt = 0;
    if (shift == 0.0) {
      if (idir == 1) {
        double cs = 1.0, oldcs = 1.0, sn = 0.0, oldsn = 0.0, r;
        for (int i = ll; i <= m - 1; ++i) {
          dlartg_(d[i - 1] * cs, e[i - 1], &cs, &sn, &r);
          if (i > ll) e[i - 2] = oldsn * r;
          dlartg_(oldcs * r, d[i] * sn, &oldcs, &oldsn, &d[i - 1]);
          csv[cnt] = cs; snv[cnt] = sn; ocsv[cnt] = oldcs; osnv[cnt] = oldsn; cnt++;
        }
        double hh = d[m - 1] * cs;
        d[m - 1] = hh * oldcs;
        e[m - 2] = hh * oldsn;
        for (int k = 0; k < cnt; ++k) {
          int r0 = ll - 1 + k, r1 = r0 + 1;
          for (int j = 0; j < 3; ++j) {
            double t1 = VT[r0][j], t2 = VT[r1][j];
            VT[r0][j] = snv[k] * t2 + csv[k] * t1;
            VT[r1][j] = csv[k] * t2 - snv[k] * t1;
          }
        }
        for (int k = 0; k < cnt; ++k) {
          int c0 = ll - 1 + k, c1 = c0 + 1;
          for (int i2 = 0; i2 < 3; ++i2) {
            double t1 = U[i2][c0], t2 = U[i2][c1];
            U[i2][c0] = osnv[k] * t2 + ocsv[k] * t1;
            U[i2][c1] = ocsv[k] * t2 - osnv[k] * t1;
          }
        }
        if (fabs(e[m - 2]) <= thresh) e[m - 2] = 0.0;
      } else {
        double cs = 1.0, oldcs = 1.0, sn = 0.0, oldsn = 0.0, r;
        for (int i = m; i >= ll + 1; --i) {
          dlartg_(d[i - 1] * cs, e[i - 2], &cs, &sn, &r);
          if (i < m) e[i - 1] = oldsn * r;
          dlartg_(oldcs * r, d[i - 2] * sn, &oldcs, &oldsn, &d[i - 1]);
          int k = i - ll - 1;
          csv[k] = cs; snv[k] = -sn; ocsv[k] = oldcs; osnv[k] = -oldsn; cnt++;
        }
        double hh = d[ll - 1] * cs;
        d[ll - 1] = hh * oldcs;
        e[ll - 1] = hh * oldsn;
        for (int k = cnt - 1; k >= 0; --k) {
          int r0 = ll - 1 + k, r1 = r0 + 1;
          for (int j = 0; j < 3; ++j) {
            double t1 = VT[r0][j], t2 = VT[r1][j];
            VT[r0][j] = osnv[k] * t2 + ocsv[k] * t1;
            VT[r1][j] = ocsv[k] * t2 - osnv[k] * t1;
          }
        }
        for (int k = cnt - 1; k >= 0; --k) {
          int c0 = ll - 1 + k, c1 = c0 + 1;
          for (int i2 = 0; i2 < 3; ++i2) {
            double t1 = U[i2][c0], t2 = U[i2][c1];
            U[i2][c0] = snv[k] * t2 + csv[k] * t1;
            U[i2][c1] = csv[k] * t2 - snv[k] * t1;
          }
        }
        if (fabs(e[ll - 1]) <= thresh) e[ll - 1] = 0.0;
      }
    } else {
      if (idir == 1) {
        double f = (fabs(d[ll - 1]) - shift) * (copysign(1.0, d[ll - 1]) + shift / d[ll - 1]);
        double g = e[ll - 1];
        double cosr, sinr, cosl2, sinl2, r;
        for (int i = ll; i <= m - 1; ++i) {
          dlartg_(f, g, &cosr, &sinr, &r);
          if (i > ll) e[i - 2] = r;
          f = cosr * d[i - 1] + sinr * e[i - 1];
          e[i - 1] = cosr * e[i - 1] - sinr * d[i - 1];
          g = sinr * d[i];
          d[i] = cosr * d[i];
          dlartg_(f, g, &cosl2, &sinl2, &r);
          d[i - 1] = r;
          f = cosl2 * e[i - 1] + sinl2 * d[i];
          d[i] = cosl2 * d[i] - sinl2 * e[i - 1];
          if (i < m - 1) {
            g = sinl2 * e[i];
            e[i] = cosl2 * e[i];
          }
          csv[cnt] = cosr; snv[cnt] = sinr; ocsv[cnt] = cosl2; osnv[cnt] = sinl2; cnt++;
        }
        e[m - 2] = f;
        for (int k = 0; k < cnt; ++k) {
          int r0 = ll - 1 + k, r1 = r0 + 1;
          for (int j = 0; j < 3; ++j) {
            double t1 = VT[r0][j], t2 = VT[r1][j];
            VT[r0][j] = snv[k] * t2 + csv[k] * t1;
            VT[r1][j] = csv[k] * t2 - snv[k] * t1;
          }
        }
        for (int k = 0; k < cnt; ++k) {
          int c0 = ll - 1 + k, c1 = c0 + 1;
          for (int i2 = 0; i2 < 3; ++i2) {
            double t1 = U[i2][c0], t2 = U[i2][c1];
            U[i2][c0] = osnv[k] * t2 + ocsv[k] * t1;
            U[i2][c1] = ocsv[k] * t2 - osnv[k] * t1;
          }
        }
        if (fabs(e[m - 2]) <= thresh) e[m - 2] = 0.0;
      } else {
        double f = (fabs(d[m - 1]) - shift) * (copysign(1.0, d[m - 1]) + shift / d[m - 1]);
        double g = e[m - 2];
        for (int i = m; i >= ll + 1; --i) {
          double cosr, sinr, cosl2, sinl2, r;
          dlartg_(f, g, &cosr, &sinr, &r);
          if (i < m) e[i - 1] = r;
          f = cosr * d[i - 1] + sinr * e[i - 2];
          e[i - 2] = cosr * e[i - 2] - sinr * d[i - 1];
          g = sinr * d[i - 2];
          d[i - 2] = cosr * d[i - 2];
          dlartg_(f, g, &cosl2, &sinl2, &r);
          d[i - 1] = r;
          f = cosl2 * e[i - 2] + sinl2 * d[i - 2];
          d[i - 2] = cosl2 * d[i - 2] - sinl2 * e[i - 2];
          if (i > ll + 1) {
            g = sinl2 * e[i - 3];
            e[i - 3] = cosl2 * e[i - 3];
          }
          int k = i - ll - 1;
          ocsv[k] = cosl2; osnv[k] = -sinl2; csv[k] = cosr; snv[k] = -sinr; cnt++;
        }
        e[ll - 1] = f;
        for (int k = cnt - 1; k >= 0; --k) {
          int r0 = ll - 1 + k, r1 = r0 + 1;
          for (int j = 0; j < 3; ++j) {
            double t1 = VT[r0][j], t2 = VT[r1][j];
            VT[r0][j] = snv[k] * t2 + csv[k] * t1;
            VT[r1][j] = csv[k] * t2 - snv[k] * t1;
          }
        }
        for (int k = cnt - 1; k >= 0; --k) {
          int c0 = ll - 1 + k, c1 = c0 + 1;
          for (int i2 = 0; i2 < 3; ++i2) {
            double t1 = U[i2][c0], t2 = U[i2][c1];
            U[i2][c0] = osnv[k] * t2 + ocsv[k] * t1;
            U[i2][c1] = ocsv[k] * t2 - osnv[k] * t1;
          }
        }
        if (fabs(e[ll - 1]) <= thresh) e[ll - 1] = 0.0;
      }
    }
  }
  for (int i = 0; i < n; ++i)
    if (d[i] < 0.0) { d[i] = -d[i]; for (int j = 0; j < 3; ++j) VT[i][j] = -VT[i][j]; }
  for (int i = 1; i <= n - 1; ++i) {
    int isub = 1; double smn = d[0];
    for (int j = 2; j <= n + 1 - i; ++j)
      if (d[j - 1] <= smn) { isub = j; smn = d[j - 1]; }
    if (isub != n + 1 - i) {
      int a = isub - 1, b2 = n - i;
      double t = d[a]; d[a] = d[b2]; d[b2] = t;
      for (int j = 0; j < 3; ++j) { t = VT[a][j]; VT[a][j] = VT[b2][j]; VT[b2][j] = t; }
      for (int j = 0; j < 3; ++j) { t = U[j][a]; U[j][a] = U[j][b2]; U[j][b2] = t; }
    }
  }
}

__global__ void k_svd(const float* __restrict__ Fx, const float* __restrict__ Fy,
                      float* __restrict__ out, int B) {
  int b = blockIdx.x;
  if (threadIdx.x != 0) return;
  double A[3][3];
  for (int d = 0; d < 3; ++d)
    for (int e = 0; e < 3; ++e) {
      double s = 0.0;
      for (int c = 0; c < 32; ++c)
        s += (double)Fx[((size_t)b * 32 + c) * 3 + d] * (double)Fy[((size_t)b * 32 + c) * 3 + e];
      A[d][e] = s;
    }
  double dg[3], eg[2], tauq0, tauq1, taup0;
  double v1_1 = 0, v1_2 = 0, v2_1 = 0, w1 = 0;
  {
    double alpha = A[0][0];
    double xn = sqrt(A[1][0] * A[1][0] + A[2][0] * A[2][0]);
    if (xn == 0.0) { tauq0 = 0.0; dg[0] = alpha; }
    else {
      double beta = -copysign(sqrt(alpha * alpha + xn * xn), alpha);
      tauq0 = (beta - alpha) / beta;
      double scal = 1.0 / (alpha - beta);
      v1_1 = A[1][0] * scal; v1_2 = A[2][0] * scal;
      dg[0] = beta;
    }
    for (int j = 1; j < 3; ++j) {
      double w = A[0][j] + v1_1 * A[1][j] + v1_2 * A[2][j];
      w *= tauq0;
      A[0][j] -= w; A[1][j] -= w * v1_1; A[2][j] -= w * v1_2;
    }
  }
  {
    double alpha = A[0][1];
    double xn = fabs(A[0][2]);
    if (xn == 0.0) { taup0 = 0.0; eg[0] = alpha; }
    else {
      double beta = -copysign(sqrt(alpha * alpha + xn * xn), alpha);
      taup0 = (beta - alpha) / beta;
      w1 = A[0][2] / (alpha - beta);
      eg[0] = beta;
    }
    for (int i = 1; i < 3; ++i) {
      double t = A[i][1] + w1 * A[i][2];
      t *= taup0;
      A[i][1] -= t; A[i][2] -= t * w1;
    }
  }
  {
    double alpha = A[1][1];
    double xn = fabs(A[2][1]);
    if (xn == 0.0) { tauq1 = 0.0; dg[1] = alpha; }
    else {
      double beta = -copysign(sqrt(alpha * alpha + xn * xn), alpha);
      tauq1 = (beta - alpha) / beta;
      v2_1 = A[2][1] / (alpha - beta);
      dg[1] = beta;
    }
    double w = A[1][2] + v2_1 * A[2][2];
    w *= tauq1;
    A[1][2] -= w; A[2][2] -= w * v2_1;
  }
  eg[1] = A[1][2];
  dg[2] = A[2][2];
  double U[3][3] = {{1, 0, 0}, {0, 1, 0}, {0, 0, 1}};
  double VT[3][3] = {{1, 0, 0}, {0, 1, 0}, {0, 0, 1}};
  dbdsqr3(dg, eg, VT, U);
  for (int j = 0; j < 3; ++j) {
    double w = U[1][j] + v2_1 * U[2][j];
    w *= tauq1;
    U[1][j] -= w; U[2][j] -= w * v2_1;
  }
  for (int j = 0; j < 3; ++j) {
    double w = U[0][j] + v1_1 * U[1][j] + v1_2 * U[2][j];
    w *= tauq0;
    U[0][j] -= w; U[1][j] -= w * v1_1; U[2][j] -= w * v1_2;
  }
  for (int r = 0; r < 3; ++r) {
    double t = VT[r][1] + w1 * VT[r][2];
    t *= taup0;
    VT[r][1] -= t; VT[r][2] -= t * w1;
  }
  for (int i = 0; i < 3; ++i)
    for (int j = 0; j < 3; ++j) {
      double r = 0;
      for (int k = 0; k < 3; ++k) r += U[i][k] * VT[j][k];
      out[b * 9 + i * 3 + j] = (float)r;
    }
  for (int dd = 0; dd < 3; ++dd) {
    float sx = 0.f, sy = 0.f;
    for (int c = 0; c < 32; ++c) {
      float vx = Fx[((size_t)b * 32 + c) * 3 + dd];
      float vy = Fy[((size_t)b * 32 + c) * 3 + dd];
      sx = fmaf(vx, vx, sx);
      sy = fmaf(vy, vy, sy);
    }
    out[B * 9 + b * 3 + dd] = sqrtf(sy) / sqrtf(sx);
  }
}

extern "C" void kernel_launch(void* const* d_in, const int* in_sizes, int n_in,
                              void* d_out, int out_size, void* d_ws, size_t ws_size,
                              hipStream_t stream) {
  (void)in_sizes; (void)n_in; (void)out_size; (void)ws_size;
  const int B = 2, N0 = 2048;
  const float* W[24];
  for (int i = 0; i < 24; ++i) W[i] = (const float*)d_in[i];

  float* ws = (float*)d_ws;
  const size_t P = (size_t)B * 64 * 3 * 2048;  // 786432 floats
  float* bufA = ws;
  float* bufB = bufA + P;
  float* bufC = bufB + P;
  float* bufD = bufC + P;
  float* bufApm = bufD + P;
  float* bufBpm = bufApm + P;
  float* C1 = bufBpm + P;
  float* C2 = C1 + P;
  float* C3 = C2 + P;
  float* C4 = C3 + P;
  float* C5 = C4 + P;
  float* M1 = C5 + P;
  float* M2 = M1 + P;
  float* M3 = M2 + P;
  float* M4 = M3 + P;
  float* M5 = M4 + P;
  float* M6 = M5 + P;
  float* M7 = M6 + P;
  float* M8 = M7 + P;
  float* M9 = M8 + P;
  float* M10 = M9 + P;
  float* px = M10 + P;               // B*3*2048 = 12288
  float* py = px + 12288;
  float* dps = py + 12288;           // 4096
  float* xx0 = dps + 4096;           // 4096
  float* xx1 = xx0 + 4096;           // 4096
  float* meanX = xx1 + 4096;         // 384
  float* meanY = meanX + 384;
  float* cbX = meanY + 384;
  float* cbY = cbX + 384;
  float* blkX = cbY + 384;           // 768
  float* blkY = blkX + 768;
  float* Fxb = blkY + 768;           // 192
  float* Fyb = Fxb + 192;
  int* idxA = (int*)(Fyb + 192);     // 65536
  int* idxB = idxA + 65536;
  int* sel = idxB + 65536;           // 2048

  auto knn = [&](const float* xa, const float* xb2, int D, int N, int* ia, int* ib, int ns) {
    k_xx2<<<dim3((N + 255) / 256, B, ns), 256, 0, stream>>>(xa, xb2, xx0, xx1, D, N);
    dim3 g2(N / 4, B, ns);
    if (D == 192) k_knn2<192><<<g2, 256, 0, stream>>>(xa, xb2, xx0, xx1, ia, ib, N);
    else          k_knn2<3><<<g2, 256, 0, stream>>>(xa, xb2, xx0, xx1, ia, ib, N);
  };

  const float* fx = W[0];
  const float* fy = W[1];
  int N = N0;
  for (int blk = 0; blk < 2; ++blk) {
    int D = (blk == 0) ? 3 : 192;
    const float* dgw = W[blk ? 12 : 2]; const float* dgd = W[blk ? 13 : 3];
    const float* qw  = W[blk ? 14 : 4]; const float* qd  = W[blk ? 15 : 5];
    const float* kw  = W[blk ? 16 : 6]; const float* kd  = W[blk ? 17 : 7];
    const float* vw  = W[blk ? 18 : 8]; const float* vd  = W[blk ? 19 : 9];
    const float* gw  = W[blk ? 20 : 10]; const float* gd = W[blk ? 21 : 11];
    dim3 gP(B * N / 4);
    dim3 gL((3 * N + 255) / 256, B, 1);

    // ======== dgcnn, both sides in merged launches ========
    knn(fx, fy, D, N, idxA, idxB, 2);
    {
      LinSlots s{};  // stage1: W1*x, (W2-W1)*x for fx and fy
      int wsd = (blk == 0) ? 2 : 128;
      int off2 = (blk == 0) ? 1 : 64;
      const float* Xs[4] = {fx, fx, fy, fy};
      float* cms[4] = {C1, C2, C3, C4};
      float* pms[4] = {M1, M2, M3, M4};
      for (int i = 0; i < 4; ++i) {
        s.W[i] = dgw; s.X[i] = Xs[i]; s.bias[i] = nullptr;
        s.cm[i] = cms[i]; s.pm[i] = pms[i];
        s.ws[i] = wsd; s.woff[i] = (i & 1) ? off2 : 0; s.sub[i] = (i & 1);
      }
      gL.z = 16;
      if (blk == 0) k_linm<1><<<gL, 256, 0, stream>>>(s, N);
      else          k_linm<64><<<gL, 256, 0, stream>>>(s, N);
    }
    {
      LinSlots s{};  // stage2: Wd * each
      const float* Xs[4] = {C1, C2, C3, C4};
      float* pms[4] = {M5, M6, M7, M8};
      for (int i = 0; i < 4; ++i) {
        s.W[i] = dgd; s.X[i] = Xs[i]; s.bias[i] = nullptr;
        s.cm[i] = nullptr; s.pm[i] = pms[i];
        s.ws[i] = 64; s.woff[i] = 0; s.sub[i] = 0;
      }
      gL.z = 16;
      k_linm<64><<<gL, 256, 0, stream>>>(s, N);
    }
    k_edge2<<<dim3(B * N / 4, 2), 256, 0, stream>>>(M1, M2, M5, M6, M3, M4, M7, M8,
                                                    idxA, idxB, bufA, bufB, N);

    // ======== cross_context #1: x=bufA, y=bufB -> bufC ========
    knn(bufB, bufB, 192, N, idxB, idxB, 1);
    {
      LinSlots s{};  // stage1: q,k1,k2,v1,v2
      const float* Wm[5] = {qw, kw, kw, vw, vw};
      const float* Xs[5] = {bufA, bufB, bufB, bufB, bufB};
      float* cms[5] = {C1, C2, C3, C4, C5};
      float* pms[5] = {M1, M3, M4, M5, M6};
      int wss[5] = {64, 128, 128, 128, 128};
      int offs[5] = {0, 0, 64, 0, 64};
      int subs[5] = {0, 0, 1, 0, 1};
      for (int i = 0; i < 5; ++i) {
        s.W[i] = Wm[i]; s.X[i] = Xs[i]; s.bias[i] = nullptr;
        s.cm[i] = cms[i]; s.pm[i] = pms[i];
        s.ws[i] = wss[i]; s.woff[i] = offs[i]; s.sub[i] = subs[i];
      }
      gL.z = 20;
      k_linm<64><<<gL, 256, 0, stream>>>(s, N);
    }
    {
      LinSlots s{};  // stage2: qd,kd,kd,vd,vd
      const float* Wm[5] = {qd, kd, kd, vd, vd};
      const float* Xs[5] = {C1, C2, C3, C4, C5};
      float* pms[5] = {M2, M7, M8, M9, M10};
      for (int i = 0; i < 5; ++i) {
        s.W[i] = Wm[i]; s.X[i] = Xs[i]; s.bias[i] = nullptr;
        s.cm[i] = nullptr; s.pm[i] = pms[i];
        s.ws[i] = 64; s.woff[i] = 0; s.sub[i] = 0;
      }
      gL.z = 20;
      k_linm<64><<<gL, 256, 0, stream>>>(s, N);
    }
    k_att<<<gP, 256, 0, stream>>>(bufA, M1, M2, M3, M4, M7, M8, M5, M6, M9, M10, idxB, bufC, N);

    // ======== cross_context #2: x=bufB, y=bufC -> bufD ========
    knn(bufC, bufC, 192, N, idxA, idxA, 1);
    {
      LinSlots s{};
      const float* Wm[5] = {qw, kw, kw, vw, vw};
      const float* Xs[5] = {bufB, bufC, bufC, bufC, bufC};
      float* cms[5] = {C1, C2, C3, C4, C5};
      float* pms[5] = {M1, M3, M4, M5, M6};
      int wss[5] = {64, 128, 128, 128, 128};
      int offs[5] = {0, 0, 64, 0, 64};
      int subs[5] = {0, 0, 1, 0, 1};
      for (int i = 0; i < 5; ++i) {
        s.W[i] = Wm[i]; s.X[i] = Xs[i]; s.bias[i] = nullptr;
        s.cm[i] = cms[i]; s.pm[i] = pms[i];
        s.ws[i] = wss[i]; s.woff[i] = offs[i]; s.sub[i] = subs[i];
      }
      gL.z = 20;
      k_linm<64><<<gL, 256, 0, stream>>>(s, N);
    }
    {
      LinSlots s{};
      const float* Wm[5] = {qd, kd, kd, vd, vd};
      const float* Xs[5] = {C1, C2, C3, C4, C5};
      float* pms[5] = {M2, M7, M8, M9, M10};
      for (int i = 0; i < 5; ++i) {
        s.W[i] = Wm[i]; s.X[i] = Xs[i]; s.bias[i] = nullptr;
        s.cm[i] = nullptr; s.pm[i] = pms[i];
        s.ws[i] = 64; s.woff[i] = 0; s.sub[i] = 0;
      }
      gL.z = 20;
      k_linm<64><<<gL, 256, 0, stream>>>(s, N);
    }
    k_att<<<gP, 256, 0, stream>>>(bufB, M1, M2, M3, M4, M7, M8, M5, M6, M9, M10, idxA, bufD, N);

    // ======== global fuse ========
    k_cmean2<<<dim3(192, B, 2), 256, 0, stream>>>(bufC, bufD, meanX, meanY, N, 192, 0, 1.f / (float)N);
    k_gbias2<<<dim3(B, 2), 192, 0, stream>>>(gw, meanX, meanY, cbX, cbY);
    {
      LinSlots s{};  // gw on both sides (with bias)
      const float* Xs[2] = {bufC, bufD};
      const float* bs[2] = {cbX, cbY};
      float* cms[2] = {C1, C2};
      float* pms[2] = {M1, M2};
      for (int i = 0; i < 2; ++i) {
        s.W[i] = gw; s.X[i] = Xs[i]; s.bias[i] = bs[i];
        s.cm[i] = cms[i]; s.pm[i] = pms[i];
        s.ws[i] = 128; s.woff[i] = 0; s.sub[i] = 0;
      }
      gL.z = 8;
      k_linm<64><<<gL, 256, 0, stream>>>(s, N);
    }
    {
      LinSlots s{};  // gd on both sides
      const float* Xs[2] = {C1, C2};
      float* pms[2] = {M3, M4};
      for (int i = 0; i < 2; ++i) {
        s.W[i] = gd; s.X[i] = Xs[i]; s.bias[i] = nullptr;
        s.cm[i] = nullptr; s.pm[i] = pms[i];
        s.ws[i] = 64; s.woff[i] = 0; s.sub[i] = 0;
      }
      gL.z = 8;
      k_linm<64><<<gL, 256, 0, stream>>>(s, N);
    }
    k_gfin<<<dim3(B * N / 4, 2), 256, 0, stream>>>(M1, M3, M2, M4, bufA, bufApm, bufB, bufBpm, N);

    // ======== score + top-half selection ========
    int Nh = N / 2;
    k_parmean<<<dim3((B * 3 * N + 255) / 256), 256, 0, stream>>>(bufA, bufB, px, py, N, B);
    k_dotphi<<<dim3((B * N + 255) / 256), 256, 0, stream>>>(bufA, bufB, px, py, dps, N, B);
    k_topsel<<<dim3(B), 1024, 0, stream>>>(dps, sel, N, Nh);
    k_gather<<<dim3(B * Nh / 4), 256, 0, stream>>>(bufApm, bufBpm, sel, bufC, bufD, N, Nh);
    k_cmean2<<<dim3(192, B, 2), 256, 0, stream>>>(bufC, bufD, blkX, blkY, Nh, 384, blk * 192, 1.f / (float)Nh);
    fx = bufC; fy = bufD;
    N = Nh;
  }
  k_head<<<dim3(2, B), 96, 0, stream>>>(blkX, blkY, W[22], W[23], Fxb, Fyb);
  k_svd<<<dim3(B), 64, 0, stream>>>(Fxb, Fyb, (float*)d_out, B);
}

// Round 11
// 1378.326 us; speedup vs baseline: 2.5411x; 2.5006x over previous
//
#include <hip/hip_runtime.h>
#include <math.h>

#define SLOPE 0.2f
#define EPSV 1e-12f
#define NEGINF (-3.0e38f)

static __device__ __forceinline__ float lrelu_combine(float xv, float dvv, float dot, float dsq) {
  float xneg = xv - dot / (dsq + EPSV) * dvv;
  float w = (dot >= 0.f) ? xv : xneg;
  return SLOPE * xv + (1.f - SLOPE) * w;
}

// ---------------- squared norms per point, up to 2 inputs (side = blockIdx.z) ----------------
__global__ void k_xx2(const float* __restrict__ x0, const float* __restrict__ x1,
                      float* __restrict__ xxA, float* __restrict__ xxB, int D, int N) {
  int side = blockIdx.z;
  const float* x = side ? x1 : x0;
  float* xx = side ? xxB : xxA;
  int b = blockIdx.y;
  int m = blockIdx.x * 256 + threadIdx.x;
  if (m >= N) return;
  const float* xp = x + (size_t)b * D * N + m;
  float s = 0.f;
  for (int d = 0; d < D; ++d) { float v = xp[(size_t)d * N]; s = fmaf(v, v, s); }
  xx[b * N + m] = s;
}

// ---------------- fused knn top-16 (round-7 proven: unroll 4, VGPR ~52, ~99us @ N=2048 D=192) ----
// 4 queries/block, 4 m-points/thread. Ascending-d fmaf chain, 2*dot - xxn - xxm; selection via
// float4 scan + 64-lane butterfly with (max, min-index) tie-break -> matches lax.top_k exactly.
template <int D>
__global__ void __launch_bounds__(256) k_knn2(const float* __restrict__ x0, const float* __restrict__ x1,
                                              const float* __restrict__ xxA, const float* __restrict__ xxB,
                                              int* __restrict__ idx0, int* __restrict__ idx1, int N) {
  int side = blockIdx.z;
  const float* x = side ? x1 : x0;
  const float* xx = side ? xxB : xxA;
  int* idx = side ? idx1 : idx0;
  __shared__ float qt[D * 4];
  __shared__ float dist[4][2048];
  __shared__ float xxq[4];
  int b = blockIdx.y, tid = threadIdx.x;
  int q0 = blockIdx.x * 4;
  const float* xb = x + (size_t)b * D * N;
  for (int i = tid; i < D * 4; i += 256) qt[i] = xb[(size_t)(i >> 2) * N + q0 + (i & 3)];
  if (tid < 4) xxq[tid] = xx[b * N + q0 + tid];
  __syncthreads();
  int kouter = N >> 10;
  for (int k = 0; k < kouter; ++k) {
    int m0 = tid + (k << 10);
    float4 a0 = {0, 0, 0, 0}, a1 = {0, 0, 0, 0}, a2 = {0, 0, 0, 0}, a3 = {0, 0, 0, 0};
#pragma unroll 4
    for (int d = 0; d < D; ++d) {
      const float4 q4 = *(const float4*)&qt[d * 4];
      const float* xr = xb + (size_t)d * N + m0;
      float v0 = xr[0], v1 = xr[256], v2 = xr[512], v3 = xr[768];
      a0.x = fmaf(q4.x, v0, a0.x); a0.y = fmaf(q4.y, v0, a0.y);
      a0.z = fmaf(q4.z, v0, a0.z); a0.w = fmaf(q4.w, v0, a0.w);
      a1.x = fmaf(q4.x, v1, a1.x); a1.y = fmaf(q4.y, v1, a1.y);
      a1.z = fmaf(q4.z, v1, a1.z); a1.w = fmaf(q4.w, v1, a1.w);
      a2.x = fmaf(q4.x, v2, a2.x); a2.y = fmaf(q4.y, v2, a2.y);
      a2.z = fmaf(q4.z, v2, a2.z); a2.w = fmaf(q4.w, v2, a2.w);
      a3.x = fmaf(q4.x, v3, a3.x); a3.y = fmaf(q4.y, v3, a3.y);
      a3.z = fmaf(q4.z, v3, a3.z); a3.w = fmaf(q4.w, v3, a3.w);
    }
    const float* xxb2 = xx + b * N + m0;
    float x0v = xxb2[0], x1v = xxb2[256], x2v = xxb2[512], x3v = xxb2[768];
    dist[0][m0]       = 2.f * a0.x - xxq[0] - x0v;
    dist[1][m0]       = 2.f * a0.y - xxq[1] - x0v;
    dist[2][m0]       = 2.f * a0.z - xxq[2] - x0v;
    dist[3][m0]       = 2.f * a0.w - xxq[3] - x0v;
    dist[0][m0 + 256] = 2.f * a1.x - xxq[0] - x1v;
    dist[1][m0 + 256] = 2.f * a1.y - xxq[1] - x1v;
    dist[2][m0 + 256] = 2.f * a1.z - xxq[2] - x1v;
    dist[3][m0 + 256] = 2.f * a1.w - xxq[3] - x1v;
    dist[0][m0 + 512] = 2.f * a2.x - xxq[0] - x2v;
    dist[1][m0 + 512] = 2.f * a2.y - xxq[1] - x2v;
    dist[2][m0 + 512] = 2.f * a2.z - xxq[2] - x2v;
    dist[3][m0 + 512] = 2.f * a2.w - xxq[3] - x2v;
    dist[0][m0 + 768] = 2.f * a3.x - xxq[0] - x3v;
    dist[1][m0 + 768] = 2.f * a3.y - xxq[1] - x3v;
    dist[2][m0 + 768] = 2.f * a3.z - xxq[2] - x3v;
    dist[3][m0 + 768] = 2.f * a3.w - xxq[3] - x3v;
  }
  __syncthreads();
  int g = tid >> 6, lane = tid & 63;
  float* dr = dist[g];
  int n = q0 + g;
  int imax = N >> 8;
  int* op = idx + ((size_t)b * N + n) * 16;
  for (int r = 0; r < 16; ++r) {
    float bv = NEGINF;
    int bi = N;
    for (int i = 0; i < imax; ++i) {
      int mb = i * 256 + lane * 4;
      float4 v = *(const float4*)&dr[mb];
      if (v.x > bv) { bv = v.x; bi = mb; }
      if (v.y > bv) { bv = v.y; bi = mb + 1; }
      if (v.z > bv) { bv = v.z; bi = mb + 2; }
      if (v.w > bv) { bv = v.w; bi = mb + 3; }
    }
#pragma unroll
    for (int s = 1; s < 64; s <<= 1) {
      float ov = __shfl_xor(bv, s, 64);
      int oi = __shfl_xor(bi, s, 64);
      if (ov > bv || (ov == bv && oi < bi)) { bv = ov; bi = oi; }
    }
    if (lane == 0) { op[r] = bi; dr[bi] = NEGINF; }
  }
}

// ---------------- multi-slot 64-out linear (slot = blockIdx.z>>2), dual-layout output ----------------
struct LinSlots {
  const float* W[5]; const float* X[5]; const float* bias[5];
  float* cm[5]; float* pm[5];
  int ws[5]; int woff[5]; int sub[5];
};

template <int KT>
__global__ void __launch_bounds__(256) k_linm(LinSlots S, int N) {
  __shared__ float wl[64 * ((KT + 3) & ~3)];
  const int KP = (KT + 3) & ~3;
  int slot = blockIdx.z >> 2;
  int oc = (blockIdx.z & 3) * 16;
  const float* W = S.W[slot];
  int ws = S.ws[slot], woff = S.woff[slot], sub = S.sub[slot];
  int tid = threadIdx.x;
  for (int i = tid; i < 64 * KT; i += 256) {
    int o = i / KT, k = i - o * KT;
    float v = W[o * ws + woff + k];
    if (sub) v -= W[o * ws + k];
    wl[o * KP + k] = v;
  }
  __syncthreads();
  int b = blockIdx.y;
  int j = blockIdx.x * 256 + tid;
  int M3 = 3 * N;
  if (j >= M3) return;
  const float* Xb = S.X[slot] + (size_t)b * KT * M3;
  float xv[KT];
#pragma unroll
  for (int k = 0; k < KT; ++k) xv[k] = Xb[(size_t)k * M3 + j];
  int d = j / N;
  const float* bias = S.bias[slot];
  float acc[16];
  if (bias) {
#pragma unroll
    for (int oo = 0; oo < 16; ++oo) acc[oo] = bias[b * 192 + (oc + oo) * 3 + d];
  } else {
#pragma unroll
    for (int oo = 0; oo < 16; ++oo) acc[oo] = 0.f;
  }
#pragma unroll
  for (int oo = 0; oo < 16; ++oo) {
    const float* wr = &wl[(oc + oo) * KP];
    float s = acc[oo];
#pragma unroll
    for (int k = 0; k < KT; ++k) s = fmaf(wr[k], xv[k], s);
    acc[oo] = s;
  }
  if (S.cm[slot]) {
    float* ob = S.cm[slot] + (size_t)b * 64 * M3;
#pragma unroll
    for (int oo = 0; oo < 16; ++oo) ob[(size_t)(oc + oo) * M3 + j] = acc[oo];
  }
  if (S.pm[slot]) {
    int n = j - d * N;
    float4* pp = (float4*)(S.pm[slot] + ((size_t)((b * N + n) * 3 + d)) * 64 + oc);
    pp[0] = make_float4(acc[0], acc[1], acc[2], acc[3]);
    pp[1] = make_float4(acc[4], acc[5], acc[6], acc[7]);
    pp[2] = make_float4(acc[8], acc[9], acc[10], acc[11]);
    pp[3] = make_float4(acc[12], acc[13], acc[14], acc[15]);
  }
}

// ---------------- edge conv, wave per point, side = blockIdx.y ----------------
__global__ void __launch_bounds__(256) k_edge2(const float* __restrict__ P1a, const float* __restrict__ P2a,
                                               const float* __restrict__ D1a, const float* __restrict__ D2a,
                                               const float* __restrict__ P1b, const float* __restrict__ P2b,
                                               const float* __restrict__ D1b, const float* __restrict__ D2b,
                                               const int* __restrict__ idxA, const int* __restrict__ idxB,
                                               float* __restrict__ outA, float* __restrict__ outB, int N) {
  int side = blockIdx.y;
  const float* P1 = side ? P1b : P1a;
  const float* P2 = side ? P2b : P2a;
  const float* D1 = side ? D1b : D1a;
  const float* D2 = side ? D2b : D2a;
  const int* idx = side ? idxB : idxA;
  float* out = side ? outB : outA;
  int tid = threadIdx.x;
  int p = blockIdx.x * 4 + (tid >> 6);
  int c = tid & 63;
  int b = p / N, n = p - b * N;
  size_t bn = ((size_t)(b * N + n) * 3) * 64 + c;
  float p2[3], d2[3];
#pragma unroll
  for (int d = 0; d < 3; ++d) { p2[d] = P2[bn + d * 64]; d2[d] = D2[bn + d * 64]; }
  const int* ip = idx + ((size_t)b * N + n) * 16;
  float acc0 = 0.f, acc1 = 0.f, acc2 = 0.f;
  for (int j = 0; j < 16; ++j) {
    int m = ip[j];
    size_t bm = ((size_t)(b * N + m) * 3) * 64 + c;
    float xl[3], dv[3];
#pragma unroll
    for (int d = 0; d < 3; ++d) {
      xl[d] = P1[bm + d * 64] + p2[d];
      dv[d] = D1[bm + d * 64] + d2[d];
    }
    float dot = xl[0] * dv[0] + xl[1] * dv[1] + xl[2] * dv[2];
    float dsq = dv[0] * dv[0] + dv[1] * dv[1] + dv[2] * dv[2];
    acc0 += lrelu_combine(xl[0], dv[0], dot, dsq);
    acc1 += lrelu_combine(xl[1], dv[1], dot, dsq);
    acc2 += lrelu_combine(xl[2], dv[2], dot, dsq);
  }
  size_t r0 = (size_t)((b * 64 + c) * 3) * N;
  out[r0 + n] = acc0 * (1.f / 16.f);
  out[r0 + N + n] = acc1 * (1.f / 16.f);
  out[r0 + 2 * (size_t)N + n] = acc2 * (1.f / 16.f);
}

// ---------------- fused Q-finisher + K-logits + softmax + V-attention + residual ----------------
__global__ void __launch_bounds__(256) k_att(const float* __restrict__ xres,
                                             const float* __restrict__ QXL, const float* __restrict__ QDV,
                                             const float* __restrict__ KP1, const float* __restrict__ KP2,
                                             const float* __restrict__ KD1, const float* __restrict__ KD2,
                                             const float* __restrict__ VP1, const float* __restrict__ VP2,
                                             const float* __restrict__ VD1, const float* __restrict__ VD2,
                                             const int* __restrict__ idx,
                                             float* __restrict__ out, int N) {
  int tid = threadIdx.x;
  int p = blockIdx.x * 4 + (tid >> 6);
  int c = tid & 63;
  int b = p / N, n = p - b * N;
  size_t bn = ((size_t)(b * N + n) * 3) * 64 + c;
  float qv[3], kp2[3], kd2[3], vp2[3], vd2[3];
  {  // inline qfin (exact arithmetic of the former k_qfin)
    float xl[3], dv[3];
#pragma unroll
    for (int d = 0; d < 3; ++d) { xl[d] = QXL[bn + d * 64]; dv[d] = QDV[bn + d * 64]; }
    float dot = xl[0] * dv[0] + xl[1] * dv[1] + xl[2] * dv[2];
    float dsq = dv[0] * dv[0] + dv[1] * dv[1] + dv[2] * dv[2];
    float z[3];
#pragma unroll
    for (int d = 0; d < 3; ++d) z[d] = lrelu_combine(xl[d], dv[d], dot, dsq);
    float n2 = z[0] * z[0] + z[1] * z[1] + z[2] * z[2];
    float cn2 = n2;
#pragma unroll
    for (int s = 1; s < 64; s <<= 1) cn2 += __shfl_xor(cn2, s, 64);
    float n_o = sqrtf(n2), cn = sqrtf(cn2);
    float scl = (n_o / fmaxf(cn, EPSV)) / fmaxf(n_o, EPSV);
#pragma unroll
    for (int d = 0; d < 3; ++d) qv[d] = z[d] * scl;
  }
#pragma unroll
  for (int d = 0; d < 3; ++d) {
    kp2[d] = KP2[bn + d * 64];
    kd2[d] = KD2[bn + d * 64];
    vp2[d] = VP2[bn + d * 64];
    vd2[d] = VD2[bn + d * 64];
  }
  const int* ip = idx + ((size_t)b * N + n) * 16;
  float l[16];
#pragma unroll
  for (int j = 0; j < 16; ++j) {
    int m = ip[j];
    size_t bm = ((size_t)(b * N + m) * 3) * 64 + c;
    float xl[3], dv[3];
#pragma unroll
    for (int d = 0; d < 3; ++d) {
      xl[d] = KP1[bm + d * 64] + kp2[d];
      dv[d] = KD1[bm + d * 64] + kd2[d];
    }
    float dot = xl[0] * dv[0] + xl[1] * dv[1] + xl[2] * dv[2];
    float dsq = dv[0] * dv[0] + dv[1] * dv[1] + dv[2] * dv[2];
    float z[3];
#pragma unroll
    for (int d = 0; d < 3; ++d) z[d] = lrelu_combine(xl[d], dv[d], dot, dsq);
    float n2 = z[0] * z[0] + z[1] * z[1] + z[2] * z[2];
    float cn2 = n2;
#pragma unroll
    for (int s = 1; s < 64; s <<= 1) cn2 += __shfl_xor(cn2, s, 64);
    float n_o = sqrtf(n2), cn = sqrtf(cn2);
    float scl = (n_o / fmaxf(cn, EPSV)) / fmaxf(n_o, EPSV);
    float part = (z[0] * qv[0] + z[1] * qv[1] + z[2] * qv[2]) * scl;
#pragma unroll
    for (int s = 1; s < 32; s <<= 1) part += __shfl_xor(part, s, 32);
    part = __shfl(part, 0, 32);
    l[j] = part * 0.102062072615966f;  // 1/sqrt(96)
  }
  float mx = l[0];
#pragma unroll
  for (int j = 1; j < 16; ++j) mx = fmaxf(mx, l[j]);
  float sum = 0.f;
#pragma unroll
  for (int j = 0; j < 16; ++j) { l[j] = expf(l[j] - mx); sum += l[j]; }
  float inv = 1.f / sum;
#pragma unroll
  for (int j = 0; j < 16; ++j) l[j] *= inv;
  float acc0 = 0.f, acc1 = 0.f, acc2 = 0.f;
#pragma unroll
  for (int j = 0; j < 16; ++j) {
    int m = ip[j];
    float av = l[j];
    size_t bm = ((size_t)(b * N + m) * 3) * 64 + c;
    float xl[3], dv[3];
#pragma unroll
    for (int d = 0; d < 3; ++d) {
      xl[d] = VP1[bm + d * 64] + vp2[d];
      dv[d] = VD1[bm + d * 64] + vd2[d];
    }
    float dot = xl[0] * dv[0] + xl[1] * dv[1] + xl[2] * dv[2];
    float dsq = dv[0] * dv[0] + dv[1] * dv[1] + dv[2] * dv[2];
    acc0 = fmaf(av, lrelu_combine(xl[0], dv[0], dot, dsq), acc0);
    acc1 = fmaf(av, lrelu_combine(xl[1], dv[1], dot, dsq), acc1);
    acc2 = fmaf(av, lrelu_combine(xl[2], dv[2], dot, dsq), acc2);
  }
  size_t r0 = (size_t)((b * 64 + c) * 3) * N;
  out[r0 + n] = xres[r0 + n] + acc0;
  out[r0 + N + n] = xres[r0 + N + n] + acc1;
  out[r0 + 2 * (size_t)N + n] = xres[r0 + 2 * (size_t)N + n] + acc2;
}

// ---------------- g-fuse finisher: wave per point, side = blockIdx.y ----------------
__global__ void __launch_bounds__(256) k_gfin(const float* __restrict__ XLa, const float* __restrict__ DVa,
                                              const float* __restrict__ XLb, const float* __restrict__ DVb,
                                              float* __restrict__ outa, float* __restrict__ outpa,
                                              float* __restrict__ outb, float* __restrict__ outpb, int N) {
  int side = blockIdx.y;
  const float* XL = side ? XLb : XLa;
  const float* DV = side ? DVb : DVa;
  float* out = side ? outb : outa;
  float* outpm = side ? outpb : outpa;
  int tid = threadIdx.x;
  int p = blockIdx.x * 4 + (tid >> 6);
  int c = tid & 63;
  int b = p / N, n = p - b * N;
  size_t bn = ((size_t)(b * N + n) * 3) * 64 + c;
  float xl[3], dv[3];
#pragma unroll
  for (int d = 0; d < 3; ++d) { xl[d] = XL[bn + d * 64]; dv[d] = DV[bn + d * 64]; }
  float dot = xl[0] * dv[0] + xl[1] * dv[1] + xl[2] * dv[2];
  float dsq = dv[0] * dv[0] + dv[1] * dv[1] + dv[2] * dv[2];
  size_t r0 = (size_t)((b * 64 + c) * 3) * N;
#pragma unroll
  for (int d = 0; d < 3; ++d) {
    float z = lrelu_combine(xl[d], dv[d], dot, dsq);
    out[r0 + (size_t)d * N + n] = z;
    outpm[bn + d * 64] = z;
  }
}

// ---------------- bias for g-fuse, both sides in one launch ----------------
__global__ void k_gbias2(const float* __restrict__ gw, const float* __restrict__ meanX,
                         const float* __restrict__ meanY,
                         float* __restrict__ cbX, float* __restrict__ cbY) {
  int b = blockIdx.x, which = blockIdx.y, tid = threadIdx.x;  // 192 threads
  int o = tid / 3, d = tid - o * 3;
  const float* mb = (which ? meanY : meanX) + b * 192;
  float* cb = (which ? cbY : cbX);
  float s = 0.f;
  for (int c = 0; c < 64; ++c) s = fmaf(gw[o * 128 + 64 + c], mb[c * 3 + d], s);
  cb[b * 192 + tid] = s;
}

// ---------------- column mean over N for both arrays in one launch ----------------
__global__ void k_cmean2(const float* __restrict__ x1, const float* __restrict__ x2,
                         float* __restrict__ o1, float* __restrict__ o2,
                         int N, int ostride, int obase, float inv) {
  __shared__ float red[256];
  int b = blockIdx.y, cd = blockIdx.x, which = blockIdx.z, tid = threadIdx.x;
  const float* x = which ? x2 : x1;
  float* out = which ? o2 : o1;
  const float* p = x + ((size_t)b * 192 + cd) * N;
  float s = 0.f;
  for (int i = tid; i < N; i += 256) s += p[i];
  red[tid] = s;
  __syncthreads();
  for (int st = 128; st > 0; st >>= 1) {
    if (tid < st) red[tid] += red[tid + st];
    __syncthreads();
  }
  if (tid == 0) out[(size_t)b * ostride + obase + cd] = red[0] * inv;
}

// ---------------- channel-mean (fx_par pre-normalization) for both arrays ----------------
__global__ void k_parmean(const float* __restrict__ fx, const float* __restrict__ fy,
                          float* __restrict__ px, float* __restrict__ py, int N, int B) {
  int gi = blockIdx.x * 256 + threadIdx.x;
  int total = B * 3 * N;
  if (gi >= total) return;
  int b = gi / (3 * N);
  int r = gi - b * 3 * N;
  const float* fxb = fx + (size_t)b * 192 * N + r;
  const float* fyb = fy + (size_t)b * 192 * N + r;
  float sx = 0.f, sy = 0.f;
  for (int c = 0; c < 64; ++c) { sx += fxb[(size_t)c * 3 * N]; sy += fyb[(size_t)c * 3 * N]; }
  px[gi] = sx * (1.f / 64.f);
  py[gi] = sy * (1.f / 64.f);
}

// ---------------- score logits: sum_c (fx.px)(fy.py) (softmax+norm skipped: monotone) ----------------
__global__ void k_dotphi(const float* __restrict__ fx, const float* __restrict__ fy,
                         const float* __restrict__ px, const float* __restrict__ py,
                         float* __restrict__ dps, int N, int B) {
  int gi = blockIdx.x * 256 + threadIdx.x;
  if (gi >= B * N) return;
  int b = gi / N, n = gi - b * N;
  const float* fxb = fx + (size_t)b * 192 * N + n;
  const float* fyb = fy + (size_t)b * 192 * N + n;
  const float* pxb = px + (size_t)b * 3 * N + n;
  const float* pyb = py + (size_t)b * 3 * N + n;
  float acc = 0.f;
  for (int c = 0; c < 64; ++c) {
    float ax = 0.f, ay = 0.f;
    for (int d = 0; d < 3; ++d) {
      ax = fmaf(fxb[(size_t)(c * 3 + d) * N], pxb[(size_t)d * N], ax);
      ay = fmaf(fyb[(size_t)(c * 3 + d) * N], pyb[(size_t)d * N], ay);
    }
    acc = fmaf(ax, ay, acc);
  }
  dps[gi] = acc;
}

// ---------------- top-N/2 selection: bitonic sort (desc value, asc index) ----------------
__global__ void __launch_bounds__(1024) k_topsel(const float* __restrict__ dps,
                                                 int* __restrict__ sel, int N, int Nh) {
  __shared__ float kv[2048];
  __shared__ int ki[2048];
  int b = blockIdx.x, tid = threadIdx.x;
  for (int i = tid; i < N; i += 1024) { kv[i] = dps[b * N + i]; ki[i] = i; }
  __syncthreads();
  for (int kk = 2; kk <= N; kk <<= 1) {
    for (int jj = kk >> 1; jj > 0; jj >>= 1) {
      for (int i = tid; i < N; i += 1024) {
        int ixj = i ^ jj;
        if (ixj > i) {
          float va = kv[i], vb = kv[ixj];
          int ia = ki[i], ib = ki[ixj];
          bool aFirst = (va > vb) || (va == vb && ia < ib);
          bool up = ((i & kk) == 0);
          bool doswap = up ? (!aFirst) : aFirst;
          if (doswap) { kv[i] = vb; kv[ixj] = va; ki[i] = ib; ki[ixj] = ia; }
        }
      }
      __syncthreads();
    }
  }
  for (int i = tid; i < Nh; i += 1024) sel[b * Nh + i] = ki[i];
}

// ---------------- gather selected points (pm source, cm dest), wave per point ----------------
__global__ void __launch_bounds__(256) k_gather(const float* __restrict__ sxpm, const float* __restrict__ sypm,
                                                const int* __restrict__ sel,
                                                float* __restrict__ dx, float* __restrict__ dy,
                                                int N, int Nh) {
  int tid = threadIdx.x;
  int p = blockIdx.x * 4 + (tid >> 6);
  int c = tid & 63;
  int b = p / Nh, i = p - b * Nh;
  int s = sel[b * Nh + i];
  size_t bs = ((size_t)(b * N + s) * 3) * 64 + c;
  size_t r0 = (size_t)((b * 64 + c) * 3) * Nh;
#pragma unroll
  for (int d = 0; d < 3; ++d) {
    dx[r0 + (size_t)d * Nh + i] = sxpm[bs + d * 64];
    dy[r0 + (size_t)d * Nh + i] = sypm[bs + d * 64];
  }
}

// ---------------- final head: vn_lin_lrelu(concat blocks, h_w, h_d) ----------------
__global__ void k_head(const float* __restrict__ blkX, const float* __restrict__ blkY,
                       const float* __restrict__ hw, const float* __restrict__ hd,
                       float* __restrict__ Fx, float* __restrict__ Fy) {
  __shared__ float f[3][128];
  __shared__ float xl[3][32];
  __shared__ float dv[3][32];
  int which = blockIdx.x, b = blockIdx.y, tid = threadIdx.x;
  const float* blk = which ? blkY : blkX;
  float* F = which ? Fy : Fx;
  int o = tid & 31, dd = tid >> 5;
  for (int i = tid; i < 384; i += 96) f[i % 3][i / 3] = blk[(size_t)b * 384 + i];
  __syncthreads();
  float s = 0.f;
  for (int c = 0; c < 128; ++c) s = fmaf(hw[o * 128 + c], f[dd][c], s);
  xl[dd][o] = s;
  __syncthreads();
  float s2 = 0.f;
  for (int p = 0; p < 32; ++p) s2 = fmaf(hd[o * 32 + p], xl[dd][p], s2);
  dv[dd][o] = s2;
  __syncthreads();
  float dot = xl[0][o] * dv[0][o] + xl[1][o] * dv[1][o] + xl[2][o] * dv[2][o];
  float dsq = dv[0][o] * dv[0][o] + dv[1][o] * dv[1][o] + dv[2][o] * dv[2][o];
  F[((size_t)b * 32 + o) * 3 + dd] = lrelu_combine(xl[dd][o], dv[dd][o], dot, dsq);
}

// ================== LAPACK-faithful 3x3 SVD (dgesdd path: dgebrd + dbdsqr) ==================
#define DEPS 2.220446049250313e-16
#define DUNFL 2.2250738585072014e-308

static __device__ void dlartg_(double f, double g, double* cs, double* sn, double* r) {
  if (g == 0.0) { *cs = 1.0; *sn = 0.0; *r = f; }
  else if (f == 0.0) { *cs = 0.0; *sn = copysign(1.0, g); *r = fabs(g); }
  else {
    double d = sqrt(f * f + g * g);
    double c = fabs(f) / d;
    double rr = copysign(d, f);
    *cs = c; *r = rr; *sn = g / rr;
  }
}

static __device__ void dlas2_(double f, double g, double h, double* ssmin, double* ssmax) {
  double fa = fabs(f), ga = fabs(g), ha = fabs(h);
  double fhmn = fmin(fa, ha), fhmx = fmax(fa, ha);
  if (fhmn == 0.0) {
    *ssmin = 0.0;
    if (fhmx == 0.0) *ssmax = ga;
    else { double mx = fmax(fhmx, ga), mn = fmin(fhmx, ga); double q = mn / mx; *ssmax = mx * sqrt(1.0 + q * q); }
  } else {
    if (ga < fhmx) {
      double as_ = 1.0 + fhmn / fhmx;
      double at = (fhmx - fhmn) / fhmx;
      double au = ga / fhmx; au = au * au;
      double c = 2.0 / (sqrt(as_ * as_ + au) + sqrt(at * at + au));
      *ssmin = fhmn * c; *ssmax = fhmx / c;
    } else {
      double au = fhmx / ga;
      if (au == 0.0) { *ssmin = (fhmn * fhmx) / ga; *ssmax = ga; }
      else {
        double as_ = 1.0 + fhmn / fhmx;
        double at = (fhmx - fhmn) / fhmx;
        double t1 = as_ * au, t2 = at * au;
        double c = 1.0 / (sqrt(1.0 + t1 * t1) + sqrt(1.0 + t2 * t2));
        double sm = (fhmn * c) * au; *ssmin = sm + sm;
        *ssmax = ga / (c + c);
      }
    }
  }
}

static __device__ void dlasv2_(double f, double g, double h,
                               double* ssmin, double* ssmax,
                               double* snr, double* csr, double* snl, double* csl) {
  double ft = f, fa = fabs(f), ht = h, ha = fabs(h);
  int pmax = 1;
  bool swp = (ha > fa);
  if (swp) { pmax = 3; double t = ft; ft = ht; ht = t; t = fa; fa = ha; ha = t; }
  double gt = g, ga = fabs(g);
  double clt = 0, crt = 0, slt = 0, srt = 0;
  if (ga == 0.0) {
    *ssmin = ha; *ssmax = fa; clt = 1.0; crt = 1.0; slt = 0.0; srt = 0.0;
  } else {
    bool gasmal = true;
    if (ga > fa) {
      pmax = 2;
      if ((fa / ga) < DEPS) {
        gasmal = false;
        *ssmax = ga;
        *ssmin = (ha > 1.0) ? (fa / (ga / ha)) : ((fa / ga) * ha);
        clt = 1.0; slt = ht / gt; srt = 1.0; crt = ft / gt;
      }
    }
    if (gasmal) {
      double dd = fa - ha;
      double l = (dd == fa) ? 1.0 : (dd / fa);
      double mq = gt / ft;
      double t = 2.0 - l;
      double mm = mq * mq, tt = t * t;
      double s = sqrt(tt + mm);
      double r = (l == 0.0) ? fabs(mq) : sqrt(l * l + mm);
      double a = 0.5 * (s + r);
      *ssmin = ha / a;
      *ssmax = fa * a;
      if (mm == 0.0) {
        if (l == 0.0) t = copysign(2.0, ft) * copysign(1.0, gt);
        else t = gt / copysign(dd, ft) + mq / t;
      } else {
        t = (mq / (s + t) + mq / (r + l)) * (1.0 + a);
      }
      double l2 = sqrt(t * t + 4.0);
      crt = 2.0 / l2;
      srt = t / l2;
      clt = (crt + srt * mq) / a;
      slt = (ht / ft) * srt / a;
    }
  }
  if (swp) { *csl = srt; *snl = crt; *csr = slt; *snr = clt; }
  else { *csl = clt; *snl = slt; *csr = crt; *snr = srt; }
  double tsign = 0.0;
  if (pmax == 1) tsign = copysign(1.0, *csr) * copysign(1.0, *csl) * copysign(1.0, f);
  if (pmax == 2) tsign = copysign(1.0, *snr) * copysign(1.0, *csl) * copysign(1.0, g);
  if (pmax == 3) tsign = copysign(1.0, *snr) * copysign(1.0, *snl) * copysign(1.0, h);
  *ssmax = copysign(*ssmax, tsign);
  *ssmin = copysign(*ssmin, tsign * copysign(1.0, f) * copysign(1.0, h));
}

static __device__ void dbdsqr3(double d[3], double e[2], double VT[3][3], double U[3][3]) {
  const int n = 3;
  double tolmul = fmax(10.0, fmin(100.0, pow(DEPS, -0.125)));
  double tol = tolmul * DEPS;
  double thresh;
  {
    double sminoa = fabs(d[0]);
    if (sminoa != 0.0) {
      double mu = sminoa;
      for (int i = 1; i < n; ++i) {
        mu = fabs(d[i]) * (mu / (mu + fabs(e[i - 1])));
        sminoa = fmin(sminoa, mu);
        if (sminoa == 0.0) break;
      }
    }
    sminoa = sminoa / sqrt((double)n);
    thresh = fmax(tol * sminoa, 6.0 * n * n * DUNFL);
  }
  int maxit = 6 * n * n;
  int iter = 0, oldll = -1, oldm = -1, idir = 0;
  int m = n;
  double sminl = 0.0;
  int guard = 0;
  while (true) {
    if (m <= 1) break;
    if (iter > maxit) break;
    if (++guard > 500) break;
    double smaxb = fabs(d[m - 1]);
    int ll = 0; bool found = false;
    for (int lll = 1; lll <= m - 1; ++lll) {
      int l = m - lll;
      double abss = fabs(d[l - 1]);
      double abse = fabs(e[l - 1]);
      if (abse <= thresh) { ll = l; found = true; break; }
      smaxb = fmax(smaxb, fmax(abss, abse));
    }
    if (found) {
      e[ll - 1] = 0.0;
      if (ll == m - 1) { m = m - 1; continue; }
      ll = ll + 1;
    } else ll = 1;
    if (ll == m - 1) {
      double sigmn, sigmx, sinr, cosr, sinl2, cosl2;
      dlasv2_(d[m - 2], e[m - 2], d[m - 1], &sigmn, &sigmx, &sinr, &cosr, &sinl2, &cosl2);
      d[m - 2] = sigmx; d[m - 1] = sigmn; e[m - 2] = 0.0;
      for (int j = 0; j < 3; ++j) {
        double t1 = VT[m - 2][j], t2 = VT[m - 1][j];
        VT[m - 2][j] = cosr * t1 + sinr * t2;
        VT[m - 1][j] = cosr * t2 - sinr * t1;
      }
      for (int i2 = 0; i2 < 3; ++i2) {
        double t1 = U[i2][m - 2], t2 = U[i2][m - 1];
        U[i2][m - 2] = cosl2 * t1 + sinl2 * t2;
        U[i2][m - 1] = cosl2 * t2 - sinl2 * t1;
      }
      m -= 2;
      continue;
    }
    if (ll > oldm || m < oldll)
      idir = (fabs(d[ll - 1]) >= fabs(d[m - 1])) ? 1 : 2;
    if (idir == 1) {
      if (fabs(e[m - 2]) <= tol * fabs(d[m - 1])) { e[m - 2] = 0.0; continue; }
      double mu = fabs(d[ll - 1]); sminl = mu;
      bool conv = true;
      for (int lll = ll; lll <= m - 1; ++lll) {
        if (fabs(e[lll - 1]) > tol * mu) { conv = false; break; }
        mu = fabs(d[lll]) * (mu / (mu + fabs(e[lll - 1])));
        sminl = fmin(sminl, mu);
      }
      if (conv) { e[m - 2] = 0.0; continue; }
    } else {
      if (fabs(e[ll - 1]) <= tol * fabs(d[ll - 1])) { e[ll - 1] = 0.0; continue; }
      double mu = fabs(d[m - 1]); sminl = mu;
      bool conv = true;
      for (int lll = m - 1; lll >= ll; --lll) {
        if (fabs(e[lll - 1]) > tol * mu) { conv = false; break; }
        mu = fabs(d[lll - 1]) * (mu / (mu + fabs(e[lll - 1])));
        sminl = fmin(sminl, mu);
      }
      if (conv) { e[ll - 1] = 0.0; continue; }
    }
    oldll = ll; oldm = m;
    double shift = 0.0, rr;
    if (!(n * tol * (sminl / smaxb) <= fmax(DEPS, 0.01 * tol))) {
      double sll;
      if (idir == 1) { sll = fabs(d[ll - 1]); dlas2_(d[m - 2], e[m - 2], d[m - 1], &shift, &rr); }
      else { sll = fabs(d[m - 1]); dlas2_(d[ll - 1], e[ll - 1], d[ll], &shift, &rr); }
      if (sll > 0.0) { double q = shift / sll; if (q * q < DEPS) shift = 0.0; }
    }
    iter += m - ll;
    double csv[2], snv[2], ocsv[2], osnv[2];
    int cnt = 0;
    if (shift == 0.0) {
      if (idir == 1) {
        double cs = 1.0, oldcs = 1.0, sn = 0.0, oldsn = 0.0, r;
        for (int i = ll; i <= m - 1; ++i) {
          dlartg_(d[i - 1] * cs, e[i - 1], &cs, &sn, &r);
          if (i > ll) e[i - 2] = oldsn * r;
          dlartg_(oldcs * r, d[i] * sn, &oldcs, &oldsn, &d[i - 1]);
          csv[cnt] = cs; snv[cnt] = sn; ocsv[cnt] = oldcs; osnv[cnt] = oldsn; cnt++;
        }
        double hh = d[m - 1] * cs;
        d[m - 1] = hh * oldcs;
        e[m - 2] = hh * oldsn;
        for (int k = 0; k < cnt; ++k) {
          int r0 = ll - 1 + k, r1 = r0 + 1;
          for (int j = 0; j < 3; ++j) {
            double t1 = VT[r0][j], t2 = VT[r1][j];
            VT[r0][j] = snv[k] * t2 + csv[k] * t1;
            VT[r1][j] = csv[k] * t2 - snv[k] * t1;
          }
        }
        for (int k = 0; k < cnt; ++k) {
          int c0 = ll - 1 + k, c1 = c0 + 1;
          for (int i2 = 0; i2 < 3; ++i2) {
            double t1 = U[i2][c0], t2 = U[i2][c1];
            U[i2][c0] = osnv[k] * t2 + ocsv[k] * t1;
            U[i2][c1] = ocsv[k] * t2 - osnv[k] * t1;
          }
        }
        if (fabs(e[m - 2]) <= thresh) e[m - 2] = 0.0;
      } else {
        double cs = 1.0, oldcs = 1.0, sn = 0.0, oldsn = 0.0, r;
        for (int i = m; i >= ll + 1; --i) {
          dlartg_(d[i - 1] * cs, e[i - 2], &cs, &sn, &r);
          if (i < m) e[i - 1] = oldsn * r;
          dlartg_(oldcs * r, d[i - 2] * sn, &oldcs, &oldsn, &d[i - 1]);
          int k = i - ll - 1;
          csv[k] = cs; snv[k] = -sn; ocsv[k] = oldcs; osnv[k] = -oldsn; cnt++;
        }
        double hh = d[ll - 1] * cs;
        d[ll - 1] = hh * oldcs;
        e[ll - 1] = hh * oldsn;
        for (int k = cnt - 1; k >= 0; --k) {
          int r0 = ll - 1 + k, r1 = r0 + 1;
          for (int j = 0; j < 3; ++j) {
            double t1 = VT[r0][j], t2 = VT[r1][j];
            VT[r0][j] = osnv[k] * t2 + ocsv[k] * t1;
            VT[r1][j] = ocsv[k] * t2 - osnv[k] * t1;
          }
        }
        for (int k = cnt - 1; k >= 0; --k) {
          int c0 = ll - 1 + k, c1 = c0 + 1;
          for (int i2 = 0; i2 < 3; ++i2) {
            double t1 = U[i2][c0], t2 = U[i2][c1];
            U[i2][c0] = snv[k] * t2 + csv[k] * t1;
            U[i2][c1] = csv[k] * t2 - snv[k] * t1;
          }
        }
        if (fabs(e[ll - 1]) <= thresh) e[ll - 1] = 0.0;
      }
    } else {
      if (idir == 1) {
        double f = (fabs(d[ll - 1]) - shift) * (copysign(1.0, d[ll - 1]) + shift / d[ll - 1]);
        double g = e[ll - 1];
        double cosr, sinr, cosl2, sinl2, r;
        for (int i = ll; i <= m - 1; ++i) {
          dlartg_(f, g, &cosr, &sinr, &r);
          if (i > ll) e[i - 2] = r;
          f = cosr * d[i - 1] + sinr * e[i - 1];
          e[i - 1] = cosr * e[i - 1] - sinr * d[i - 1];
          g = sinr * d[i];
          d[i] = cosr * d[i];
          dlartg_(f, g, &cosl2, &sinl2, &r);
          d[i - 1] = r;
          f = cosl2 * e[i - 1] + sinl2 * d[i];
          d[i] = cosl2 * d[i] - sinl2 * e[i - 1];
          if (i < m - 1) {
            g = sinl2 * e[i];
            e[i] = cosl2 * e[i];
          }
          csv[cnt] = cosr; snv[cnt] = sinr; ocsv[cnt] = cosl2; osnv[cnt] = sinl2; cnt++;
        }
        e[m - 2] = f;
        for (int k = 0; k < cnt; ++k) {
          int r0 = ll - 1 + k, r1 = r0 + 1;
          for (int j = 0; j < 3; ++j) {
            double t1 = VT[r0][j], t2 = VT[r1][j];
            VT[r0][j] = snv[k] * t2 + csv[k] * t1;
            VT[r1][j] = csv[k] * t2 - snv[k] * t1;
          }
        }
        for (int k = 0; k < cnt; ++k) {
          int c0 = ll - 1 + k, c1 = c0 + 1;
          for (int i2 = 0; i2 < 3; ++i2) {
            double t1 = U[i2][c0], t2 = U[i2][c1];
            U[i2][c0] = osnv[k] * t2 + ocsv[k] * t1;
            U[i2][c1] = ocsv[k] * t2 - osnv[k] * t1;
          }
        }
        if (fabs(e[m - 2]) <= thresh) e[m - 2] = 0.0;
      } else {
        double f = (fabs(d[m - 1]) - shift) * (copysign(1.0, d[m - 1]) + shift / d[m - 1]);
        double g = e[m - 2];
        for (int i = m; i >= ll + 1; --i) {
          double cosr, sinr, cosl2, sinl2, r;
          dlartg_(f, g, &cosr, &sinr, &r);
          if (i < m) e[i - 1] = r;
          f = cosr * d[i - 1] + sinr * e[i - 2];
          e[i - 2] = cosr * e[i - 2] - sinr * d[i - 1];
          g = sinr * d[i - 2];
          d[i - 2] = cosr * d[i - 2];
          dlartg_(f, g, &cosl2, &sinl2, &r);
          d[i - 1] = r;
          f = cosl2 * e[i - 2] + sinl2 * d[i - 2];
          d[i - 2] = cosl2 * d[i - 2] - sinl2 * e[i - 2];
          if (i > ll + 1) {
            g = sinl2 * e[i - 3];
            e[i - 3] = cosl2 * e[i - 3];
          }
          int k = i - ll - 1;
          ocsv[k] = cosl2; osnv[k] = -sinl2; csv[k] = cosr; snv[k] = -sinr; cnt++;
        }
        e[ll - 1] = f;
        for (int k = cnt - 1; k >= 0; --k) {
          int r0 = ll - 1 + k, r1 = r0 + 1;
          for (int j = 0; j < 3; ++j) {
            double t1 = VT[r0][j], t2 = VT[r1][j];
            VT[r0][j] = snv[k] * t2 + csv[k] * t1;
            VT[r1][j] = csv[k] * t2 - snv[k] * t1;
          }
        }
        for (int k = cnt - 1; k >= 0; --k) {
          int c0 = ll - 1 + k, c1 = c0 + 1;
          for (int i2 = 0; i2 < 3; ++i2) {
            double t1 = U[i2][c0], t2 = U[i2][c1];
            U[i2][c0] = osnv[k] * t2 + ocsv[k] * t1;
            U[i2][c1] = ocsv[k] * t2 - osnv[k] * t1;
          }
        }
        if (fabs(e[ll - 1]) <= thresh) e[ll - 1] = 0.0;
      }
    }
  }
  for (int i = 0; i < n; ++i)
    if (d[i] < 0.0) { d[i] = -d[i]; for (int j = 0; j < 3; ++j) VT[i][j] = -VT[i][j]; }
  for (int i = 1; i <= n - 1; ++i) {
    int isub = 1; double smn = d[0];
    for (int j = 2; j <= n + 1 - i; ++j)
      if (d[j - 1] <= smn) { isub = j; smn = d[j - 1]; }
    if (isub != n + 1 - i) {
      int a = isub - 1, b2 = n - i;
      double t = d[a]; d[a] = d[b2]; d[b2] = t;
      for (int j = 0; j < 3; ++j) { t = VT[a][j]; VT[a][j] = VT[b2][j]; VT[b2][j] = t; }
      for (int j = 0; j < 3; ++j) { t = U[j][a]; U[j][a] = U[j][b2]; U[j][b2] = t; }
    }
  }
}

__global__ void k_svd(const float* __restrict__ Fx, const float* __restrict__ Fy,
                      float* __restrict__ out, int B) {
  int b = blockIdx.x;
  if (threadIdx.x != 0) return;
  double A[3][3];
  for (int d = 0; d < 3; ++d)
    for (int e = 0; e < 3; ++e) {
      double s = 0.0;
      for (int c = 0; c < 32; ++c)
        s += (double)Fx[((size_t)b * 32 + c) * 3 + d] * (double)Fy[((size_t)b * 32 + c) * 3 + e];
      A[d][e] = s;
    }
  double dg[3], eg[2], tauq0, tauq1, taup0;
  double v1_1 = 0, v1_2 = 0, v2_1 = 0, w1 = 0;
  {
    double alpha = A[0][0];
    double xn = sqrt(A[1][0] * A[1][0] + A[2][0] * A[2][0]);
    if (xn == 0.0) { tauq0 = 0.0; dg[0] = alpha; }
    else {
      double beta = -copysign(sqrt(alpha * alpha + xn * xn), alpha);
      tauq0 = (beta - alpha) / beta;
      double scal = 1.0 / (alpha - beta);
      v1_1 = A[1][0] * scal; v1_2 = A[2][0] * scal;
      dg[0] = beta;
    }
    for (int j = 1; j < 3; ++j) {
      double w = A[0][j] + v1_1 * A[1][j] + v1_2 * A[2][j];
      w *= tauq0;
      A[0][j] -= w; A[1][j] -= w * v1_1; A[2][j] -= w * v1_2;
    }
  }
  {
    double alpha = A[0][1];
    double xn = fabs(A[0][2]);
    if (xn == 0.0) { taup0 = 0.0; eg[0] = alpha; }
    else {
      double beta = -copysign(sqrt(alpha * alpha + xn * xn), alpha);
      taup0 = (beta - alpha) / beta;
      w1 = A[0][2] / (alpha - beta);
      eg[0] = beta;
    }
    for (int i = 1; i < 3; ++i) {
      double t = A[i][1] + w1 * A[i][2];
      t *= taup0;
      A[i][1] -= t; A[i][2] -= t * w1;
    }
  }
  {
    double alpha = A[1][1];
    double xn = fabs(A[2][1]);
    if (xn == 0.0) { tauq1 = 0.0; dg[1] = alpha; }
    else {
      double beta = -copysign(sqrt(alpha * alpha + xn * xn), alpha);
      tauq1 = (beta - alpha) / beta;
      v2_1 = A[2][1] / (alpha - beta);
      dg[1] = beta;
    }
    double w = A[1][2] + v2_1 * A[2][2];
    w *= tauq1;
    A[1][2] -= w; A[2][2] -= w * v2_1;
  }
  eg[1] = A[1][2];
  dg[2] = A[2][2];
  double U[3][3] = {{1, 0, 0}, {0, 1, 0}, {0, 0, 1}};
  double VT[3][3] = {{1, 0, 0}, {0, 1, 0}, {0, 0, 1}};
  dbdsqr3(dg, eg, VT, U);
  for (int j = 0; j < 3; ++j) {
    double w = U[1][j] + v2_1 * U[2][j];
    w *= tauq1;
    U[1][j] -= w; U[2][j] -= w * v2_1;
  }
  for (int j = 0; j < 3; ++j) {
    double w = U[0][j] + v1_1 * U[1][j] + v1_2 * U[2][j];
    w *= tauq0;
    U[0][j] -= w; U[1][j] -= w * v1_1; U[2][j] -= w * v1_2;
  }
  for (int r = 0; r < 3; ++r) {
    double t = VT[r][1] + w1 * VT[r][2];
    t *= taup0;
    VT[r][1] -= t; VT[r][2] -= t * w1;
  }
  for (int i = 0; i < 3; ++i)
    for (int j = 0; j < 3; ++j) {
      double r = 0;
      for (int k = 0; k < 3; ++k) r += U[i][k] * VT[j][k];
      out[b * 9 + i * 3 + j] = (float)r;
    }
  for (int dd = 0; dd < 3; ++dd) {
    float sx = 0.f, sy = 0.f;
    for (int c = 0; c < 32; ++c) {
      float vx = Fx[((size_t)b * 32 + c) * 3 + dd];
      float vy = Fy[((size_t)b * 32 + c) * 3 + dd];
      sx = fmaf(vx, vx, sx);
      sy = fmaf(vy, vy, sy);
    }
    out[B * 9 + b * 3 + dd] = sqrtf(sy) / sqrtf(sx);
  }
}

extern "C" void kernel_launch(void* const* d_in, const int* in_sizes, int n_in,
                              void* d_out, int out_size, void* d_ws, size_t ws_size,
                              hipStream_t stream) {
  (void)in_sizes; (void)n_in; (void)out_size; (void)ws_size;
  const int B = 2, N0 = 2048;
  const float* W[24];
  for (int i = 0; i < 24; ++i) W[i] = (const float*)d_in[i];

  float* ws = (float*)d_ws;
  const size_t P = (size_t)B * 64 * 3 * 2048;  // 786432 floats
  float* bufA = ws;
  float* bufB = bufA + P;
  float* bufC = bufB + P;
  float* bufD = bufC + P;
  float* bufApm = bufD + P;
  float* bufBpm = bufApm + P;
  float* C1 = bufBpm + P;
  float* C2 = C1 + P;
  float* C3 = C2 + P;
  float* C4 = C3 + P;
  float* C5 = C4 + P;
  float* M1 = C5 + P;
  float* M2 = M1 + P;
  float* M3 = M2 + P;
  float* M4 = M3 + P;
  float* M5 = M4 + P;
  float* M6 = M5 + P;
  float* M7 = M6 + P;
  float* M8 = M7 + P;
  float* M9 = M8 + P;
  float* M10 = M9 + P;
  float* px = M10 + P;               // B*3*2048 = 12288
  float* py = px + 12288;
  float* dps = py + 12288;           // 4096
  float* xx0 = dps + 4096;           // 4096
  float* xx1 = xx0 + 4096;           // 4096
  float* meanX = xx1 + 4096;         // 384
  float* meanY = meanX + 384;
  float* cbX = meanY + 384;
  float* cbY = cbX + 384;
  float* blkX = cbY + 384;           // 768
  float* blkY = blkX + 768;
  float* Fxb = blkY + 768;           // 192
  float* Fyb = Fxb + 192;
  int* idxA = (int*)(Fyb + 192);     // 65536
  int* idxB = idxA + 65536;
  int* sel = idxB + 65536;           // 2048

  auto knn = [&](const float* xa, const float* xb2, int D, int N, int* ia, int* ib, int ns) {
    k_xx2<<<dim3((N + 255) / 256, B, ns), 256, 0, stream>>>(xa, xb2, xx0, xx1, D, N);
    dim3 g2(N / 4, B, ns);
    if (D == 192) k_knn2<192><<<g2, 256, 0, stream>>>(xa, xb2, xx0, xx1, ia, ib, N);
    else          k_knn2<3><<<g2, 256, 0, stream>>>(xa, xb2, xx0, xx1, ia, ib, N);
  };

  const float* fx = W[0];
  const float* fy = W[1];
  int N = N0;
  for (int blk = 0; blk < 2; ++blk) {
    int D = (blk == 0) ? 3 : 192;
    const float* dgw = W[blk ? 12 : 2]; const float* dgd = W[blk ? 13 : 3];
    const float* qw  = W[blk ? 14 : 4]; const float* qd  = W[blk ? 15 : 5];
    const float* kw  = W[blk ? 16 : 6]; const float* kd  = W[blk ? 17 : 7];
    const float* vw  = W[blk ? 18 : 8]; const float* vd  = W[blk ? 19 : 9];
    const float* gw  = W[blk ? 20 : 10]; const float* gd = W[blk ? 21 : 11];
    dim3 gP(B * N / 4);
    dim3 gL((3 * N + 255) / 256, B, 1);

    // ======== dgcnn, both sides in merged launches ========
    knn(fx, fy, D, N, idxA, idxB, 2);
    {
      LinSlots s{};  // stage1: W1*x, (W2-W1)*x for fx and fy
      int wsd = (blk == 0) ? 2 : 128;
      int off2 = (blk == 0) ? 1 : 64;
      const float* Xs[4] = {fx, fx, fy, fy};
      float* cms[4] = {C1, C2, C3, C4};
      float* pms[4] = {M1, M2, M3, M4};
      for (int i = 0; i < 4; ++i) {
        s.W[i] = dgw; s.X[i] = Xs[i]; s.bias[i] = nullptr;
        s.cm[i] = cms[i]; s.pm[i] = pms[i];
        s.ws[i] = wsd; s.woff[i] = (i & 1) ? off2 : 0; s.sub[i] = (i & 1);
      }
      gL.z = 16;
      if (blk == 0) k_linm<1><<<gL, 256, 0, stream>>>(s, N);
      else          k_linm<64><<<gL, 256, 0, stream>>>(s, N);
    }
    {
      LinSlots s{};  // stage2: Wd * each
      const float* Xs[4] = {C1, C2, C3, C4};
      float* pms[4] = {M5, M6, M7, M8};
      for (int i = 0; i < 4; ++i) {
        s.W[i] = dgd; s.X[i] = Xs[i]; s.bias[i] = nullptr;
        s.cm[i] = nullptr; s.pm[i] = pms[i];
        s.ws[i] = 64; s.woff[i] = 0; s.sub[i] = 0;
      }
      gL.z = 16;
      k_linm<64><<<gL, 256, 0, stream>>>(s, N);
    }
    k_edge2<<<dim3(B * N / 4, 2), 256, 0, stream>>>(M1, M2, M5, M6, M3, M4, M7, M8,
                                                    idxA, idxB, bufA, bufB, N);

    // ======== cross_context #1: x=bufA, y=bufB -> bufC ========
    knn(bufB, bufB, 192, N, idxB, idxB, 1);
    {
      LinSlots s{};  // stage1: q,k1,k2,v1,v2
      const float* Wm[5] = {qw, kw, kw, vw, vw};
      const float* Xs[5] = {bufA, bufB, bufB, bufB, bufB};
      float* cms[5] = {C1, C2, C3, C4, C5};
      float* pms[5] = {M1, M3, M4, M5, M6};
      int wss[5] = {64, 128, 128, 128, 128};
      int offs[5] = {0, 0, 64, 0, 64};
      int subs[5] = {0, 0, 1, 0, 1};
      for (int i = 0; i < 5; ++i) {
        s.W[i] = Wm[i]; s.X[i] = Xs[i]; s.bias[i] = nullptr;
        s.cm[i] = cms[i]; s.pm[i] = pms[i];
        s.ws[i] = wss[i]; s.woff[i] = offs[i]; s.sub[i] = subs[i];
      }
      gL.z = 20;
      k_linm<64><<<gL, 256, 0, stream>>>(s, N);
    }
    {
      LinSlots s{};  // stage2: qd,kd,kd,vd,vd
      const float* Wm[5] = {qd, kd, kd, vd, vd};
      const float* Xs[5] = {C1, C2, C3, C4, C5};
      float* pms[5] = {M2, M7, M8, M9, M10};
      for (int i = 0; i < 5; ++i) {
        s.W[i] = Wm[i]; s.X[i] = Xs[i]; s.bias[i] = nullptr;
        s.cm[i] = nullptr; s.pm[i] = pms[i];
        s.ws[i] = 64; s.woff[i] = 0; s.sub[i] = 0;
      }
      gL.z = 20;
      k_linm<64><<<gL, 256, 0, stream>>>(s, N);
    }
    k_att<<<gP, 256, 0, stream>>>(bufA, M1, M2, M3, M4, M7, M8, M5, M6, M9, M10, idxB, bufC, N);

    // ======== cross_context #2: x=bufB, y=bufC -> bufD ========
    knn(bufC, bufC, 192, N, idxA, idxA, 1);
    {
      LinSlots s{};
      const float* Wm[5] = {qw, kw, kw, vw, vw};
      const float* Xs[5] = {bufB, bufC, bufC, bufC, bufC};
      float* cms[5] = {C1, C2, C3, C4, C5};
      float* pms[5] = {M1, M3, M4, M5, M6};
      int wss[5] = {64, 128, 128, 128, 128};
      int offs[5] = {0, 0, 64, 0, 64};
      int subs[5] = {0, 0, 1, 0, 1};
      for (int i = 0; i < 5; ++i) {
        s.W[i] = Wm[i]; s.X[i] = Xs[i]; s.bias[i] = nullptr;
        s.cm[i] = cms[i]; s.pm[i] = pms[i];
        s.ws[i] = wss[i]; s.woff[i] = offs[i]; s.sub[i] = subs[i];
      }
      gL.z = 20;
      k_linm<64><<<gL, 256, 0, stream>>>(s, N);
    }
    {
      LinSlots s{};
      const float* Wm[5] = {qd, kd, kd, vd, vd};
      const float* Xs[5] = {C1, C2, C3, C4, C5};
      float* pms[5] = {M2, M7, M8, M9, M10};
      for (int i = 0; i < 5; ++i) {
        s.W[i] = Wm[i]; s.X[i] = Xs[i]; s.bias[i] = nullptr;
        s.cm[i] = nullptr; s.pm[i] = pms[i];
        s.ws[i] = 64; s.woff[i] = 0; s.sub[i] = 0;
      }
      gL.z = 20;
      k_linm<64><<<gL, 256, 0, stream>>>(s, N);
    }
    k_att<<<gP, 256, 0, stream>>>(bufB, M1, M2, M3, M4, M7, M8, M5, M6, M9, M10, idxA, bufD, N);

    // ======== global fuse ========
    k_cmean2<<<dim3(192, B, 2), 256, 0, stream>>>(bufC, bufD, meanX, meanY, N, 192, 0, 1.f / (float)N);
    k_gbias2<<<dim3(B, 2), 192, 0, stream>>>(gw, meanX, meanY, cbX, cbY);
    {
      LinSlots s{};  // gw on both sides (with bias)
      const float* Xs[2] = {bufC, bufD};
      const float* bs[2] = {cbX, cbY};
      float* cms[2] = {C1, C2};
      float* pms[2] = {M1, M2};
      for (int i = 0; i < 2; ++i) {
        s.W[i] = gw; s.X[i] = Xs[i]; s.bias[i] = bs[i];
        s.cm[i] = cms[i]; s.pm[i] = pms[i];
        s.ws[i] = 128; s.woff[i] = 0; s.sub[i] = 0;
      }
      gL.z = 8;
      k_linm<64><<<gL, 256, 0, stream>>>(s, N);
    }
    {
      LinSlots s{};  // gd on both sides
      const float* Xs[2] = {C1, C2};
      float* pms[2] = {M3, M4};
      for (int i = 0; i < 2; ++i) {
        s.W[i] = gd; s.X[i] = Xs[i]; s.bias[i] = nullptr;
        s.cm[i] = nullptr; s.pm[i] = pms[i];
        s.ws[i] = 64; s.woff[i] = 0; s.sub[i] = 0;
      }
      gL.z = 8;
      k_linm<64><<<gL, 256, 0, stream>>>(s, N);
    }
    k_gfin<<<dim3(B * N / 4, 2), 256, 0, stream>>>(M1, M3, M2, M4, bufA, bufApm, bufB, bufBpm, N);

    // ======== score + top-half selection ========
    int Nh = N / 2;
    k_parmean<<<dim3((B * 3 * N + 255) / 256), 256, 0, stream>>>(bufA, bufB, px, py, N, B);
    k_dotphi<<<dim3((B * N + 255) / 256), 256, 0, stream>>>(bufA, bufB, px, py, dps, N, B);
    k_topsel<<<dim3(B), 1024, 0, stream>>>(dps, sel, N, Nh);
    k_gather<<<dim3(B * Nh / 4), 256, 0, stream>>>(bufApm, bufBpm, sel, bufC, bufD, N, Nh);
    k_cmean2<<<dim3(192, B, 2), 256, 0, stream>>>(bufC, bufD, blkX, blkY, Nh, 384, blk * 192, 1.f / (float)Nh);
    fx = bufC; fy = bufD;
    N = Nh;
  }
  k_head<<<dim3(2, B), 96, 0, stream>>>(blkX, blkY, W[22], W[23], Fxb, Fyb);
  k_svd<<<dim3(B), 64, 0, stream>>>(Fxb, Fyb, (float*)d_out, B);
}

// Round 12
// 1354.844 us; speedup vs baseline: 2.5851x; 1.0173x over previous
//
#include <hip/hip_runtime.h>
#include <math.h>

#define SLOPE 0.2f
#define EPSV 1e-12f
#define NEGINF (-3.0e38f)

static __device__ __forceinline__ float lrelu_combine(float xv, float dvv, float dot, float dsq) {
  float xneg = xv - dot / (dsq + EPSV) * dvv;
  float w = (dot >= 0.f) ? xv : xneg;
  return SLOPE * xv + (1.f - SLOPE) * w;
}

// ---------------- squared norms per point, up to 2 inputs (side = blockIdx.z) ----------------
__global__ void k_xx2(const float* __restrict__ x0, const float* __restrict__ x1,
                      float* __restrict__ xxA, float* __restrict__ xxB, int D, int N) {
  int side = blockIdx.z;
  const float* x = side ? x1 : x0;
  float* xx = side ? xxB : xxA;
  int b = blockIdx.y;
  int m = blockIdx.x * 256 + threadIdx.x;
  if (m >= N) return;
  const float* xp = x + (size_t)b * D * N + m;
  float s = 0.f;
  for (int d = 0; d < D; ++d) { float v = xp[(size_t)d * N]; s = fmaf(v, v, s); }
  xx[b * N + m] = s;
}

// ---------------- fused knn top-16 (round-7 structure + float4 m-contiguous loads) ----------------
// 4 queries/block, 4 consecutive m per thread. Per-(q,m) chain: ascending-d fmaf, 2*dot - xxn - xxm
// -> dist values bit-identical to prior rounds; selection phase unchanged -> indices bit-identical.
template <int D>
__global__ void __launch_bounds__(256) k_knn2(const float* __restrict__ x0, const float* __restrict__ x1,
                                              const float* __restrict__ xxA, const float* __restrict__ xxB,
                                              int* __restrict__ idx0, int* __restrict__ idx1, int N) {
  int side = blockIdx.z;
  const float* x = side ? x1 : x0;
  const float* xx = side ? xxB : xxA;
  int* idx = side ? idx1 : idx0;
  __shared__ float qt[D * 4];
  __shared__ float dist[4][2048];
  __shared__ float xxq[4];
  int b = blockIdx.y, tid = threadIdx.x;
  int q0 = blockIdx.x * 4;
  const float* xb = x + (size_t)b * D * N;
  for (int i = tid; i < D * 4; i += 256) qt[i] = xb[(size_t)(i >> 2) * N + q0 + (i & 3)];
  if (tid < 4) xxq[tid] = xx[b * N + q0 + tid];
  __syncthreads();
  int kouter = N >> 10;
  for (int k = 0; k < kouter; ++k) {
    int m0 = (k << 10) + tid * 4;   // 4 consecutive m per thread
    // a{i} = accumulators for m0+i; components .x..w = queries q0..q0+3
    float4 a0 = {0, 0, 0, 0}, a1 = {0, 0, 0, 0}, a2 = {0, 0, 0, 0}, a3 = {0, 0, 0, 0};
#pragma unroll 4
    for (int d = 0; d < D; ++d) {
      const float4 q4 = *(const float4*)&qt[d * 4];
      const float4 xv = *(const float4*)&xb[(size_t)d * N + m0];
      a0.x = fmaf(q4.x, xv.x, a0.x); a0.y = fmaf(q4.y, xv.x, a0.y);
      a0.z = fmaf(q4.z, xv.x, a0.z); a0.w = fmaf(q4.w, xv.x, a0.w);
      a1.x = fmaf(q4.x, xv.y, a1.x); a1.y = fmaf(q4.y, xv.y, a1.y);
      a1.z = fmaf(q4.z, xv.y, a1.z); a1.w = fmaf(q4.w, xv.y, a1.w);
      a2.x = fmaf(q4.x, xv.z, a2.x); a2.y = fmaf(q4.y, xv.z, a2.y);
      a2.z = fmaf(q4.z, xv.z, a2.z); a2.w = fmaf(q4.w, xv.z, a2.w);
      a3.x = fmaf(q4.x, xv.w, a3.x); a3.y = fmaf(q4.y, xv.w, a3.y);
      a3.z = fmaf(q4.z, xv.w, a3.z); a3.w = fmaf(q4.w, xv.w, a3.w);
    }
    const float4 xxm = *(const float4*)&xx[b * N + m0];
    {
      float4 o;
      o.x = 2.f * a0.x - xxq[0] - xxm.x;
      o.y = 2.f * a1.x - xxq[0] - xxm.y;
      o.z = 2.f * a2.x - xxq[0] - xxm.z;
      o.w = 2.f * a3.x - xxq[0] - xxm.w;
      *(float4*)&dist[0][m0] = o;
      o.x = 2.f * a0.y - xxq[1] - xxm.x;
      o.y = 2.f * a1.y - xxq[1] - xxm.y;
      o.z = 2.f * a2.y - xxq[1] - xxm.z;
      o.w = 2.f * a3.y - xxq[1] - xxm.w;
      *(float4*)&dist[1][m0] = o;
      o.x = 2.f * a0.z - xxq[2] - xxm.x;
      o.y = 2.f * a1.z - xxq[2] - xxm.y;
      o.z = 2.f * a2.z - xxq[2] - xxm.z;
      o.w = 2.f * a3.z - xxq[2] - xxm.w;
      *(float4*)&dist[2][m0] = o;
      o.x = 2.f * a0.w - xxq[3] - xxm.x;
      o.y = 2.f * a1.w - xxq[3] - xxm.y;
      o.z = 2.f * a2.w - xxq[3] - xxm.z;
      o.w = 2.f * a3.w - xxq[3] - xxm.w;
      *(float4*)&dist[3][m0] = o;
    }
  }
  __syncthreads();
  int g = tid >> 6, lane = tid & 63;
  float* dr = dist[g];
  int n = q0 + g;
  int imax = N >> 8;
  int* op = idx + ((size_t)b * N + n) * 16;
  for (int r = 0; r < 16; ++r) {
    float bv = NEGINF;
    int bi = N;
    for (int i = 0; i < imax; ++i) {
      int mb = i * 256 + lane * 4;
      float4 v = *(const float4*)&dr[mb];
      if (v.x > bv) { bv = v.x; bi = mb; }
      if (v.y > bv) { bv = v.y; bi = mb + 1; }
      if (v.z > bv) { bv = v.z; bi = mb + 2; }
      if (v.w > bv) { bv = v.w; bi = mb + 3; }
    }
#pragma unroll
    for (int s = 1; s < 64; s <<= 1) {
      float ov = __shfl_xor(bv, s, 64);
      int oi = __shfl_xor(bi, s, 64);
      if (ov > bv || (ov == bv && oi < bi)) { bv = ov; bi = oi; }
    }
    if (lane == 0) { op[r] = bi; dr[bi] = NEGINF; }
  }
}

// ---------------- multi-slot 64-out linear (slot = blockIdx.z>>2), dual-layout output ----------------
struct LinSlots {
  const float* W[5]; const float* X[5]; const float* bias[5];
  float* cm[5]; float* pm[5];
  int ws[5]; int woff[5]; int sub[5];
};

template <int KT>
__global__ void __launch_bounds__(256) k_linm(LinSlots S, int N) {
  __shared__ float wl[64 * ((KT + 3) & ~3)];
  const int KP = (KT + 3) & ~3;
  int slot = blockIdx.z >> 2;
  int oc = (blockIdx.z & 3) * 16;
  const float* W = S.W[slot];
  int ws = S.ws[slot], woff = S.woff[slot], sub = S.sub[slot];
  int tid = threadIdx.x;
  for (int i = tid; i < 64 * KT; i += 256) {
    int o = i / KT, k = i - o * KT;
    float v = W[o * ws + woff + k];
    if (sub) v -= W[o * ws + k];
    wl[o * KP + k] = v;
  }
  __syncthreads();
  int b = blockIdx.y;
  int j = blockIdx.x * 256 + tid;
  int M3 = 3 * N;
  if (j >= M3) return;
  const float* Xb = S.X[slot] + (size_t)b * KT * M3;
  float xv[KT];
#pragma unroll
  for (int k = 0; k < KT; ++k) xv[k] = Xb[(size_t)k * M3 + j];
  int d = j / N;
  const float* bias = S.bias[slot];
  float acc[16];
  if (bias) {
#pragma unroll
    for (int oo = 0; oo < 16; ++oo) acc[oo] = bias[b * 192 + (oc + oo) * 3 + d];
  } else {
#pragma unroll
    for (int oo = 0; oo < 16; ++oo) acc[oo] = 0.f;
  }
#pragma unroll
  for (int oo = 0; oo < 16; ++oo) {
    const float* wr = &wl[(oc + oo) * KP];
    float s = acc[oo];
#pragma unroll
    for (int k = 0; k < KT; ++k) s = fmaf(wr[k], xv[k], s);
    acc[oo] = s;
  }
  if (S.cm[slot]) {
    float* ob = S.cm[slot] + (size_t)b * 64 * M3;
#pragma unroll
    for (int oo = 0; oo < 16; ++oo) ob[(size_t)(oc + oo) * M3 + j] = acc[oo];
  }
  if (S.pm[slot]) {
    int n = j - d * N;
    float4* pp = (float4*)(S.pm[slot] + ((size_t)((b * N + n) * 3 + d)) * 64 + oc);
    pp[0] = make_float4(acc[0], acc[1], acc[2], acc[3]);
    pp[1] = make_float4(acc[4], acc[5], acc[6], acc[7]);
    pp[2] = make_float4(acc[8], acc[9], acc[10], acc[11]);
    pp[3] = make_float4(acc[12], acc[13], acc[14], acc[15]);
  }
}

// ---------------- edge conv, wave per point, side = blockIdx.y ----------------
__global__ void __launch_bounds__(256) k_edge2(const float* __restrict__ P1a, const float* __restrict__ P2a,
                                               const float* __restrict__ D1a, const float* __restrict__ D2a,
                                               const float* __restrict__ P1b, const float* __restrict__ P2b,
                                               const float* __restrict__ D1b, const float* __restrict__ D2b,
                                               const int* __restrict__ idxA, const int* __restrict__ idxB,
                                               float* __restrict__ outA, float* __restrict__ outB, int N) {
  int side = blockIdx.y;
  const float* P1 = side ? P1b : P1a;
  const float* P2 = side ? P2b : P2a;
  const float* D1 = side ? D1b : D1a;
  const float* D2 = side ? D2b : D2a;
  const int* idx = side ? idxB : idxA;
  float* out = side ? outB : outA;
  int tid = threadIdx.x;
  int p = blockIdx.x * 4 + (tid >> 6);
  int c = tid & 63;
  int b = p / N, n = p - b * N;
  size_t bn = ((size_t)(b * N + n) * 3) * 64 + c;
  float p2[3], d2[3];
#pragma unroll
  for (int d = 0; d < 3; ++d) { p2[d] = P2[bn + d * 64]; d2[d] = D2[bn + d * 64]; }
  const int* ip = idx + ((size_t)b * N + n) * 16;
  float acc0 = 0.f, acc1 = 0.f, acc2 = 0.f;
  for (int j = 0; j < 16; ++j) {
    int m = ip[j];
    size_t bm = ((size_t)(b * N + m) * 3) * 64 + c;
    float xl[3], dv[3];
#pragma unroll
    for (int d = 0; d < 3; ++d) {
      xl[d] = P1[bm + d * 64] + p2[d];
      dv[d] = D1[bm + d * 64] + d2[d];
    }
    float dot = xl[0] * dv[0] + xl[1] * dv[1] + xl[2] * dv[2];
    float dsq = dv[0] * dv[0] + dv[1] * dv[1] + dv[2] * dv[2];
    acc0 += lrelu_combine(xl[0], dv[0], dot, dsq);
    acc1 += lrelu_combine(xl[1], dv[1], dot, dsq);
    acc2 += lrelu_combine(xl[2], dv[2], dot, dsq);
  }
  size_t r0 = (size_t)((b * 64 + c) * 3) * N;
  out[r0 + n] = acc0 * (1.f / 16.f);
  out[r0 + N + n] = acc1 * (1.f / 16.f);
  out[r0 + 2 * (size_t)N + n] = acc2 * (1.f / 16.f);
}

// ---------------- fused Q-finisher + K-logits + softmax + V-attention + residual ----------------
__global__ void __launch_bounds__(256) k_att(const float* __restrict__ xres,
                                             const float* __restrict__ QXL, const float* __restrict__ QDV,
                                             const float* __restrict__ KP1, const float* __restrict__ KP2,
                                             const float* __restrict__ KD1, const float* __restrict__ KD2,
                                             const float* __restrict__ VP1, const float* __restrict__ VP2,
                                             const float* __restrict__ VD1, const float* __restrict__ VD2,
                                             const int* __restrict__ idx,
                                             float* __restrict__ out, int N) {
  int tid = threadIdx.x;
  int p = blockIdx.x * 4 + (tid >> 6);
  int c = tid & 63;
  int b = p / N, n = p - b * N;
  size_t bn = ((size_t)(b * N + n) * 3) * 64 + c;
  float qv[3], kp2[3], kd2[3], vp2[3], vd2[3];
  {  // inline qfin (exact arithmetic of the former k_qfin)
    float xl[3], dv[3];
#pragma unroll
    for (int d = 0; d < 3; ++d) { xl[d] = QXL[bn + d * 64]; dv[d] = QDV[bn + d * 64]; }
    float dot = xl[0] * dv[0] + xl[1] * dv[1] + xl[2] * dv[2];
    float dsq = dv[0] * dv[0] + dv[1] * dv[1] + dv[2] * dv[2];
    float z[3];
#pragma unroll
    for (int d = 0; d < 3; ++d) z[d] = lrelu_combine(xl[d], dv[d], dot, dsq);
    float n2 = z[0] * z[0] + z[1] * z[1] + z[2] * z[2];
    float cn2 = n2;
#pragma unroll
    for (int s = 1; s < 64; s <<= 1) cn2 += __shfl_xor(cn2, s, 64);
    float n_o = sqrtf(n2), cn = sqrtf(cn2);
    float scl = (n_o / fmaxf(cn, EPSV)) / fmaxf(n_o, EPSV);
#pragma unroll
    for (int d = 0; d < 3; ++d) qv[d] = z[d] * scl;
  }
#pragma unroll
  for (int d = 0; d < 3; ++d) {
    kp2[d] = KP2[bn + d * 64];
    kd2[d] = KD2[bn + d * 64];
    vp2[d] = VP2[bn + d * 64];
    vd2[d] = VD2[bn + d * 64];
  }
  const int* ip = idx + ((size_t)b * N + n) * 16;
  float l[16];
#pragma unroll
  for (int j = 0; j < 16; ++j) {
    int m = ip[j];
    size_t bm = ((size_t)(b * N + m) * 3) * 64 + c;
    float xl[3], dv[3];
#pragma unroll
    for (int d = 0; d < 3; ++d) {
      xl[d] = KP1[bm + d * 64] + kp2[d];
      dv[d] = KD1[bm + d * 64] + kd2[d];
    }
    float dot = xl[0] * dv[0] + xl[1] * dv[1] + xl[2] * dv[2];
    float dsq = dv[0] * dv[0] + dv[1] * dv[1] + dv[2] * dv[2];
    float z[3];
#pragma unroll
    for (int d = 0; d < 3; ++d) z[d] = lrelu_combine(xl[d], dv[d], dot, dsq);
    float n2 = z[0] * z[0] + z[1] * z[1] + z[2] * z[2];
    float cn2 = n2;
#pragma unroll
    for (int s = 1; s < 64; s <<= 1) cn2 += __shfl_xor(cn2, s, 64);
    float n_o = sqrtf(n2), cn = sqrtf(cn2);
    float scl = (n_o / fmaxf(cn, EPSV)) / fmaxf(n_o, EPSV);
    float part = (z[0] * qv[0] + z[1] * qv[1] + z[2] * qv[2]) * scl;
#pragma unroll
    for (int s = 1; s < 32; s <<= 1) part += __shfl_xor(part, s, 32);
    part = __shfl(part, 0, 32);
    l[j] = part * 0.102062072615966f;  // 1/sqrt(96)
  }
  float mx = l[0];
#pragma unroll
  for (int j = 1; j < 16; ++j) mx = fmaxf(mx, l[j]);
  float sum = 0.f;
#pragma unroll
  for (int j = 0; j < 16; ++j) { l[j] = expf(l[j] - mx); sum += l[j]; }
  float inv = 1.f / sum;
#pragma unroll
  for (int j = 0; j < 16; ++j) l[j] *= inv;
  float acc0 = 0.f, acc1 = 0.f, acc2 = 0.f;
#pragma unroll
  for (int j = 0; j < 16; ++j) {
    int m = ip[j];
    float av = l[j];
    size_t bm = ((size_t)(b * N + m) * 3) * 64 + c;
    float xl[3], dv[3];
#pragma unroll
    for (int d = 0; d < 3; ++d) {
      xl[d] = VP1[bm + d * 64] + vp2[d];
      dv[d] = VD1[bm + d * 64] + vd2[d];
    }
    float dot = xl[0] * dv[0] + xl[1] * dv[1] + xl[2] * dv[2];
    float dsq = dv[0] * dv[0] + dv[1] * dv[1] + dv[2] * dv[2];
    acc0 = fmaf(av, lrelu_combine(xl[0], dv[0], dot, dsq), acc0);
    acc1 = fmaf(av, lrelu_combine(xl[1], dv[1], dot, dsq), acc1);
    acc2 = fmaf(av, lrelu_combine(xl[2], dv[2], dot, dsq), acc2);
  }
  size_t r0 = (size_t)((b * 64 + c) * 3) * N;
  out[r0 + n] = xres[r0 + n] + acc0;
  out[r0 + N + n] = xres[r0 + N + n] + acc1;
  out[r0 + 2 * (size_t)N + n] = xres[r0 + 2 * (size_t)N + n] + acc2;
}

// ---------------- g-fuse finisher: wave per point, side = blockIdx.y ----------------
__global__ void __launch_bounds__(256) k_gfin(const float* __restrict__ XLa, const float* __restrict__ DVa,
                                              const float* __restrict__ XLb, const float* __restrict__ DVb,
                                              float* __restrict__ outa, float* __restrict__ outpa,
                                              float* __restrict__ outb, float* __restrict__ outpb, int N) {
  int side = blockIdx.y;
  const float* XL = side ? XLb : XLa;
  const float* DV = side ? DVb : DVa;
  float* out = side ? outb : outa;
  float* outpm = side ? outpb : outpa;
  int tid = threadIdx.x;
  int p = blockIdx.x * 4 + (tid >> 6);
  int c = tid & 63;
  int b = p / N, n = p - b * N;
  size_t bn = ((size_t)(b * N + n) * 3) * 64 + c;
  float xl[3], dv[3];
#pragma unroll
  for (int d = 0; d < 3; ++d) { xl[d] = XL[bn + d * 64]; dv[d] = DV[bn + d * 64]; }
  float dot = xl[0] * dv[0] + xl[1] * dv[1] + xl[2] * dv[2];
  float dsq = dv[0] * dv[0] + dv[1] * dv[1] + dv[2] * dv[2];
  size_t r0 = (size_t)((b * 64 + c) * 3) * N;
#pragma unroll
  for (int d = 0; d < 3; ++d) {
    float z = lrelu_combine(xl[d], dv[d], dot, dsq);
    out[r0 + (size_t)d * N + n] = z;
    outpm[bn + d * 64] = z;
  }
}

// ---------------- bias for g-fuse, both sides in one launch ----------------
__global__ void k_gbias2(const float* __restrict__ gw, const float* __restrict__ meanX,
                         const float* __restrict__ meanY,
                         float* __restrict__ cbX, float* __restrict__ cbY) {
  int b = blockIdx.x, which = blockIdx.y, tid = threadIdx.x;  // 192 threads
  int o = tid / 3, d = tid - o * 3;
  const float* mb = (which ? meanY : meanX) + b * 192;
  float* cb = (which ? cbY : cbX);
  float s = 0.f;
  for (int c = 0; c < 64; ++c) s = fmaf(gw[o * 128 + 64 + c], mb[c * 3 + d], s);
  cb[b * 192 + tid] = s;
}

// ---------------- column mean over N for both arrays in one launch ----------------
__global__ void k_cmean2(const float* __restrict__ x1, const float* __restrict__ x2,
                         float* __restrict__ o1, float* __restrict__ o2,
                         int N, int ostride, int obase, float inv) {
  __shared__ float red[256];
  int b = blockIdx.y, cd = blockIdx.x, which = blockIdx.z, tid = threadIdx.x;
  const float* x = which ? x2 : x1;
  float* out = which ? o2 : o1;
  const float* p = x + ((size_t)b * 192 + cd) * N;
  float s = 0.f;
  for (int i = tid; i < N; i += 256) s += p[i];
  red[tid] = s;
  __syncthreads();
  for (int st = 128; st > 0; st >>= 1) {
    if (tid < st) red[tid] += red[tid + st];
    __syncthreads();
  }
  if (tid == 0) out[(size_t)b * ostride + obase + cd] = red[0] * inv;
}

// ---------------- channel-mean (fx_par pre-normalization) for both arrays ----------------
__global__ void k_parmean(const float* __restrict__ fx, const float* __restrict__ fy,
                          float* __restrict__ px, float* __restrict__ py, int N, int B) {
  int gi = blockIdx.x * 256 + threadIdx.x;
  int total = B * 3 * N;
  if (gi >= total) return;
  int b = gi / (3 * N);
  int r = gi - b * 3 * N;
  const float* fxb = fx + (size_t)b * 192 * N + r;
  const float* fyb = fy + (size_t)b * 192 * N + r;
  float sx = 0.f, sy = 0.f;
  for (int c = 0; c < 64; ++c) { sx += fxb[(size_t)c * 3 * N]; sy += fyb[(size_t)c * 3 * N]; }
  px[gi] = sx * (1.f / 64.f);
  py[gi] = sy * (1.f / 64.f);
}

// ---------------- score logits: sum_c (fx.px)(fy.py) (softmax+norm skipped: monotone) ----------------
__global__ void k_dotphi(const float* __restrict__ fx, const float* __restrict__ fy,
                         const float* __restrict__ px, const float* __restrict__ py,
                         float* __restrict__ dps, int N, int B) {
  int gi = blockIdx.x * 256 + threadIdx.x;
  if (gi >= B * N) return;
  int b = gi / N, n = gi - b * N;
  const float* fxb = fx + (size_t)b * 192 * N + n;
  const float* fyb = fy + (size_t)b * 192 * N + n;
  const float* pxb = px + (size_t)b * 3 * N + n;
  const float* pyb = py + (size_t)b * 3 * N + n;
  float acc = 0.f;
  for (int c = 0; c < 64; ++c) {
    float ax = 0.f, ay = 0.f;
    for (int d = 0; d < 3; ++d) {
      ax = fmaf(fxb[(size_t)(c * 3 + d) * N], pxb[(size_t)d * N], ax);
      ay = fmaf(fyb[(size_t)(c * 3 + d) * N], pyb[(size_t)d * N], ay);
    }
    acc = fmaf(ax, ay, acc);
  }
  dps[gi] = acc;
}

// ---------------- top-N/2 selection: bitonic sort (desc value, asc index) ----------------
__global__ void __launch_bounds__(1024) k_topsel(const float* __restrict__ dps,
                                                 int* __restrict__ sel, int N, int Nh) {
  __shared__ float kv[2048];
  __shared__ int ki[2048];
  int b = blockIdx.x, tid = threadIdx.x;
  for (int i = tid; i < N; i += 1024) { kv[i] = dps[b * N + i]; ki[i] = i; }
  __syncthreads();
  for (int kk = 2; kk <= N; kk <<= 1) {
    for (int jj = kk >> 1; jj > 0; jj >>= 1) {
      for (int i = tid; i < N; i += 1024) {
        int ixj = i ^ jj;
        if (ixj > i) {
          float va = kv[i], vb = kv[ixj];
          int ia = ki[i], ib = ki[ixj];
          bool aFirst = (va > vb) || (va == vb && ia < ib);
          bool up = ((i & kk) == 0);
          bool doswap = up ? (!aFirst) : aFirst;
          if (doswap) { kv[i] = vb; kv[ixj] = va; ki[i] = ib; ki[ixj] = ia; }
        }
      }
      __syncthreads();
    }
  }
  for (int i = tid; i < Nh; i += 1024) sel[b * Nh + i] = ki[i];
}

// ---------------- gather selected points (pm source, cm dest), wave per point ----------------
__global__ void __launch_bounds__(256) k_gather(const float* __restrict__ sxpm, const float* __restrict__ sypm,
                                                const int* __restrict__ sel,
                                                float* __restrict__ dx, float* __restrict__ dy,
                                                int N, int Nh) {
  int tid = threadIdx.x;
  int p = blockIdx.x * 4 + (tid >> 6);
  int c = tid & 63;
  int b = p / Nh, i = p - b * Nh;
  int s = sel[b * Nh + i];
  size_t bs = ((size_t)(b * N + s) * 3) * 64 + c;
  size_t r0 = (size_t)((b * 64 + c) * 3) * Nh;
#pragma unroll
  for (int d = 0; d < 3; ++d) {
    dx[r0 + (size_t)d * Nh + i] = sxpm[bs + d * 64];
    dy[r0 + (size_t)d * Nh + i] = sypm[bs + d * 64];
  }
}

// ---------------- final head: vn_lin_lrelu(concat blocks, h_w, h_d) ----------------
__global__ void k_head(const float* __restrict__ blkX, const float* __restrict__ blkY,
                       const float* __restrict__ hw, const float* __restrict__ hd,
                       float* __restrict__ Fx, float* __restrict__ Fy) {
  __shared__ float f[3][128];
  __shared__ float xl[3][32];
  __shared__ float dv[3][32];
  int which = blockIdx.x, b = blockIdx.y, tid = threadIdx.x;
  const float* blk = which ? blkY : blkX;
  float* F = which ? Fy : Fx;
  int o = tid & 31, dd = tid >> 5;
  for (int i = tid; i < 384; i += 96) f[i % 3][i / 3] = blk[(size_t)b * 384 + i];
  __syncthreads();
  float s = 0.f;
  for (int c = 0; c < 128; ++c) s = fmaf(hw[o * 128 + c], f[dd][c], s);
  xl[dd][o] = s;
  __syncthreads();
  float s2 = 0.f;
  for (int p = 0; p < 32; ++p) s2 = fmaf(hd[o * 32 + p], xl[dd][p], s2);
  dv[dd][o] = s2;
  __syncthreads();
  float dot = xl[0][o] * dv[0][o] + xl[1][o] * dv[1][o] + xl[2][o] * dv[2][o];
  float dsq = dv[0][o] * dv[0][o] + dv[1][o] * dv[1][o] + dv[2][o] * dv[2][o];
  F[((size_t)b * 32 + o) * 3 + dd] = lrelu_combine(xl[dd][o], dv[dd][o], dot, dsq);
}

// ================== LAPACK-faithful 3x3 SVD (dgesdd path: dgebrd + dbdsqr) ==================
#define DEPS 2.220446049250313e-16
#define DUNFL 2.2250738585072014e-308

static __device__ void dlartg_(double f, double g, double* cs, double* sn, double* r) {
  if (g == 0.0) { *cs = 1.0; *sn = 0.0; *r = f; }
  else if (f == 0.0) { *cs = 0.0; *sn = copysign(1.0, g); *r = fabs(g); }
  else {
    double d = sqrt(f * f + g * g);
    double c = fabs(f) / d;
    double rr = copysign(d, f);
    *cs = c; *r = rr; *sn = g / rr;
  }
}

static __device__ void dlas2_(double f, double g, double h, double* ssmin, double* ssmax) {
  double fa = fabs(f), ga = fabs(g), ha = fabs(h);
  double fhmn = fmin(fa, ha), fhmx = fmax(fa, ha);
  if (fhmn == 0.0) {
    *ssmin = 0.0;
    if (fhmx == 0.0) *ssmax = ga;
    else { double mx = fmax(fhmx, ga), mn = fmin(fhmx, ga); double q = mn / mx; *ssmax = mx * sqrt(1.0 + q * q); }
  } else {
    if (ga < fhmx) {
      double as_ = 1.0 + fhmn / fhmx;
      double at = (fhmx - fhmn) / fhmx;
      double au = ga / fhmx; au = au * au;
      double c = 2.0 / (sqrt(as_ * as_ + au) + sqrt(at * at + au));
      *ssmin = fhmn * c; *ssmax = fhmx / c;
    } else {
      double au = fhmx / ga;
      if (au == 0.0) { *ssmin = (fhmn * fhmx) / ga; *ssmax = ga; }
      else {
        double as_ = 1.0 + fhmn / fhmx;
        double at = (fhmx - fhmn) / fhmx;
        double t1 = as_ * au, t2 = at * au;
        double c = 1.0 / (sqrt(1.0 + t1 * t1) + sqrt(1.0 + t2 * t2));
        double sm = (fhmn * c) * au; *ssmin = sm + sm;
        *ssmax = ga / (c + c);
      }
    }
  }
}

static __device__ void dlasv2_(double f, double g, double h,
                               double* ssmin, double* ssmax,
                               double* snr, double* csr, double* snl, double* csl) {
  double ft = f, fa = fabs(f), ht = h, ha = fabs(h);
  int pmax = 1;
  bool swp = (ha > fa);
  if (swp) { pmax = 3; double t = ft; ft = ht; ht = t; t = fa; fa = ha; ha = t; }
  double gt = g, ga = fabs(g);
  double clt = 0, crt = 0, slt = 0, srt = 0;
  if (ga == 0.0) {
    *ssmin = ha; *ssmax = fa; clt = 1.0; crt = 1.0; slt = 0.0; srt = 0.0;
  } else {
    bool gasmal = true;
    if (ga > fa) {
      pmax = 2;
      if ((fa / ga) < DEPS) {
        gasmal = false;
        *ssmax = ga;
        *ssmin = (ha > 1.0) ? (fa / (ga / ha)) : ((fa / ga) * ha);
        clt = 1.0; slt = ht / gt; srt = 1.0; crt = ft / gt;
      }
    }
    if (gasmal) {
      double dd = fa - ha;
      double l = (dd == fa) ? 1.0 : (dd / fa);
      double mq = gt / ft;
      double t = 2.0 - l;
      double mm = mq * mq, tt = t * t;
      double s = sqrt(tt + mm);
      double r = (l == 0.0) ? fabs(mq) : sqrt(l * l + mm);
      double a = 0.5 * (s + r);
      *ssmin = ha / a;
      *ssmax = fa * a;
      if (mm == 0.0) {
        if (l == 0.0) t = copysign(2.0, ft) * copysign(1.0, gt);
        else t = gt / copysign(dd, ft) + mq / t;
      } else {
        t = (mq / (s + t) + mq / (r + l)) * (1.0 + a);
      }
      double l2 = sqrt(t * t + 4.0);
      crt = 2.0 / l2;
      srt = t / l2;
      clt = (crt + srt * mq) / a;
      slt = (ht / ft) * srt / a;
    }
  }
  if (swp) { *csl = srt; *snl = crt; *csr = slt; *snr = clt; }
  else { *csl = clt; *snl = slt; *csr = crt; *snr = srt; }
  double tsign = 0.0;
  if (pmax == 1) tsign = copysign(1.0, *csr) * copysign(1.0, *csl) * copysign(1.0, f);
  if (pmax == 2) tsign = copysign(1.0, *snr) * copysign(1.0, *csl) * copysign(1.0, g);
  if (pmax == 3) tsign = copysign(1.0, *snr) * copysign(1.0, *snl) * copysign(1.0, h);
  *ssmax = copysign(*ssmax, tsign);
  *ssmin = copysign(*ssmin, tsign * copysign(1.0, f) * copysign(1.0, h));
}

static __device__ void dbdsqr3(double d[3], double e[2], double VT[3][3], double U[3][3]) {
  const int n = 3;
  double tolmul = fmax(10.0, fmin(100.0, pow(DEPS, -0.125)));
  double tol = tolmul * DEPS;
  double thresh;
  {
    double sminoa = fabs(d[0]);
    if (sminoa != 0.0) {
      double mu = sminoa;
      for (int i = 1; i < n; ++i) {
        mu = fabs(d[i]) * (mu / (mu + fabs(e[i - 1])));
        sminoa = fmin(sminoa, mu);
        if (sminoa == 0.0) break;
      }
    }
    sminoa = sminoa / sqrt((double)n);
    thresh = fmax(tol * sminoa, 6.0 * n * n * DUNFL);
  }
  int maxit = 6 * n * n;
  int iter = 0, oldll = -1, oldm = -1, idir = 0;
  int m = n;
  double sminl = 0.0;
  int guard = 0;
  while (true) {
    if (m <= 1) break;
    if (iter > maxit) break;
    if (++guard > 500) break;
    double smaxb = fabs(d[m - 1]);
    int ll = 0; bool found = false;
    for (int lll = 1; lll <= m - 1; ++lll) {
      int l = m - lll;
      double abss = fabs(d[l - 1]);
      double abse = fabs(e[l - 1]);
      if (abse <= thresh) { ll = l; found = true; break; }
      smaxb = fmax(smaxb, fmax(abss, abse));
    }
    if (found) {
      e[ll - 1] = 0.0;
      if (ll == m - 1) { m = m - 1; continue; }
      ll = ll + 1;
    } else ll = 1;
    if (ll == m - 1) {
      double sigmn, sigmx, sinr, cosr, sinl2, cosl2;
      dlasv2_(d[m - 2], e[m - 2], d[m - 1], &sigmn, &sigmx, &sinr, &cosr, &sinl2, &cosl2);
      d[m - 2] = sigmx; d[m - 1] = sigmn; e[m - 2] = 0.0;
      for (int j = 0; j < 3; ++j) {
        double t1 = VT[m - 2][j], t2 = VT[m - 1][j];
        VT[m - 2][j] = cosr * t1 + sinr * t2;
        VT[m - 1][j] = cosr * t2 - sinr * t1;
      }
      for (int i2 = 0; i2 < 3; ++i2) {
        double t1 = U[i2][m - 2], t2 = U[i2][m - 1];
        U[i2][m - 2] = cosl2 * t1 + sinl2 * t2;
        U[i2][m - 1] = cosl2 * t2 - sinl2 * t1;
      }
      m -= 2;
      continue;
    }
    if (ll > oldm || m < oldll)
      idir = (fabs(d[ll - 1]) >= fabs(d[m - 1])) ? 1 : 2;
    if (idir == 1) {
      if (fabs(e[m - 2]) <= tol * fabs(d[m - 1])) { e[m - 2] = 0.0; continue; }
      double mu = fabs(d[ll - 1]); sminl = mu;
      bool conv = true;
      for (int lll = ll; lll <= m - 1; ++lll) {
        if (fabs(e[lll - 1]) > tol * mu) { conv = false; break; }
        mu = fabs(d[lll]) * (mu / (mu + fabs(e[lll - 1])));
        sminl = fmin(sminl, mu);
      }
      if (conv) { e[m - 2] = 0.0; continue; }
    } else {
      if (fabs(e[ll - 1]) <= tol * fabs(d[ll - 1])) { e[ll - 1] = 0.0; continue; }
      double mu = fabs(d[m - 1]); sminl = mu;
      bool conv = true;
      for (int lll = m - 1; lll >= ll; --lll) {
        if (fabs(e[lll - 1]) > tol * mu) { conv = false; break; }
        mu = fabs(d[lll - 1]) * (mu / (mu + fabs(e[lll - 1])));
        sminl = fmin(sminl, mu);
      }
      if (conv) { e[ll - 1] = 0.0; continue; }
    }
    oldll = ll; oldm = m;
    double shift = 0.0, rr;
    if (!(n * tol * (sminl / smaxb) <= fmax(DEPS, 0.01 * tol))) {
      double sll;
      if (idir == 1) { sll = fabs(d[ll - 1]); dlas2_(d[m - 2], e[m - 2], d[m - 1], &shift, &rr); }
      else { sll = fabs(d[m - 1]); dlas2_(d[ll - 1], e[ll - 1], d[ll], &shift, &rr); }
      if (sll > 0.0) { double q = shift / sll; if (q * q < DEPS) shift = 0.0; }
    }
    iter += m - ll;
    double csv[2], snv[2], ocsv[2], osnv[2];
    int cnt = 0;
    if (shift == 0.0) {
      if (idir == 1) {
        double cs = 1.0, oldcs = 1.0, sn = 0.0, oldsn = 0.0, r;
        for (int i = ll; i <= m - 1; ++i) {
          dlartg_(d[i - 1] * cs, e[i - 1], &cs, &sn, &r);
          if (i > ll) e[i - 2] = oldsn * r;
          dlartg_(oldcs * r, d[i] * sn, &oldcs, &oldsn, &d[i - 1]);
          csv[cnt] = cs; snv[cnt] = sn; ocsv[cnt] = oldcs; osnv[cnt] = oldsn; cnt++;
        }
        double hh = d[m - 1] * cs;
        d[m - 1] = hh * oldcs;
        e[m - 2] = hh * oldsn;
        for (int k = 0; k < cnt; ++k) {
          int r0 = ll - 1 + k, r1 = r0 + 1;
          for (int j = 0; j < 3; ++j) {
            double t1 = VT[r0][j], t2 = VT[r1][j];
            VT[r0][j] = snv[k] * t2 + csv[k] * t1;
            VT[r1][j] = csv[k] * t2 - snv[k] * t1;
          }
        }
        for (int k = 0; k < cnt; ++k) {
          int c0 = ll - 1 + k, c1 = c0 + 1;
          for (int i2 = 0; i2 < 3; ++i2) {
            double t1 = U[i2][c0], t2 = U[i2][c1];
            U[i2][c0] = osnv[k] * t2 + ocsv[k] * t1;
            U[i2][c1] = ocsv[k] * t2 - osnv[k] * t1;
          }
        }
        if (fabs(e[m - 2]) <= thresh) e[m - 2] = 0.0;
      } else {
        double cs = 1.0, oldcs = 1.0, sn = 0.0, oldsn = 0.0, r;
        for (int i = m; i >= ll + 1; --i) {
          dlartg_(d[i - 1] * cs, e[i - 2], &cs, &sn, &r);
          if (i < m) e[i - 1] = oldsn * r;
          dlartg_(oldcs * r, d[i - 2] * sn, &oldcs, &oldsn, &d[i - 1]);
          int k = i - ll - 1;
          csv[k] = cs; snv[k] = -sn; ocsv[k] = oldcs; osnv[k] = -oldsn; cnt++;
        }
        double hh = d[ll - 1] * cs;
        d[ll - 1] = hh * oldcs;
        e[ll - 1] = hh * oldsn;
        for (int k = cnt - 1; k >= 0; --k) {
          int r0 = ll - 1 + k, r1 = r0 + 1;
          for (int j = 0; j < 3; ++j) {
            double t1 = VT[r0][j], t2 = VT[r1][j];
            VT[r0][j] = osnv[k] * t2 + ocsv[k] * t1;
            VT[r1][j] = ocsv[k] * t2 - osnv[k] * t1;
          }
        }
        for (int k = cnt - 1; k >= 0; --k) {
          int c0 = ll - 1 + k, c1 = c0 + 1;
          for (int i2 = 0; i2 < 3; ++i2) {
            double t1 = U[i2][c0], t2 = U[i2][c1];
            U[i2][c0] = snv[k] * t2 + csv[k] * t1;
            U[i2][c1] = csv[k] * t2 - snv[k] * t1;
          }
        }
        if (fabs(e[ll - 1]) <= thresh) e[ll - 1] = 0.0;
      }
    } else {
      if (idir == 1) {
        double f = (fabs(d[ll - 1]) - shift) * (copysign(1.0, d[ll - 1]) + shift / d[ll - 1]);
        double g = e[ll - 1];
        double cosr, sinr, cosl2, sinl2, r;
        for (int i = ll; i <= m - 1; ++i) {
          dlartg_(f, g, &cosr, &sinr, &r);
          if (i > ll) e[i - 2] = r;
          f = cosr * d[i - 1] + sinr * e[i - 1];
          e[i - 1] = cosr * e[i - 1] - sinr * d[i - 1];
          g = sinr * d[i];
          d[i] = cosr * d[i];
          dlartg_(f, g, &cosl2, &sinl2, &r);
          d[i - 1] = r;
          f = cosl2 * e[i - 1] + sinl2 * d[i];
          d[i] = cosl2 * d[i] - sinl2 * e[i - 1];
          if (i < m - 1) {
            g = sinl2 * e[i];
            e[i] = cosl2 * e[i];
          }
          csv[cnt] = cosr; snv[cnt] = sinr; ocsv[cnt] = cosl2; osnv[cnt] = sinl2; cnt++;
        }
        e[m - 2] = f;
        for (int k = 0; k < cnt; ++k) {
          int r0 = ll - 1 + k, r1 = r0 + 1;
          for (int j = 0; j < 3; ++j) {
            double t1 = VT[r0][j], t2 = VT[r1][j];
            VT[r0][j] = snv[k] * t2 + csv[k] * t1;
            VT[r1][j] = csv[k] * t2 - snv[k] * t1;
          }
        }
        for (int k = 0; k < cnt; ++k) {
          int c0 = ll - 1 + k, c1 = c0 + 1;
          for (int i2 = 0; i2 < 3; ++i2) {
            double t1 = U[i2][c0], t2 = U[i2][c1];
            U[i2][c0] = osnv[k] * t2 + ocsv[k] * t1;
            U[i2][c1] = ocsv[k] * t2 - osnv[k] * t1;
          }
        }
        if (fabs(e[m - 2]) <= thresh) e[m - 2] = 0.0;
      } else {
        double f = (fabs(d[m - 1]) - shift) * (copysign(1.0, d[m - 1]) + shift / d[m - 1]);
        double g = e[m - 2];
        for (int i = m; i >= ll + 1; --i) {
          double cosr, sinr, cosl2, sinl2, r;
          dlartg_(f, g, &cosr, &sinr, &r);
          if (i < m) e[i - 1] = r;
          f = cosr * d[i - 1] + sinr * e[i - 2];
          e[i - 2] = cosr * e[i - 2] - sinr * d[i - 1];
          g = sinr * d[i - 2];
          d[i - 2] = cosr * d[i - 2];
          dlartg_(f, g, &cosl2, &sinl2, &r);
          d[i - 1] = r;
          f = cosl2 * e[i - 2] + sinl2 * d[i - 2];
          d[i - 2] = cosl2 * d[i - 2] - sinl2 * e[i - 2];
          if (i > ll + 1) {
            g = sinl2 * e[i - 3];
            e[i - 3] = cosl2 * e[i - 3];
          }
          int k = i - ll - 1;
          ocsv[k] = cosl2; osnv[k] = -sinl2; csv[k] = cosr; snv[k] = -sinr; cnt++;
        }
        e[ll - 1] = f;
        for (int k = cnt - 1; k >= 0; --k) {
          int r0 = ll - 1 + k, r1 = r0 + 1;
          for (int j = 0; j < 3; ++j) {
            double t1 = VT[r0][j], t2 = VT[r1][j];
            VT[r0][j] = snv[k] * t2 + csv[k] * t1;
            VT[r1][j] = csv[k] * t2 - snv[k] * t1;
          }
        }
        for (int k = cnt - 1; k >= 0; --k) {
          int c0 = ll - 1 + k, c1 = c0 + 1;
          for (int i2 = 0; i2 < 3; ++i2) {
            double t1 = U[i2][c0], t2 = U[i2][c1];
            U[i2][c0] = osnv[k] * t2 + ocsv[k] * t1;
            U[i2][c1] = ocsv[k] * t2 - osnv[k] * t1;
          }
        }
        if (fabs(e[ll - 1]) <= thresh) e[ll - 1] = 0.0;
      }
    }
  }
  for (int i = 0; i < n; ++i)
    if (d[i] < 0.0) { d[i] = -d[i]; for (int j = 0; j < 3; ++j) VT[i][j] = -VT[i][j]; }
  for (int i = 1; i <= n - 1; ++i) {
    int isub = 1; double smn = d[0];
    for (int j = 2; j <= n + 1 - i; ++j)
      if (d[j - 1] <= smn) { isub = j; smn = d[j - 1]; }
    if (isub != n + 1 - i) {
      int a = isub - 1, b2 = n - i;
      double t = d[a]; d[a] = d[b2]; d[b2] = t;
      for (int j = 0; j < 3; ++j) { t = VT[a][j]; VT[a][j] = VT[b2][j]; VT[b2][j] = t; }
      for (int j = 0; j < 3; ++j) { t = U[j][a]; U[j][a] = U[j][b2]; U[j][b2] = t; }
    }
  }
}

__global__ void k_svd(const float* __restrict__ Fx, const float* __restrict__ Fy,
                      float* __restrict__ out, int B) {
  int b = blockIdx.x;
  if (threadIdx.x != 0) return;
  double A[3][3];
  for (int d = 0; d < 3; ++d)
    for (int e = 0; e < 3; ++e) {
      double s = 0.0;
      for (int c = 0; c < 32; ++c)
        s += (double)Fx[((size_t)b * 32 + c) * 3 + d] * (double)Fy[((size_t)b * 32 + c) * 3 + e];
      A[d][e] = s;
    }
  double dg[3], eg[2], tauq0, tauq1, taup0;
  double v1_1 = 0, v1_2 = 0, v2_1 = 0, w1 = 0;
  {
    double alpha = A[0][0];
    double xn = sqrt(A[1][0] * A[1][0] + A[2][0] * A[2][0]);
    if (xn == 0.0) { tauq0 = 0.0; dg[0] = alpha; }
    else {
      double beta = -copysign(sqrt(alpha * alpha + xn * xn), alpha);
      tauq0 = (beta - alpha) / beta;
      double scal = 1.0 / (alpha - beta);
      v1_1 = A[1][0] * scal; v1_2 = A[2][0] * scal;
      dg[0] = beta;
    }
    for (int j = 1; j < 3; ++j) {
      double w = A[0][j] + v1_1 * A[1][j] + v1_2 * A[2][j];
      w *= tauq0;
      A[0][j] -= w; A[1][j] -= w * v1_1; A[2][j] -= w * v1_2;
    }
  }
  {
    double alpha = A[0][1];
    double xn = fabs(A[0][2]);
    if (xn == 0.0) { taup0 = 0.0; eg[0] = alpha; }
    else {
      double beta = -copysign(sqrt(alpha * alpha + xn * xn), alpha);
      taup0 = (beta - alpha) / beta;
      w1 = A[0][2] / (alpha - beta);
      eg[0] = beta;
    }
    for (int i = 1; i < 3; ++i) {
      double t = A[i][1] + w1 * A[i][2];
      t *= taup0;
      A[i][1] -= t; A[i][2] -= t * w1;
    }
  }
  {
    double alpha = A[1][1];
    double xn = fabs(A[2][1]);
    if (xn == 0.0) { tauq1 = 0.0; dg[1] = alpha; }
    else {
      double beta = -copysign(sqrt(alpha * alpha + xn * xn), alpha);
      tauq1 = (beta - alpha) / beta;
      v2_1 = A[2][1] / (alpha - beta);
      dg[1] = beta;
    }
    double w = A[1][2] + v2_1 * A[2][2];
    w *= tauq1;
    A[1][2] -= w; A[2][2] -= w * v2_1;
  }
  eg[1] = A[1][2];
  dg[2] = A[2][2];
  double U[3][3] = {{1, 0, 0}, {0, 1, 0}, {0, 0, 1}};
  double VT[3][3] = {{1, 0, 0}, {0, 1, 0}, {0, 0, 1}};
  dbdsqr3(dg, eg, VT, U);
  for (int j = 0; j < 3; ++j) {
    double w = U[1][j] + v2_1 * U[2][j];
    w *= tauq1;
    U[1][j] -= w; U[2][j] -= w * v2_1;
  }
  for (int j = 0; j < 3; ++j) {
    double w = U[0][j] + v1_1 * U[1][j] + v1_2 * U[2][j];
    w *= tauq0;
    U[0][j] -= w; U[1][j] -= w * v1_1; U[2][j] -= w * v1_2;
  }
  for (int r = 0; r < 3; ++r) {
    double t = VT[r][1] + w1 * VT[r][2];
    t *= taup0;
    VT[r][1] -= t; VT[r][2] -= t * w1;
  }
  for (int i = 0; i < 3; ++i)
    for (int j = 0; j < 3; ++j) {
      double r = 0;
      for (int k = 0; k < 3; ++k) r += U[i][k] * VT[j][k];
      out[b * 9 + i * 3 + j] = (float)r;
    }
  for (int dd = 0; dd < 3; ++dd) {
    float sx = 0.f, sy = 0.f;
    for (int c = 0; c < 32; ++c) {
      float vx = Fx[((size_t)b * 32 + c) * 3 + dd];
      float vy = Fy[((size_t)b * 32 + c) * 3 + dd];
      sx = fmaf(vx, vx, sx);
      sy = fmaf(vy, vy, sy);
    }
    out[B * 9 + b * 3 + dd] = sqrtf(sy) / sqrtf(sx);
  }
}

extern "C" void kernel_launch(void* const* d_in, const int* in_sizes, int n_in,
                              void* d_out, int out_size, void* d_ws, size_t ws_size,
                              hipStream_t stream) {
  (void)in_sizes; (void)n_in; (void)out_size; (void)ws_size;
  const int B = 2, N0 = 2048;
  const float* W[24];
  for (int i = 0; i < 24; ++i) W[i] = (const float*)d_in[i];

  float* ws = (float*)d_ws;
  const size_t P = (size_t)B * 64 * 3 * 2048;  // 786432 floats
  float* bufA = ws;
  float* bufB = bufA + P;
  float* bufC = bufB + P;
  float* bufD = bufC + P;
  float* bufApm = bufD + P;
  float* bufBpm = bufApm + P;
  float* C1 = bufBpm + P;
  float* C2 = C1 + P;
  float* C3 = C2 + P;
  float* C4 = C3 + P;
  float* C5 = C4 + P;
  float* M1 = C5 + P;
  float* M2 = M1 + P;
  float* M3 = M2 + P;
  float* M4 = M3 + P;
  float* M5 = M4 + P;
  float* M6 = M5 + P;
  float* M7 = M6 + P;
  float* M8 = M7 + P;
  float* M9 = M8 + P;
  float* M10 = M9 + P;
  float* px = M10 + P;               // B*3*2048 = 12288
  float* py = px + 12288;
  float* dps = py + 12288;           // 4096
  float* xx0 = dps + 4096;           // 4096
  float* xx1 = xx0 + 4096;           // 4096
  float* meanX = xx1 + 4096;         // 384
  float* meanY = meanX + 384;
  float* cbX = meanY + 384;
  float* cbY = cbX + 384;
  float* blkX = cbY + 384;           // 768
  float* blkY = blkX + 768;
  float* Fxb = blkY + 768;           // 192
  float* Fyb = Fxb + 192;
  int* idxA = (int*)(Fyb + 192);     // 65536
  int* idxB = idxA + 65536;
  int* sel = idxB + 65536;           // 2048

  auto knn = [&](const float* xa, const float* xb2, int D, int N, int* ia, int* ib, int ns) {
    k_xx2<<<dim3((N + 255) / 256, B, ns), 256, 0, stream>>>(xa, xb2, xx0, xx1, D, N);
    dim3 g2(N / 4, B, ns);
    if (D == 192) k_knn2<192><<<g2, 256, 0, stream>>>(xa, xb2, xx0, xx1, ia, ib, N);
    else          k_knn2<3><<<g2, 256, 0, stream>>>(xa, xb2, xx0, xx1, ia, ib, N);
  };

  const float* fx = W[0];
  const float* fy = W[1];
  int N = N0;
  for (int blk = 0; blk < 2; ++blk) {
    int D = (blk == 0) ? 3 : 192;
    const float* dgw = W[blk ? 12 : 2]; const float* dgd = W[blk ? 13 : 3];
    const float* qw  = W[blk ? 14 : 4]; const float* qd  = W[blk ? 15 : 5];
    const float* kw  = W[blk ? 16 : 6]; const float* kd  = W[blk ? 17 : 7];
    const float* vw  = W[blk ? 18 : 8]; const float* vd  = W[blk ? 19 : 9];
    const float* gw  = W[blk ? 20 : 10]; const float* gd = W[blk ? 21 : 11];
    dim3 gP(B * N / 4);
    dim3 gL((3 * N + 255) / 256, B, 1);

    // ======== dgcnn, both sides in merged launches ========
    knn(fx, fy, D, N, idxA, idxB, 2);
    {
      LinSlots s{};  // stage1: W1*x, (W2-W1)*x for fx and fy
      int wsd = (blk == 0) ? 2 : 128;
      int off2 = (blk == 0) ? 1 : 64;
      const float* Xs[4] = {fx, fx, fy, fy};
      float* cms[4] = {C1, C2, C3, C4};
      float* pms[4] = {M1, M2, M3, M4};
      for (int i = 0; i < 4; ++i) {
        s.W[i] = dgw; s.X[i] = Xs[i]; s.bias[i] = nullptr;
        s.cm[i] = cms[i]; s.pm[i] = pms[i];
        s.ws[i] = wsd; s.woff[i] = (i & 1) ? off2 : 0; s.sub[i] = (i & 1);
      }
      gL.z = 16;
      if (blk == 0) k_linm<1><<<gL, 256, 0, stream>>>(s, N);
      else          k_linm<64><<<gL, 256, 0, stream>>>(s, N);
    }
    {
      LinSlots s{};  // stage2: Wd * each
      const float* Xs[4] = {C1, C2, C3, C4};
      float* pms[4] = {M5, M6, M7, M8};
      for (int i = 0; i < 4; ++i) {
        s.W[i] = dgd; s.X[i] = Xs[i]; s.bias[i] = nullptr;
        s.cm[i] = nullptr; s.pm[i] = pms[i];
        s.ws[i] = 64; s.woff[i] = 0; s.sub[i] = 0;
      }
      gL.z = 16;
      k_linm<64><<<gL, 256, 0, stream>>>(s, N);
    }
    k_edge2<<<dim3(B * N / 4, 2), 256, 0, stream>>>(M1, M2, M5, M6, M3, M4, M7, M8,
                                                    idxA, idxB, bufA, bufB, N);

    // ======== cross_context #1: x=bufA, y=bufB -> bufC ========
    knn(bufB, bufB, 192, N, idxB, idxB, 1);
    {
      LinSlots s{};  // stage1: q,k1,k2,v1,v2
      const float* Wm[5] = {qw, kw, kw, vw, vw};
      const float* Xs[5] = {bufA, bufB, bufB, bufB, bufB};
      float* cms[5] = {C1, C2, C3, C4, C5};
      float* pms[5] = {M1, M3, M4, M5, M6};
      int wss[5] = {64, 128, 128, 128, 128};
      int offs[5] = {0, 0, 64, 0, 64};
      int subs[5] = {0, 0, 1, 0, 1};
      for (int i = 0; i < 5; ++i) {
        s.W[i] = Wm[i]; s.X[i] = Xs[i]; s.bias[i] = nullptr;
        s.cm[i] = cms[i]; s.pm[i] = pms[i];
        s.ws[i] = wss[i]; s.woff[i] = offs[i]; s.sub[i] = subs[i];
      }
      gL.z = 20;
      k_linm<64><<<gL, 256, 0, stream>>>(s, N);
    }
    {
      LinSlots s{};  // stage2: qd,kd,kd,vd,vd
      const float* Wm[5] = {qd, kd, kd, vd, vd};
      const float* Xs[5] = {C1, C2, C3, C4, C5};
      float* pms[5] = {M2, M7, M8, M9, M10};
      for (int i = 0; i < 5; ++i) {
        s.W[i] = Wm[i]; s.X[i] = Xs[i]; s.bias[i] = nullptr;
        s.cm[i] = nullptr; s.pm[i] = pms[i];
        s.ws[i] = 64; s.woff[i] = 0; s.sub[i] = 0;
      }
      gL.z = 20;
      k_linm<64><<<gL, 256, 0, stream>>>(s, N);
    }
    k_att<<<gP, 256, 0, stream>>>(bufA, M1, M2, M3, M4, M7, M8, M5, M6, M9, M10, idxB, bufC, N);

    // ======== cross_context #2: x=bufB, y=bufC -> bufD ========
    knn(bufC, bufC, 192, N, idxA, idxA, 1);
    {
      LinSlots s{};
      const float* Wm[5] = {qw, kw, kw, vw, vw};
      const float* Xs[5] = {bufB, bufC, bufC, bufC, bufC};
      float* cms[5] = {C1, C2, C3, C4, C5};
      float* pms[5] = {M1, M3, M4, M5, M6};
      int wss[5] = {64, 128, 128, 128, 128};
      int offs[5] = {0, 0, 64, 0, 64};
      int subs[5] = {0, 0, 1, 0, 1};
      for (int i = 0; i < 5; ++i) {
        s.W[i] = Wm[i]; s.X[i] = Xs[i]; s.bias[i] = nullptr;
        s.cm[i] = cms[i]; s.pm[i] = pms[i];
        s.ws[i] = wss[i]; s.woff[i] = offs[i]; s.sub[i] = subs[i];
      }
      gL.z = 20;
      k_linm<64><<<gL, 256, 0, stream>>>(s, N);
    }
    {
      LinSlots s{};
      const float* Wm[5] = {qd, kd, kd, vd, vd};
      const float* Xs[5] = {C1, C2, C3, C4, C5};
      float* pms[5] = {M2, M7, M8, M9, M10};
      for (int i = 0; i < 5; ++i) {
        s.W[i] = Wm[i]; s.X[i] = Xs[i]; s.bias[i] = nullptr;
        s.cm[i] = nullptr; s.pm[i] = pms[i];
        s.ws[i] = 64; s.woff[i] = 0; s.sub[i] = 0;
      }
      gL.z = 20;
      k_linm<64><<<gL, 256, 0, stream>>>(s, N);
    }
    k_att<<<gP, 256, 0, stream>>>(bufB, M1, M2, M3, M4, M7, M8, M5, M6, M9, M10, idxA, bufD, N);

    // ======== global fuse ========
    k_cmean2<<<dim3(192, B, 2), 256, 0, stream>>>(bufC, bufD, meanX, meanY, N, 192, 0, 1.f / (float)N);
    k_gbias2<<<dim3(B, 2), 192, 0, stream>>>(gw, meanX, meanY, cbX, cbY);
    {
      LinSlots s{};  // gw on both sides (with bias)
      const float* Xs[2] = {bufC, bufD};
      const float* bs[2] = {cbX, cbY};
      float* cms[2] = {C1, C2};
      float* pms[2] = {M1, M2};
      for (int i = 0; i < 2; ++i) {
        s.W[i] = gw; s.X[i] = Xs[i]; s.bias[i] = bs[i];
        s.cm[i] = cms[i]; s.pm[i] = pms[i];
        s.ws[i] = 128; s.woff[i] = 0; s.sub[i] = 0;
      }
      gL.z = 8;
      k_linm<64><<<gL, 256, 0, stream>>>(s, N);
    }
    {
      LinSlots s{};  // gd on both sides
      const float* Xs[2] = {C1, C2};
      float* pms[2] = {M3, M4};
      for (int i = 0; i < 2; ++i) {
        s.W[i] = gd; s.X[i] = Xs[i]; s.bias[i] = nullptr;
        s.cm[i] = nullptr; s.pm[i] = pms[i];
        s.ws[i] = 64; s.woff[i] = 0; s.sub[i] = 0;
      }
      gL.z = 8;
      k_linm<64><<<gL, 256, 0, stream>>>(s, N);
    }
    k_gfin<<<dim3(B * N / 4, 2), 256, 0, stream>>>(M1, M3, M2, M4, bufA, bufApm, bufB, bufBpm, N);

    // ======== score + top-half selection ========
    int Nh = N / 2;
    k_parmean<<<dim3((B * 3 * N + 255) / 256), 256, 0, stream>>>(bufA, bufB, px, py, N, B);
    k_dotphi<<<dim3((B * N + 255) / 256), 256, 0, stream>>>(bufA, bufB, px, py, dps, N, B);
    k_topsel<<<dim3(B), 1024, 0, stream>>>(dps, sel, N, Nh);
    k_gather<<<dim3(B * Nh / 4), 256, 0, stream>>>(bufApm, bufBpm, sel, bufC, bufD, N, Nh);
    k_cmean2<<<dim3(192, B, 2), 256, 0, stream>>>(bufC, bufD, blkX, blkY, Nh, 384, blk * 192, 1.f / (float)Nh);
    fx = bufC; fy = bufD;
    N = Nh;
  }
  k_head<<<dim3(2, B), 96, 0, stream>>>(blkX, blkY, W[22], W[23], Fxb, Fyb);
  k_svd<<<dim3(B), 64, 0, stream>>>(Fxb, Fyb, (float*)d_out, B);
}